// Round 1
// baseline (1370.499 us; speedup 1.0000x reference)
//
#include <hip/hip_runtime.h>
#include <hip/hip_bf16.h>

#define N_NODES 50000
#define E_EDGES 1600000
#define HID 128
#define NH 8
#define HD 16

__device__ __forceinline__ float wave_reduce_sum(float v) {
    #pragma unroll
    for (int off = 32; off > 0; off >>= 1) v += __shfl_xor(v, off, 64);
    return v;
}

// ---------------- LayerNorm: one wave per row, float2 per lane ----------------
__global__ __launch_bounds__(256) void ln_kernel(const float* __restrict__ x,
                                                 const float* __restrict__ g,
                                                 const float* __restrict__ b,
                                                 float* __restrict__ out, int n) {
    int wave = threadIdx.x >> 6;
    int lane = threadIdx.x & 63;
    int row = blockIdx.x * 4 + wave;
    if (row >= n) return;
    float2 v = ((const float2*)(x + (size_t)row * HID))[lane];
    float s = wave_reduce_sum(v.x + v.y);
    float mu = s * (1.0f / HID);
    float dx = v.x - mu, dy = v.y - mu;
    float q = wave_reduce_sum(dx * dx + dy * dy);
    float rstd = rsqrtf(q * (1.0f / HID) + 1e-5f);
    float2 gg = ((const float2*)g)[lane];
    float2 bb = ((const float2*)b)[lane];
    float2 o;
    o.x = dx * rstd * gg.x + bb.x;
    o.y = dy * rstd * gg.y + bb.y;
    ((float2*)(out + (size_t)row * HID))[lane] = o;
}

// ---------------- Generic fp32 GEMM: C[M,Nc] = A[M,K]@W[K,Nc] + bias (+res, relu) ---
// block 256, tile = 16 rows x 128 cols; thread owns 8 rows (rg) x 1 col.
template <int K>
__global__ __launch_bounds__(256) void gemm_kernel(const float* __restrict__ A,
                                                   const float* __restrict__ W,
                                                   const float* __restrict__ bias,
                                                   const float* __restrict__ res,
                                                   float* __restrict__ C,
                                                   int Nc, int relu) {
    __shared__ float4 aLDS[16 * K / 4];
    int row0 = blockIdx.x * 16;
    int col0 = blockIdx.y * 128;
    const float4* A4 = (const float4*)(A + (size_t)row0 * K);
    for (int idx = threadIdx.x; idx < 16 * K / 4; idx += 256) aLDS[idx] = A4[idx];
    __syncthreads();

    int c = col0 + (threadIdx.x & 127);
    int rg = threadIdx.x >> 7;
    float acc[8] = {0.f, 0.f, 0.f, 0.f, 0.f, 0.f, 0.f, 0.f};
    const float* wp = W + c;
    #pragma unroll 4
    for (int kq = 0; kq < K / 4; ++kq) {
        float w0 = wp[(kq * 4 + 0) * Nc];
        float w1 = wp[(kq * 4 + 1) * Nc];
        float w2 = wp[(kq * 4 + 2) * Nc];
        float w3 = wp[(kq * 4 + 3) * Nc];
        #pragma unroll
        for (int i = 0; i < 8; ++i) {
            float4 a = aLDS[(rg * 8 + i) * (K / 4) + kq];
            acc[i] = fmaf(a.x, w0, acc[i]);
            acc[i] = fmaf(a.y, w1, acc[i]);
            acc[i] = fmaf(a.z, w2, acc[i]);
            acc[i] = fmaf(a.w, w3, acc[i]);
        }
    }
    float bv = bias[c];
    #pragma unroll
    for (int i = 0; i < 8; ++i) {
        int r = row0 + rg * 8 + i;
        float v = acc[i] + bv;
        if (relu) v = fmaxf(v, 0.f);
        if (res) v += res[(size_t)r * Nc + c];
        C[(size_t)r * Nc + c] = v;
    }
}

// ---------------- Edge scores: one thread per (edge, head) ----------------
__global__ __launch_bounds__(256) void edge_score_kernel(const int* __restrict__ ei,
                                                         const int* __restrict__ attr,
                                                         const float* __restrict__ Q,
                                                         const float* __restrict__ Km,
                                                         const float* __restrict__ btab,
                                                         float* __restrict__ sexp,
                                                         float* __restrict__ attn_sum) {
    int t = blockIdx.x * 256 + threadIdx.x;
    if (t >= E_EDGES * NH) return;
    int e = t >> 3, h = t & 7;
    int src = ei[e];
    int dst = ei[E_EDGES + e];
    int a = attr[e];
    a = min(max(a, 0), 12);
    const float4* qp = (const float4*)(Q + (size_t)dst * HID + h * HD);
    const float4* kp = (const float4*)(Km + (size_t)src * HID + h * HD);
    float s = 0.f;
    #pragma unroll
    for (int j = 0; j < 4; ++j) {
        float4 q = qp[j], k = kp[j];
        s += q.x * k.x + q.y * k.y + q.z * k.z + q.w * k.w;
    }
    s = s * 0.25f + btab[a * NH + h];
    float ex = __expf(s);
    sexp[t] = ex;
    atomicAdd(attn_sum + (size_t)dst * NH + h, ex);
}

// ---------------- CSR build ----------------
__global__ __launch_bounds__(256) void count_kernel(const int* __restrict__ ei, int* __restrict__ counts) {
    int e = blockIdx.x * 256 + threadIdx.x;
    if (e < E_EDGES) atomicAdd(&counts[ei[E_EDGES + e]], 1);
}

__global__ __launch_bounds__(1024) void scan_kernel(const int* __restrict__ counts,
                                                    int* __restrict__ offs,
                                                    int* __restrict__ cursor) {
    __shared__ int sdata[1024];
    int tid = threadIdx.x;
    const int CH = (N_NODES + 1023) / 1024;  // 49
    int lo = tid * CH, hi = min(lo + CH, N_NODES);
    int s = 0;
    for (int i = lo; i < hi; ++i) s += counts[i];
    sdata[tid] = s;
    __syncthreads();
    for (int off = 1; off < 1024; off <<= 1) {
        int v = (tid >= off) ? sdata[tid - off] : 0;
        __syncthreads();
        sdata[tid] += v;
        __syncthreads();
    }
    int run = sdata[tid] - s;  // exclusive prefix
    for (int i = lo; i < hi; ++i) {
        offs[i] = run;
        cursor[i] = run;
        run += counts[i];
    }
    if (tid == 0) offs[N_NODES] = E_EDGES;
}

__global__ __launch_bounds__(256) void fill_kernel(const int* __restrict__ ei,
                                                   int* __restrict__ cursor,
                                                   int* __restrict__ eids) {
    int e = blockIdx.x * 256 + threadIdx.x;
    if (e < E_EDGES) {
        int pos = atomicAdd(&cursor[ei[E_EDGES + e]], 1);
        eids[pos] = e;
    }
}

// ---------------- Message aggregation: one block (128 thr) per dst node ----------------
__global__ __launch_bounds__(128) void message_kernel(const int* __restrict__ ei,
                                                      const int* __restrict__ offs,
                                                      const int* __restrict__ eids,
                                                      const float* __restrict__ sexp,
                                                      const float* __restrict__ attn_sum,
                                                      const float* __restrict__ V,
                                                      float* __restrict__ out) {
    int n = blockIdx.x;
    int tid = threadIdx.x;
    int h = tid >> 4;
    int lo = offs[n], hi = offs[n + 1];
    float acc = 0.f;
    for (int i = lo; i < hi; ++i) {
        int e = eids[i];
        int src = ei[e];
        float w = sexp[(size_t)e * NH + h];
        acc += V[(size_t)src * HID + tid] * w;
    }
    float inv = 1.0f / (attn_sum[(size_t)n * NH + h] + 1e-8f);
    out[(size_t)n * HID + tid] = acc * inv;
}

extern "C" void kernel_launch(void* const* d_in, const int* in_sizes, int n_in,
                              void* d_out, int out_size, void* d_ws, size_t ws_size,
                              hipStream_t stream) {
    const float* x    = (const float*)d_in[0];
    const int*   ei   = (const int*)d_in[1];
    const int*   attr = (const int*)d_in[2];
    const float* Wq   = (const float*)d_in[3];
    const float* bq   = (const float*)d_in[4];
    const float* Wk   = (const float*)d_in[5];
    const float* bk   = (const float*)d_in[6];
    const float* Wv   = (const float*)d_in[7];
    const float* bv   = (const float*)d_in[8];
    const float* Wo   = (const float*)d_in[9];
    const float* bo   = (const float*)d_in[10];
    const float* ebt  = (const float*)d_in[11];
    const float* W1   = (const float*)d_in[12];
    const float* b1   = (const float*)d_in[13];
    const float* W2   = (const float*)d_in[14];
    const float* b2   = (const float*)d_in[15];
    const float* g1   = (const float*)d_in[16];
    const float* be1  = (const float*)d_in[17];
    const float* g2   = (const float*)d_in[18];
    const float* be2  = (const float*)d_in[19];
    float* out = (float*)d_out;

    char* ws = (char*)d_ws;
    const size_t szRow = (size_t)N_NODES * HID * 4;  // 25.6 MB
    size_t o = 0;
    float* h_buf   = (float*)(ws + o); o += szRow;                 // LN1 out (reused as h2)
    float* Q       = (float*)(ws + o); o += szRow;
    float* Km      = (float*)(ws + o); o += szRow;
    float* V       = (float*)(ws + o); o += szRow;
    float* sexp    = (float*)(ws + o); o += (size_t)E_EDGES * NH * 4;   // 51.2 MB
    float* asum    = (float*)(ws + o); o += (size_t)N_NODES * NH * 4;
    int*   counts  = (int*)(ws + o);   o += (size_t)N_NODES * 4;
    int*   offs    = (int*)(ws + o);   o += (size_t)(N_NODES + 1) * 4 + 252; o &= ~(size_t)255;
    int*   cursor  = (int*)(ws + o);   o += (size_t)N_NODES * 4;
    int*   eids    = (int*)(ws + o);   o += (size_t)E_EDGES * 4;
    float* attn_o  = (float*)(ws + o); o += szRow;
    float* x1      = (float*)(ws + o); o += szRow;                 // ~213 MB total
    float* h2 = h_buf;           // alias: h dead after QKV
    float* f1 = Q;               // alias: Q/K/V/sexp dead after message kernel (needs 102.4MB, has 128MB)

    hipMemsetAsync(asum, 0, (size_t)N_NODES * NH * 4, stream);
    hipMemsetAsync(counts, 0, (size_t)N_NODES * 4, stream);

    // LN1
    ln_kernel<<<(N_NODES + 3) / 4, 256, 0, stream>>>(x, g1, be1, h_buf, N_NODES);
    // QKV projections
    dim3 g128(N_NODES / 16, 1);
    gemm_kernel<128><<<g128, 256, 0, stream>>>(h_buf, Wq, bq, nullptr, Q, 128, 0);
    gemm_kernel<128><<<g128, 256, 0, stream>>>(h_buf, Wk, bk, nullptr, Km, 128, 0);
    gemm_kernel<128><<<g128, 256, 0, stream>>>(h_buf, Wv, bv, nullptr, V, 128, 0);
    // Edge scores + attn_sum
    edge_score_kernel<<<(E_EDGES * NH) / 256, 256, 0, stream>>>(ei, attr, Q, Km, ebt, sexp, asum);
    // CSR by dst
    count_kernel<<<(E_EDGES + 255) / 256, 256, 0, stream>>>(ei, counts);
    scan_kernel<<<1, 1024, 0, stream>>>(counts, offs, cursor);
    fill_kernel<<<(E_EDGES + 255) / 256, 256, 0, stream>>>(ei, cursor, eids);
    // Aggregate messages
    message_kernel<<<N_NODES, 128, 0, stream>>>(ei, offs, eids, sexp, asum, V, attn_o);
    // Wo projection + residual(x)
    gemm_kernel<128><<<g128, 256, 0, stream>>>(attn_o, Wo, bo, x, x1, 128, 0);
    // LN2
    ln_kernel<<<(N_NODES + 3) / 4, 256, 0, stream>>>(x1, g2, be2, h2, N_NODES);
    // FFN
    dim3 gffn1(N_NODES / 16, 4);
    gemm_kernel<128><<<gffn1, 256, 0, stream>>>(h2, W1, b1, nullptr, f1, 512, 1);
    gemm_kernel<512><<<g128, 256, 0, stream>>>(f1, W2, b2, x1, out, 128, 0);
}

// Round 2
// 966.340 us; speedup vs baseline: 1.4182x; 1.4182x over previous
//
#include <hip/hip_runtime.h>
#include <hip/hip_bf16.h>

#define N_NODES 50000
#define E_EDGES 1600000
#define HID 128
#define NH 8
#define HD 16

__device__ __forceinline__ float wave_reduce_sum(float v) {
    #pragma unroll
    for (int off = 32; off > 0; off >>= 1) v += __shfl_xor(v, off, 64);
    return v;
}

__device__ __forceinline__ float2 bf2(unsigned int u) {
    float2 r;
    r.x = __uint_as_float(u << 16);
    r.y = __uint_as_float(u & 0xFFFF0000u);
    return r;
}

// ---------------- LayerNorm: one wave per row, float2 per lane ----------------
__global__ __launch_bounds__(256) void ln_kernel(const float* __restrict__ x,
                                                 const float* __restrict__ g,
                                                 const float* __restrict__ b,
                                                 float* __restrict__ out, int n) {
    int wave = threadIdx.x >> 6;
    int lane = threadIdx.x & 63;
    int row = blockIdx.x * 4 + wave;
    if (row >= n) return;
    float2 v = ((const float2*)(x + (size_t)row * HID))[lane];
    float s = wave_reduce_sum(v.x + v.y);
    float mu = s * (1.0f / HID);
    float dx = v.x - mu, dy = v.y - mu;
    float q = wave_reduce_sum(dx * dx + dy * dy);
    float rstd = rsqrtf(q * (1.0f / HID) + 1e-5f);
    float2 gg = ((const float2*)g)[lane];
    float2 bb = ((const float2*)b)[lane];
    float2 o;
    o.x = dx * rstd * gg.x + bb.x;
    o.y = dy * rstd * gg.y + bb.y;
    ((float2*)(out + (size_t)row * HID))[lane] = o;
}

// ---------------- Generic fp32 GEMM: C[M,Nc] = A[M,K]@W[K,Nc] + bias (+res, relu) ---
// OB: 0 -> fp32 out (C), 1 -> bf16 out (Cb)
template <int K, int OB>
__global__ __launch_bounds__(256) void gemm_kernel(const float* __restrict__ A,
                                                   const float* __restrict__ W,
                                                   const float* __restrict__ bias,
                                                   const float* __restrict__ res,
                                                   float* __restrict__ C,
                                                   __hip_bfloat16* __restrict__ Cb,
                                                   int Nc, int relu) {
    __shared__ float4 aLDS[16 * K / 4];
    int row0 = blockIdx.x * 16;
    int col0 = blockIdx.y * 128;
    const float4* A4 = (const float4*)(A + (size_t)row0 * K);
    for (int idx = threadIdx.x; idx < 16 * K / 4; idx += 256) aLDS[idx] = A4[idx];
    __syncthreads();

    int c = col0 + (threadIdx.x & 127);
    int rg = threadIdx.x >> 7;
    float acc[8] = {0.f, 0.f, 0.f, 0.f, 0.f, 0.f, 0.f, 0.f};
    const float* wp = W + c;
    #pragma unroll 4
    for (int kq = 0; kq < K / 4; ++kq) {
        float w0 = wp[(kq * 4 + 0) * Nc];
        float w1 = wp[(kq * 4 + 1) * Nc];
        float w2 = wp[(kq * 4 + 2) * Nc];
        float w3 = wp[(kq * 4 + 3) * Nc];
        #pragma unroll
        for (int i = 0; i < 8; ++i) {
            float4 a = aLDS[(rg * 8 + i) * (K / 4) + kq];
            acc[i] = fmaf(a.x, w0, acc[i]);
            acc[i] = fmaf(a.y, w1, acc[i]);
            acc[i] = fmaf(a.z, w2, acc[i]);
            acc[i] = fmaf(a.w, w3, acc[i]);
        }
    }
    float bv = bias[c];
    #pragma unroll
    for (int i = 0; i < 8; ++i) {
        int r = row0 + rg * 8 + i;
        float v = acc[i] + bv;
        if (relu) v = fmaxf(v, 0.f);
        if (res) v += res[(size_t)r * Nc + c];
        if (OB == 0) C[(size_t)r * Nc + c] = v;
        else Cb[(size_t)r * Nc + c] = __float2bfloat16(v);
    }
}

// ---------------- CSR build ----------------
__global__ __launch_bounds__(256) void count_kernel(const int* __restrict__ ei, int* __restrict__ counts) {
    int e = blockIdx.x * 256 + threadIdx.x;
    if (e < E_EDGES) atomicAdd(&counts[ei[E_EDGES + e]], 1);
}

__global__ __launch_bounds__(1024) void scan_kernel(const int* __restrict__ counts,
                                                    int* __restrict__ offs,
                                                    int* __restrict__ cursor) {
    __shared__ int sdata[1024];
    int tid = threadIdx.x;
    const int CH = (N_NODES + 1023) / 1024;  // 49
    int lo = tid * CH, hi = min(lo + CH, N_NODES);
    int s = 0;
    for (int i = lo; i < hi; ++i) s += counts[i];
    sdata[tid] = s;
    __syncthreads();
    for (int off = 1; off < 1024; off <<= 1) {
        int v = (tid >= off) ? sdata[tid - off] : 0;
        __syncthreads();
        sdata[tid] += v;
        __syncthreads();
    }
    int run = sdata[tid] - s;  // exclusive prefix
    for (int i = lo; i < hi; ++i) {
        offs[i] = run;
        cursor[i] = run;
        run += counts[i];
    }
    if (tid == 0) offs[N_NODES] = E_EDGES;
}

// fill packed = src | (attr<<16), sorted by dst via cursor
__global__ __launch_bounds__(256) void fill_kernel(const int* __restrict__ ei,
                                                   const int* __restrict__ attr,
                                                   int* __restrict__ cursor,
                                                   unsigned int* __restrict__ packed) {
    int e = blockIdx.x * 256 + threadIdx.x;
    if (e < E_EDGES) {
        int dst = ei[E_EDGES + e];
        int pos = atomicAdd(&cursor[dst], 1);
        int a = min(max(attr[e], 0), 12);
        packed[pos] = (unsigned int)ei[e] | ((unsigned int)a << 16);
    }
}

// ---------------- Fused edge phase: scores + exp + weighted V aggregation ----------------
// One block (256 thr = 4 waves) per dst node. Wave w, edge-slot s handle edges
// lo + w*4 + s + it*16. Lane's 'sub' (0..15) covers elems sub*8..sub*8+7 (dwordx4 of bf16).
__global__ __launch_bounds__(256) void fused_attn_kernel(
    const unsigned int* __restrict__ packed,
    const int* __restrict__ offs,
    const float* __restrict__ Q,
    const uint4* __restrict__ K4,   // [N,16] uint4 = [N,128] bf16
    const uint4* __restrict__ V4,
    const float* __restrict__ btab, // [13,8]
    float* __restrict__ out) {
    __shared__ float qLDS[128];
    __shared__ float bLDS[104];
    __shared__ float accLDS[4][16][8];
    __shared__ float wsLDS[4][8];
    const int n = blockIdx.x;
    const int tid = threadIdx.x;
    const int wave = tid >> 6, lane = tid & 63;
    const int slot = lane >> 4, sub = lane & 15;
    const int h = sub >> 1;
    if (tid < 104) bLDS[tid] = btab[tid];
    if (tid < 128) qLDS[tid] = Q[(size_t)n * HID + tid];
    __syncthreads();
    float q[8];
    #pragma unroll
    for (int j = 0; j < 8; ++j) q[j] = qLDS[sub * 8 + j];
    const int lo = offs[n], hi = offs[n + 1];
    const int nit = (hi - lo + 15) >> 4;
    int i = lo + wave * 4 + slot;
    float acc[8] = {0.f, 0.f, 0.f, 0.f, 0.f, 0.f, 0.f, 0.f};
    float wsum = 0.f;
    bool valid = i < hi;
    unsigned int pk = valid ? packed[i] : 0u;
    uint4 kc = K4[(size_t)(pk & 0xFFFFu) * 16 + sub];
    uint4 vc = V4[(size_t)(pk & 0xFFFFu) * 16 + sub];
    for (int it = 0; it < nit; ++it) {
        const int inext = i + 16;
        const bool nvalid = inext < hi;
        const unsigned int pkn = nvalid ? packed[inext] : 0u;
        uint4 kn = K4[(size_t)(pkn & 0xFFFFu) * 16 + sub];
        uint4 vn = V4[(size_t)(pkn & 0xFFFFu) * 16 + sub];
        // score partial over this lane's 8 elems
        float2 k0 = bf2(kc.x), k1 = bf2(kc.y), k2 = bf2(kc.z), k3 = bf2(kc.w);
        float p = q[0] * k0.x + q[1] * k0.y + q[2] * k1.x + q[3] * k1.y
                + q[4] * k2.x + q[5] * k2.y + q[6] * k3.x + q[7] * k3.y;
        p += __shfl_xor(p, 1);  // head pair (lanes differ in bit 0)
        float s = p * 0.25f + bLDS[((pk >> 16) & 0xFu) * 8 + h];
        float w = valid ? __expf(s) : 0.f;
        wsum += w;
        float2 v0 = bf2(vc.x), v1 = bf2(vc.y), v2 = bf2(vc.z), v3 = bf2(vc.w);
        acc[0] = fmaf(w, v0.x, acc[0]);
        acc[1] = fmaf(w, v0.y, acc[1]);
        acc[2] = fmaf(w, v1.x, acc[2]);
        acc[3] = fmaf(w, v1.y, acc[3]);
        acc[4] = fmaf(w, v2.x, acc[4]);
        acc[5] = fmaf(w, v2.y, acc[5]);
        acc[6] = fmaf(w, v3.x, acc[6]);
        acc[7] = fmaf(w, v3.y, acc[7]);
        kc = kn; vc = vn; pk = pkn; valid = nvalid; i = inext;
    }
    // reduce edge-slots (lane bits 4,5) within wave
    #pragma unroll
    for (int j = 0; j < 8; ++j) {
        acc[j] += __shfl_xor(acc[j], 16);
        acc[j] += __shfl_xor(acc[j], 32);
    }
    wsum += __shfl_xor(wsum, 16);
    wsum += __shfl_xor(wsum, 32);
    if (slot == 0) {
        #pragma unroll
        for (int j = 0; j < 8; ++j) accLDS[wave][sub][j] = acc[j];
        if ((sub & 1) == 0) wsLDS[wave][h] = wsum;
    }
    __syncthreads();
    if (tid < 128) {
        const int c = tid >> 3, j = tid & 7;
        float s = accLDS[0][c][j] + accLDS[1][c][j] + accLDS[2][c][j] + accLDS[3][c][j];
        const int hh = tid >> 4;
        float ws = wsLDS[0][hh] + wsLDS[1][hh] + wsLDS[2][hh] + wsLDS[3][hh];
        out[(size_t)n * HID + tid] = s / (ws + 1e-8f);
    }
}

extern "C" void kernel_launch(void* const* d_in, const int* in_sizes, int n_in,
                              void* d_out, int out_size, void* d_ws, size_t ws_size,
                              hipStream_t stream) {
    const float* x    = (const float*)d_in[0];
    const int*   ei   = (const int*)d_in[1];
    const int*   attr = (const int*)d_in[2];
    const float* Wq   = (const float*)d_in[3];
    const float* bq   = (const float*)d_in[4];
    const float* Wk   = (const float*)d_in[5];
    const float* bk   = (const float*)d_in[6];
    const float* Wv   = (const float*)d_in[7];
    const float* bv   = (const float*)d_in[8];
    const float* Wo   = (const float*)d_in[9];
    const float* bo   = (const float*)d_in[10];
    const float* ebt  = (const float*)d_in[11];
    const float* W1   = (const float*)d_in[12];
    const float* b1   = (const float*)d_in[13];
    const float* W2   = (const float*)d_in[14];
    const float* b2   = (const float*)d_in[15];
    const float* g1   = (const float*)d_in[16];
    const float* be1  = (const float*)d_in[17];
    const float* g2   = (const float*)d_in[18];
    const float* be2  = (const float*)d_in[19];
    float* out = (float*)d_out;

    char* ws = (char*)d_ws;
    const size_t szRow  = (size_t)N_NODES * HID * 4;        // 25.6 MB
    const size_t szRowB = (size_t)N_NODES * HID * 2;        // 12.8 MB
    const size_t ALIGN = 256;
    #define ALN(v) (((v) + ALIGN - 1) & ~(ALIGN - 1))
    size_t o = 0;
    float* h_buf = (float*)(ws + o); o += szRow;
    size_t region = o;                                      // f1 aliases from here
    float* Q      = (float*)(ws + o); o += szRow;
    __hip_bfloat16* Kb = (__hip_bfloat16*)(ws + o); o += szRowB;
    __hip_bfloat16* Vb = (__hip_bfloat16*)(ws + o); o += szRowB;
    unsigned int* packed = (unsigned int*)(ws + o); o += (size_t)E_EDGES * 4;
    int* counts = (int*)(ws + o); o = ALN(o + (size_t)N_NODES * 4);
    int* offs   = (int*)(ws + o); o = ALN(o + (size_t)(N_NODES + 1) * 4);
    int* cursor = (int*)(ws + o); o = ALN(o + (size_t)N_NODES * 4);
    float* attn_o = (float*)(ws + o); o += szRow;
    // pad region so f1 (N x 512 f32 = 102.4MB) fits without touching x1
    size_t f1_end = region + (size_t)N_NODES * 512 * 4;
    if (o < f1_end) o = f1_end;
    float* x1 = (float*)(ws + o); o += szRow;               // total ~154 MB
    float* h2 = h_buf;   // alias: h dead after QKV
    float* f1 = (float*)(ws + region);  // alias: Q/K/V/packed/CSR/attn_o dead at FFN time

    hipMemsetAsync(counts, 0, (size_t)N_NODES * 4, stream);

    // CSR build (independent of projections)
    count_kernel<<<(E_EDGES + 255) / 256, 256, 0, stream>>>(ei, counts);
    scan_kernel<<<1, 1024, 0, stream>>>(counts, offs, cursor);
    fill_kernel<<<(E_EDGES + 255) / 256, 256, 0, stream>>>(ei, attr, cursor, packed);

    // LN1 + QKV projections (Q fp32, K/V bf16)
    ln_kernel<<<(N_NODES + 3) / 4, 256, 0, stream>>>(x, g1, be1, h_buf, N_NODES);
    dim3 g128(N_NODES / 16, 1);
    gemm_kernel<128, 0><<<g128, 256, 0, stream>>>(h_buf, Wq, bq, nullptr, Q, nullptr, 128, 0);
    gemm_kernel<128, 1><<<g128, 256, 0, stream>>>(h_buf, Wk, bk, nullptr, nullptr, Kb, 128, 0);
    gemm_kernel<128, 1><<<g128, 256, 0, stream>>>(h_buf, Wv, bv, nullptr, nullptr, Vb, 128, 0);

    // Fused edge phase
    fused_attn_kernel<<<N_NODES, 256, 0, stream>>>(packed, offs, Q,
                                                   (const uint4*)Kb, (const uint4*)Vb,
                                                   ebt, attn_o);

    // Wo projection + residual(x)
    gemm_kernel<128, 0><<<g128, 256, 0, stream>>>(attn_o, Wo, bo, x, x1, nullptr, 128, 0);
    // LN2
    ln_kernel<<<(N_NODES + 3) / 4, 256, 0, stream>>>(x1, g2, be2, h2, N_NODES);
    // FFN
    dim3 gffn1(N_NODES / 16, 4);
    gemm_kernel<128, 0><<<gffn1, 256, 0, stream>>>(h2, W1, b1, nullptr, f1, nullptr, 512, 1);
    gemm_kernel<512, 0><<<g128, 256, 0, stream>>>(f1, W2, b2, x1, out, nullptr, 128, 0);
}

// Round 3
// 616.662 us; speedup vs baseline: 2.2224x; 1.5670x over previous
//
#include <hip/hip_runtime.h>
#include <hip/hip_bf16.h>

#define N_NODES 50000
#define E_EDGES 1600000
#define HID 128
#define NH 8
#define HD 16

using short8 = __attribute__((ext_vector_type(8))) short;
using f32x4  = __attribute__((ext_vector_type(4))) float;

__device__ __forceinline__ float wave_reduce_sum(float v) {
    #pragma unroll
    for (int off = 32; off > 0; off >>= 1) v += __shfl_xor(v, off, 64);
    return v;
}

__device__ __forceinline__ float2 bf2(unsigned int u) {
    float2 r;
    r.x = __uint_as_float(u << 16);
    r.y = __uint_as_float(u & 0xFFFF0000u);
    return r;
}

// ---------------- LayerNorm: one wave per row, float2 per lane, bf16 out ----------------
__global__ __launch_bounds__(256) void ln_kernel(const float* __restrict__ x,
                                                 const float* __restrict__ g,
                                                 const float* __restrict__ b,
                                                 __hip_bfloat16* __restrict__ out, int n) {
    int wave = threadIdx.x >> 6;
    int lane = threadIdx.x & 63;
    int row = blockIdx.x * 4 + wave;
    if (row >= n) return;
    float2 v = ((const float2*)(x + (size_t)row * HID))[lane];
    float s = wave_reduce_sum(v.x + v.y);
    float mu = s * (1.0f / HID);
    float dx = v.x - mu, dy = v.y - mu;
    float q = wave_reduce_sum(dx * dx + dy * dy);
    float rstd = rsqrtf(q * (1.0f / HID) + 1e-5f);
    float2 gg = ((const float2*)g)[lane];
    float2 bb = ((const float2*)b)[lane];
    __hip_bfloat162 o;
    o.x = __float2bfloat16(dx * rstd * gg.x + bb.x);
    o.y = __float2bfloat16(dy * rstd * gg.y + bb.y);
    ((__hip_bfloat162*)(out + (size_t)row * HID))[lane] = o;
}

// ---------------- W convert+transpose: Wt[n][k] = bf16(W[k][n]) ----------------
__global__ __launch_bounds__(256) void wcvt_kernel(const float* __restrict__ W,
                                                   __hip_bfloat16* __restrict__ Wt,
                                                   int K, int N) {
    int t = blockIdx.x * 256 + threadIdx.x;
    if (t < K * N) {
        int n = t / K, k = t - n * K;
        Wt[t] = __float2bfloat16(W[(size_t)k * N + n]);
    }
}

// ---------------- MFMA GEMM: C[M,NC] = A[M,K](bf16) @ Wt[NC,K](bf16)^T + bias ----------
// block 256 = 4 waves; tile 64 rows x 128 cols; wave w owns rows w*16..+15 (8 col frags).
// K chunked at 128. LDS XOR-swizzled (seg ^ row&7) so ds_read_b128 frags are ~2-way.
template <int K, int OB>
__global__ __launch_bounds__(256) void gemm_mfma(const __hip_bfloat16* __restrict__ A,
                                                 const __hip_bfloat16* __restrict__ Wt,
                                                 const float* __restrict__ bias,
                                                 const float* __restrict__ res,
                                                 float* __restrict__ C,
                                                 __hip_bfloat16* __restrict__ Cb,
                                                 int M, int NC, int relu) {
    __shared__ short8 smem[1024 + 2048];  // A: 64x128 bf16 (16KB), B: 128x128 bf16 (32KB)
    const int row0 = blockIdx.x * 64;
    const int col0 = blockIdx.y * 128;
    const int tid = threadIdx.x;
    const int w = tid >> 6, l = tid & 63;
    const int lr = l & 15, hi = l >> 4;
    f32x4 acc[8] = {};
    for (int kk = 0; kk < K / 128; ++kk) {
        #pragma unroll
        for (int it = 0; it < 4; ++it) {
            int idx = tid + it * 256;
            int r = idx >> 4, s = idx & 15;
            int gr = row0 + r; if (gr >= M) gr = M - 1;
            short8 v = *(const short8*)(A + (size_t)gr * K + kk * 128 + s * 8);
            smem[r * 16 + (s ^ (r & 7))] = v;
        }
        #pragma unroll
        for (int it = 0; it < 8; ++it) {
            int idx = tid + it * 256;
            int r = idx >> 4, s = idx & 15;
            short8 v = *(const short8*)(Wt + (size_t)(col0 + r) * K + kk * 128 + s * 8);
            smem[1024 + r * 16 + (s ^ (r & 7))] = v;
        }
        __syncthreads();
        const int ar = w * 16 + lr;
        #pragma unroll
        for (int ks = 0; ks < 4; ++ks) {
            int s = ks * 4 + hi;
            short8 a = smem[ar * 16 + (s ^ (ar & 7))];
            #pragma unroll
            for (int f = 0; f < 8; ++f) {
                int br = f * 16 + lr;
                short8 b = smem[1024 + br * 16 + (s ^ (br & 7))];
                acc[f] = __builtin_amdgcn_mfma_f32_16x16x32_bf16(a, b, acc[f], 0, 0, 0);
            }
        }
        __syncthreads();
    }
    #pragma unroll
    for (int f = 0; f < 8; ++f) {
        int c = col0 + f * 16 + lr;
        float bv = bias[c];
        #pragma unroll
        for (int j = 0; j < 4; ++j) {
            int r = row0 + w * 16 + hi * 4 + j;
            if (r < M) {
                float v = acc[f][j] + bv;
                if (relu) v = fmaxf(v, 0.f);
                if (res) v += res[(size_t)r * NC + c];
                if (OB == 0) C[(size_t)r * NC + c] = v;
                else Cb[(size_t)r * NC + c] = __float2bfloat16(v);
            }
        }
    }
}

// ---------------- CSR build ----------------
__global__ __launch_bounds__(256) void count_kernel(const int* __restrict__ ei, int* __restrict__ counts) {
    int e = blockIdx.x * 256 + threadIdx.x;
    if (e < E_EDGES) atomicAdd(&counts[ei[E_EDGES + e]], 1);
}

__global__ __launch_bounds__(1024) void scan_kernel(const int* __restrict__ counts,
                                                    int* __restrict__ offs,
                                                    int* __restrict__ cursor) {
    __shared__ int sdata[1024];
    int tid = threadIdx.x;
    const int CH = (N_NODES + 1023) / 1024;  // 49
    int lo = tid * CH, hi = min(lo + CH, N_NODES);
    int s = 0;
    for (int i = lo; i < hi; ++i) s += counts[i];
    sdata[tid] = s;
    __syncthreads();
    for (int off = 1; off < 1024; off <<= 1) {
        int v = (tid >= off) ? sdata[tid - off] : 0;
        __syncthreads();
        sdata[tid] += v;
        __syncthreads();
    }
    int run = sdata[tid] - s;  // exclusive prefix
    for (int i = lo; i < hi; ++i) {
        offs[i] = run;
        cursor[i] = run;
        run += counts[i];
    }
    if (tid == 0) offs[N_NODES] = E_EDGES;
}

// fill packed = src | (attr<<16), sorted by dst via cursor
__global__ __launch_bounds__(256) void fill_kernel(const int* __restrict__ ei,
                                                   const int* __restrict__ attr,
                                                   int* __restrict__ cursor,
                                                   unsigned int* __restrict__ packed) {
    int e = blockIdx.x * 256 + threadIdx.x;
    if (e < E_EDGES) {
        int dst = ei[E_EDGES + e];
        int pos = atomicAdd(&cursor[dst], 1);
        int a = min(max(attr[e], 0), 12);
        packed[pos] = (unsigned int)ei[e] | ((unsigned int)a << 16);
    }
}

// ---------------- Fused edge phase: scores + exp + weighted V aggregation ----------------
__global__ __launch_bounds__(256) void fused_attn_kernel(
    const unsigned int* __restrict__ packed,
    const int* __restrict__ offs,
    const float* __restrict__ Q,
    const uint4* __restrict__ K4,   // [N,16] uint4 = [N,128] bf16
    const uint4* __restrict__ V4,
    const float* __restrict__ btab, // [13,8]
    __hip_bfloat16* __restrict__ out) {
    __shared__ float qLDS[128];
    __shared__ float bLDS[104];
    __shared__ float accLDS[4][16][8];
    __shared__ float wsLDS[4][8];
    const int n = blockIdx.x;
    const int tid = threadIdx.x;
    const int wave = tid >> 6, lane = tid & 63;
    const int slot = lane >> 4, sub = lane & 15;
    const int h = sub >> 1;
    if (tid < 104) bLDS[tid] = btab[tid];
    if (tid < 128) qLDS[tid] = Q[(size_t)n * HID + tid];
    __syncthreads();
    float q[8];
    #pragma unroll
    for (int j = 0; j < 8; ++j) q[j] = qLDS[sub * 8 + j];
    const int lo = offs[n], hi = offs[n + 1];
    const int nit = (hi - lo + 15) >> 4;
    int i = lo + wave * 4 + slot;
    float acc[8] = {0.f, 0.f, 0.f, 0.f, 0.f, 0.f, 0.f, 0.f};
    float wsum = 0.f;
    bool valid = i < hi;
    unsigned int pk = valid ? packed[i] : 0u;
    uint4 kc = K4[(size_t)(pk & 0xFFFFu) * 16 + sub];
    uint4 vc = V4[(size_t)(pk & 0xFFFFu) * 16 + sub];
    for (int it = 0; it < nit; ++it) {
        const int inext = i + 16;
        const bool nvalid = inext < hi;
        const unsigned int pkn = nvalid ? packed[inext] : 0u;
        uint4 kn = K4[(size_t)(pkn & 0xFFFFu) * 16 + sub];
        uint4 vn = V4[(size_t)(pkn & 0xFFFFu) * 16 + sub];
        float2 k0 = bf2(kc.x), k1 = bf2(kc.y), k2 = bf2(kc.z), k3 = bf2(kc.w);
        float p = q[0] * k0.x + q[1] * k0.y + q[2] * k1.x + q[3] * k1.y
                + q[4] * k2.x + q[5] * k2.y + q[6] * k3.x + q[7] * k3.y;
        p += __shfl_xor(p, 1);  // head pair (lanes differ in bit 0)
        float s = p * 0.25f + bLDS[((pk >> 16) & 0xFu) * 8 + h];
        float w = valid ? __expf(s) : 0.f;
        wsum += w;
        float2 v0 = bf2(vc.x), v1 = bf2(vc.y), v2 = bf2(vc.z), v3 = bf2(vc.w);
        acc[0] = fmaf(w, v0.x, acc[0]);
        acc[1] = fmaf(w, v0.y, acc[1]);
        acc[2] = fmaf(w, v1.x, acc[2]);
        acc[3] = fmaf(w, v1.y, acc[3]);
        acc[4] = fmaf(w, v2.x, acc[4]);
        acc[5] = fmaf(w, v2.y, acc[5]);
        acc[6] = fmaf(w, v3.x, acc[6]);
        acc[7] = fmaf(w, v3.y, acc[7]);
        kc = kn; vc = vn; pk = pkn; valid = nvalid; i = inext;
    }
    #pragma unroll
    for (int j = 0; j < 8; ++j) {
        acc[j] += __shfl_xor(acc[j], 16);
        acc[j] += __shfl_xor(acc[j], 32);
    }
    wsum += __shfl_xor(wsum, 16);
    wsum += __shfl_xor(wsum, 32);
    if (slot == 0) {
        #pragma unroll
        for (int j = 0; j < 8; ++j) accLDS[wave][sub][j] = acc[j];
        if ((sub & 1) == 0) wsLDS[wave][h] = wsum;
    }
    __syncthreads();
    if (tid < 128) {
        const int c = tid >> 3, j = tid & 7;
        float s = accLDS[0][c][j] + accLDS[1][c][j] + accLDS[2][c][j] + accLDS[3][c][j];
        const int hh = tid >> 4;
        float ws = wsLDS[0][hh] + wsLDS[1][hh] + wsLDS[2][hh] + wsLDS[3][hh];
        out[(size_t)n * HID + tid] = __float2bfloat16(s / (ws + 1e-8f));
    }
}

extern "C" void kernel_launch(void* const* d_in, const int* in_sizes, int n_in,
                              void* d_out, int out_size, void* d_ws, size_t ws_size,
                              hipStream_t stream) {
    const float* x    = (const float*)d_in[0];
    const int*   ei   = (const int*)d_in[1];
    const int*   attr = (const int*)d_in[2];
    const float* Wq   = (const float*)d_in[3];
    const float* bq   = (const float*)d_in[4];
    const float* Wk   = (const float*)d_in[5];
    const float* bk   = (const float*)d_in[6];
    const float* Wv   = (const float*)d_in[7];
    const float* bv   = (const float*)d_in[8];
    const float* Wo   = (const float*)d_in[9];
    const float* bo   = (const float*)d_in[10];
    const float* ebt  = (const float*)d_in[11];
    const float* W1   = (const float*)d_in[12];
    const float* b1   = (const float*)d_in[13];
    const float* W2   = (const float*)d_in[14];
    const float* b2   = (const float*)d_in[15];
    const float* g1   = (const float*)d_in[16];
    const float* be1  = (const float*)d_in[17];
    const float* g2   = (const float*)d_in[18];
    const float* be2  = (const float*)d_in[19];
    float* out = (float*)d_out;

    char* ws = (char*)d_ws;
    const size_t szRowF = (size_t)N_NODES * HID * 4;   // 25.6 MB
    const size_t szRowB = (size_t)N_NODES * HID * 2;   // 12.8 MB
    const size_t ALIGN = 256;
    #define ALN(v) (((v) + ALIGN - 1) & ~(ALIGN - 1))
    size_t o = 0;
    __hip_bfloat16* h_buf = (__hip_bfloat16*)(ws + o); o += szRowB;
    size_t region = o;                                  // f1 aliases Q..Vb (51.2MB exactly)
    float* Q = (float*)(ws + o); o += szRowF;
    __hip_bfloat16* Kb = (__hip_bfloat16*)(ws + o); o += szRowB;
    __hip_bfloat16* Vb = (__hip_bfloat16*)(ws + o); o += szRowB;
    unsigned int* packed = (unsigned int*)(ws + o); o += (size_t)E_EDGES * 4;
    int* counts = (int*)(ws + o); o = ALN(o + (size_t)N_NODES * 4);
    int* offs   = (int*)(ws + o); o = ALN(o + (size_t)(N_NODES + 1) * 4);
    int* cursor = (int*)(ws + o); o = ALN(o + (size_t)N_NODES * 4);
    __hip_bfloat16* attn_ob = (__hip_bfloat16*)(ws + o); o += szRowB;
    float* x1 = (float*)(ws + o); o += szRowF;
    __hip_bfloat16* Wqt = (__hip_bfloat16*)(ws + o); o += 128 * 128 * 2;
    __hip_bfloat16* Wkt = (__hip_bfloat16*)(ws + o); o += 128 * 128 * 2;
    __hip_bfloat16* Wvt = (__hip_bfloat16*)(ws + o); o += 128 * 128 * 2;
    __hip_bfloat16* Wot = (__hip_bfloat16*)(ws + o); o += 128 * 128 * 2;
    __hip_bfloat16* W1t = (__hip_bfloat16*)(ws + o); o += 512 * 128 * 2;
    __hip_bfloat16* W2t = (__hip_bfloat16*)(ws + o); o += 128 * 512 * 2;  // ~110 MB total
    __hip_bfloat16* h2 = h_buf;                        // alias: h dead after QKV
    __hip_bfloat16* f1 = (__hip_bfloat16*)(ws + region);  // alias: Q/K/V dead at FFN time

    hipMemsetAsync(counts, 0, (size_t)N_NODES * 4, stream);

    // CSR build
    count_kernel<<<(E_EDGES + 255) / 256, 256, 0, stream>>>(ei, counts);
    scan_kernel<<<1, 1024, 0, stream>>>(counts, offs, cursor);
    fill_kernel<<<(E_EDGES + 255) / 256, 256, 0, stream>>>(ei, attr, cursor, packed);

    // Weight conversions
    wcvt_kernel<<<64, 256, 0, stream>>>(Wq, Wqt, 128, 128);
    wcvt_kernel<<<64, 256, 0, stream>>>(Wk, Wkt, 128, 128);
    wcvt_kernel<<<64, 256, 0, stream>>>(Wv, Wvt, 128, 128);
    wcvt_kernel<<<64, 256, 0, stream>>>(Wo, Wot, 128, 128);
    wcvt_kernel<<<256, 256, 0, stream>>>(W1, W1t, 128, 512);
    wcvt_kernel<<<256, 256, 0, stream>>>(W2, W2t, 512, 128);

    // LN1 + QKV projections (Q fp32, K/V bf16)
    ln_kernel<<<(N_NODES + 3) / 4, 256, 0, stream>>>(x, g1, be1, h_buf, N_NODES);
    dim3 gm((N_NODES + 63) / 64, 1);
    gemm_mfma<128, 0><<<gm, 256, 0, stream>>>(h_buf, Wqt, bq, nullptr, Q, nullptr, N_NODES, 128, 0);
    gemm_mfma<128, 1><<<gm, 256, 0, stream>>>(h_buf, Wkt, bk, nullptr, nullptr, Kb, N_NODES, 128, 0);
    gemm_mfma<128, 1><<<gm, 256, 0, stream>>>(h_buf, Wvt, bv, nullptr, nullptr, Vb, N_NODES, 128, 0);

    // Fused edge phase
    fused_attn_kernel<<<N_NODES, 256, 0, stream>>>(packed, offs, Q,
                                                   (const uint4*)Kb, (const uint4*)Vb,
                                                   ebt, attn_ob);

    // Wo projection + residual(x) -> x1 fp32
    gemm_mfma<128, 0><<<gm, 256, 0, stream>>>(attn_ob, Wot, bo, x, x1, nullptr, N_NODES, 128, 0);
    // LN2 -> h2 bf16
    ln_kernel<<<(N_NODES + 3) / 4, 256, 0, stream>>>(x1, g2, be2, h2, N_NODES);
    // FFN
    dim3 gf1((N_NODES + 63) / 64, 4);
    gemm_mfma<128, 1><<<gf1, 256, 0, stream>>>(h2, W1t, b1, nullptr, nullptr, f1, N_NODES, 512, 1);
    gemm_mfma<512, 0><<<gm, 256, 0, stream>>>(f1, W2t, b2, x1, out, nullptr, N_NODES, 128, 0);
}

// Round 4
// 340.173 us; speedup vs baseline: 4.0288x; 1.8128x over previous
//
#include <hip/hip_runtime.h>
#include <hip/hip_bf16.h>

#define N_NODES 50000
#define E_EDGES 1600000
#define HID 128
#define NH 8
#define HD 16

#define NBKT 196        // ceil(50000/256) buckets of 256 dst nodes
#define BKT_CAP 9216    // mean 8192, sd ~90 -> +11 sigma headroom
#define CHUNK_A 4096
#define EPT 16          // edges per thread in binA (256 thr * 16)

using short8 = __attribute__((ext_vector_type(8))) short;
using f32x4  = __attribute__((ext_vector_type(4))) float;

__device__ __forceinline__ float wave_reduce_sum(float v) {
    #pragma unroll
    for (int off = 32; off > 0; off >>= 1) v += __shfl_xor(v, off, 64);
    return v;
}

__device__ __forceinline__ float2 bf2(unsigned int u) {
    float2 r;
    r.x = __uint_as_float(u << 16);
    r.y = __uint_as_float(u & 0xFFFF0000u);
    return r;
}

// ---------------- LayerNorm: one wave per row, float2 per lane, bf16 out ----------------
__global__ __launch_bounds__(256) void ln_kernel(const float* __restrict__ x,
                                                 const float* __restrict__ g,
                                                 const float* __restrict__ b,
                                                 __hip_bfloat16* __restrict__ out, int n) {
    int wave = threadIdx.x >> 6;
    int lane = threadIdx.x & 63;
    int row = blockIdx.x * 4 + wave;
    if (row >= n) return;
    float2 v = ((const float2*)(x + (size_t)row * HID))[lane];
    float s = wave_reduce_sum(v.x + v.y);
    float mu = s * (1.0f / HID);
    float dx = v.x - mu, dy = v.y - mu;
    float q = wave_reduce_sum(dx * dx + dy * dy);
    float rstd = rsqrtf(q * (1.0f / HID) + 1e-5f);
    float2 gg = ((const float2*)g)[lane];
    float2 bb = ((const float2*)b)[lane];
    __hip_bfloat162 o;
    o.x = __float2bfloat16(dx * rstd * gg.x + bb.x);
    o.y = __float2bfloat16(dy * rstd * gg.y + bb.y);
    ((__hip_bfloat162*)(out + (size_t)row * HID))[lane] = o;
}

// ---------------- All weight converts in one launch: Wt[n][k] = bf16(W[k][n]) --------
__global__ __launch_bounds__(256) void wcvt_all(const float* __restrict__ Wq,
                                                const float* __restrict__ Wk,
                                                const float* __restrict__ Wv,
                                                const float* __restrict__ Wo,
                                                const float* __restrict__ W1,
                                                const float* __restrict__ W2,
                                                __hip_bfloat16* __restrict__ Wqt,
                                                __hip_bfloat16* __restrict__ Wkt,
                                                __hip_bfloat16* __restrict__ Wvt,
                                                __hip_bfloat16* __restrict__ Wot,
                                                __hip_bfloat16* __restrict__ W1t,
                                                __hip_bfloat16* __restrict__ W2t) {
    int t = blockIdx.x * 256 + threadIdx.x;
    const float* W; __hip_bfloat16* Wt; int K, N, idx;
    if (t < 65536) {
        int which = t >> 14; idx = t & 16383; K = 128; N = 128;
        W  = which == 0 ? Wq  : which == 1 ? Wk  : which == 2 ? Wv  : Wo;
        Wt = which == 0 ? Wqt : which == 1 ? Wkt : which == 2 ? Wvt : Wot;
    } else if (t < 131072) { idx = t - 65536;  K = 128; N = 512; W = W1; Wt = W1t; }
    else if (t < 196608)   { idx = t - 131072; K = 512; N = 128; W = W2; Wt = W2t; }
    else return;
    int n = idx / K, k = idx - n * K;
    Wt[idx] = __float2bfloat16(W[(size_t)k * N + n]);
}

// ---------------- MFMA GEMM: C[M,NC] = A[M,K](bf16) @ Wt[NC,K](bf16)^T + bias ----------
template <int K, int OB>
__global__ __launch_bounds__(256) void gemm_mfma(const __hip_bfloat16* __restrict__ A,
                                                 const __hip_bfloat16* __restrict__ Wt,
                                                 const float* __restrict__ bias,
                                                 const float* __restrict__ res,
                                                 float* __restrict__ C,
                                                 __hip_bfloat16* __restrict__ Cb,
                                                 int M, int NC, int relu) {
    __shared__ short8 smem[1024 + 2048];  // A: 64x128 bf16 (16KB), B: 128x128 bf16 (32KB)
    const int row0 = blockIdx.x * 64;
    const int col0 = blockIdx.y * 128;
    const int tid = threadIdx.x;
    const int w = tid >> 6, l = tid & 63;
    const int lr = l & 15, hi = l >> 4;
    f32x4 acc[8] = {};
    for (int kk = 0; kk < K / 128; ++kk) {
        #pragma unroll
        for (int it = 0; it < 4; ++it) {
            int idx = tid + it * 256;
            int r = idx >> 4, s = idx & 15;
            int gr = row0 + r; if (gr >= M) gr = M - 1;
            short8 v = *(const short8*)(A + (size_t)gr * K + kk * 128 + s * 8);
            smem[r * 16 + (s ^ (r & 7))] = v;
        }
        #pragma unroll
        for (int it = 0; it < 8; ++it) {
            int idx = tid + it * 256;
            int r = idx >> 4, s = idx & 15;
            short8 v = *(const short8*)(Wt + (size_t)(col0 + r) * K + kk * 128 + s * 8);
            smem[1024 + r * 16 + (s ^ (r & 7))] = v;
        }
        __syncthreads();
        const int ar = w * 16 + lr;
        #pragma unroll
        for (int ks = 0; ks < 4; ++ks) {
            int s = ks * 4 + hi;
            short8 a = smem[ar * 16 + (s ^ (ar & 7))];
            #pragma unroll
            for (int f = 0; f < 8; ++f) {
                int br = f * 16 + lr;
                short8 b = smem[1024 + br * 16 + (s ^ (br & 7))];
                acc[f] = __builtin_amdgcn_mfma_f32_16x16x32_bf16(a, b, acc[f], 0, 0, 0);
            }
        }
        __syncthreads();
    }
    #pragma unroll
    for (int f = 0; f < 8; ++f) {
        int c = col0 + f * 16 + lr;
        float bv = bias[c];
        #pragma unroll
        for (int j = 0; j < 4; ++j) {
            int r = row0 + w * 16 + hi * 4 + j;
            if (r < M) {
                float v = acc[f][j] + bv;
                if (relu) v = fmaxf(v, 0.f);
                if (res) v += res[(size_t)r * NC + c];
                if (OB == 0) C[(size_t)r * NC + c] = v;
                else Cb[(size_t)r * NC + c] = __float2bfloat16(v);
            }
        }
    }
}

// ---------------- binA: bucket edges (bucket = dst>>8) with LDS staging -------------
// temp value layout: src(16b) | attr(4b)<<16 | (dst&255)<<20
__global__ __launch_bounds__(256) void binA_kernel(const int* __restrict__ ei,
                                                   const int* __restrict__ attr,
                                                   int* __restrict__ bcur,
                                                   unsigned int* __restrict__ temp) {
    __shared__ unsigned int sval[CHUNK_A];
    __shared__ unsigned short sbkt[CHUNK_A];
    __shared__ int hist[NBKT];
    __shared__ int lofs[NBKT];
    __shared__ int gbase[NBKT];
    __shared__ int lcur[NBKT];
    __shared__ int sc[256];
    const int tid = threadIdx.x;
    const int e0 = blockIdx.x * CHUNK_A;
    const int n = min(CHUNK_A, E_EDGES - e0);
    for (int i = tid; i < NBKT; i += 256) hist[i] = 0;
    __syncthreads();
    unsigned int v[EPT];
    short bk[EPT];
    #pragma unroll
    for (int j = 0; j < EPT; ++j) {
        int i = tid + j * 256;
        bk[j] = -1;
        v[j] = 0;
        if (i < n) {
            int e = e0 + i;
            int src = ei[e];
            int dst = ei[E_EDGES + e];
            int a = attr[e]; a = min(max(a, 0), 12);
            v[j] = (unsigned)src | ((unsigned)a << 16) | ((unsigned)(dst & 255) << 20);
            int b = dst >> 8;
            bk[j] = (short)b;
            atomicAdd(&hist[b], 1);
        }
    }
    __syncthreads();
    sc[tid] = (tid < NBKT) ? hist[tid] : 0;
    __syncthreads();
    for (int off = 1; off < 256; off <<= 1) {
        int x = (tid >= off) ? sc[tid - off] : 0;
        __syncthreads();
        sc[tid] += x;
        __syncthreads();
    }
    if (tid < NBKT) {
        int h = hist[tid];
        lofs[tid] = sc[tid] - h;     // exclusive prefix within block
        lcur[tid] = 0;
        gbase[tid] = h ? atomicAdd(&bcur[tid], h) : 0;
    }
    __syncthreads();
    #pragma unroll
    for (int j = 0; j < EPT; ++j) {
        if (bk[j] >= 0) {
            int p = lofs[bk[j]] + atomicAdd(&lcur[bk[j]], 1);
            sval[p] = v[j];
            sbkt[p] = (unsigned short)bk[j];
        }
    }
    __syncthreads();
    for (int i = tid; i < n; i += 256) {
        int b = sbkt[i];
        temp[(size_t)b * BKT_CAP + gbase[b] + (i - lofs[b])] = sval[i];
    }
}

// ---------------- binB: per-bucket counting sort by dst low byte; writes offs+packed --
__global__ __launch_bounds__(1024) void binB_kernel(const int* __restrict__ bcur,
                                                    const unsigned int* __restrict__ temp,
                                                    unsigned int* __restrict__ packed,
                                                    int* __restrict__ offs) {
    __shared__ int cnts[256];
    __shared__ int hist[256];
    __shared__ int cur[256];
    const int b = blockIdx.x, tid = threadIdx.x;
    if (tid < 256) {
        cnts[tid] = (tid < NBKT) ? bcur[tid] : 0;
        hist[tid] = 0;
    }
    __syncthreads();
    // inclusive scan over bucket counts (threads 0..255 active, all hit barriers)
    for (int off = 1; off < 256; off <<= 1) {
        int x = 0;
        if (tid < 256 && tid >= off) x = cnts[tid - off];
        __syncthreads();
        if (tid < 256) cnts[tid] += x;
        __syncthreads();
    }
    const int cnt = bcur[b];
    const int start = cnts[b] - cnt;  // exclusive global start of this bucket
    const size_t base = (size_t)b * BKT_CAP;
    for (int i = tid; i < cnt; i += 1024)
        atomicAdd(&hist[(temp[base + i] >> 20) & 255], 1);
    __syncthreads();
    if (tid < 256) cur[tid] = hist[tid];
    __syncthreads();
    for (int off = 1; off < 256; off <<= 1) {
        int x = 0;
        if (tid < 256 && tid >= off) x = cur[tid - off];
        __syncthreads();
        if (tid < 256) cur[tid] += x;
        __syncthreads();
    }
    const int node0 = b * 256;
    if (tid < 256) {
        int excl = cur[tid] - hist[tid];
        cur[tid] = excl;
        int node = node0 + tid;
        if (node < N_NODES) offs[node] = start + excl;
    }
    if (b == NBKT - 1 && tid == 0) offs[N_NODES] = start + cnt;
    __syncthreads();
    for (int i = tid; i < cnt; i += 1024) {
        unsigned int v = temp[base + i];
        int d = (v >> 20) & 255;
        int p = start + atomicAdd(&cur[d], 1);
        packed[p] = v & 0xFFFFFu;   // src | attr<<16
    }
}

// ---------------- Fused edge phase: scores + exp + weighted V aggregation ----------------
__global__ __launch_bounds__(256) void fused_attn_kernel(
    const unsigned int* __restrict__ packed,
    const int* __restrict__ offs,
    const float* __restrict__ Q,
    const uint4* __restrict__ K4,   // [N,16] uint4 = [N,128] bf16
    const uint4* __restrict__ V4,
    const float* __restrict__ btab, // [13,8]
    __hip_bfloat16* __restrict__ out) {
    __shared__ float qLDS[128];
    __shared__ float bLDS[104];
    __shared__ float accLDS[4][16][8];
    __shared__ float wsLDS[4][8];
    const int n = blockIdx.x;
    const int tid = threadIdx.x;
    const int wave = tid >> 6, lane = tid & 63;
    const int slot = lane >> 4, sub = lane & 15;
    const int h = sub >> 1;
    if (tid < 104) bLDS[tid] = btab[tid];
    if (tid < 128) qLDS[tid] = Q[(size_t)n * HID + tid];
    __syncthreads();
    float q[8];
    #pragma unroll
    for (int j = 0; j < 8; ++j) q[j] = qLDS[sub * 8 + j];
    const int lo = offs[n], hi = offs[n + 1];
    const int nit = (hi - lo + 15) >> 4;
    int i = lo + wave * 4 + slot;
    float acc[8] = {0.f, 0.f, 0.f, 0.f, 0.f, 0.f, 0.f, 0.f};
    float wsum = 0.f;
    bool valid = i < hi;
    unsigned int pk = valid ? packed[i] : 0u;
    uint4 kc = K4[(size_t)(pk & 0xFFFFu) * 16 + sub];
    uint4 vc = V4[(size_t)(pk & 0xFFFFu) * 16 + sub];
    for (int it = 0; it < nit; ++it) {
        const int inext = i + 16;
        const bool nvalid = inext < hi;
        const unsigned int pkn = nvalid ? packed[inext] : 0u;
        uint4 kn = K4[(size_t)(pkn & 0xFFFFu) * 16 + sub];
        uint4 vn = V4[(size_t)(pkn & 0xFFFFu) * 16 + sub];
        float2 k0 = bf2(kc.x), k1 = bf2(kc.y), k2 = bf2(kc.z), k3 = bf2(kc.w);
        float p = q[0] * k0.x + q[1] * k0.y + q[2] * k1.x + q[3] * k1.y
                + q[4] * k2.x + q[5] * k2.y + q[6] * k3.x + q[7] * k3.y;
        p += __shfl_xor(p, 1);  // head pair (lanes differ in bit 0)
        float s = p * 0.25f + bLDS[((pk >> 16) & 0xFu) * 8 + h];
        float w = valid ? __expf(s) : 0.f;
        wsum += w;
        float2 v0 = bf2(vc.x), v1 = bf2(vc.y), v2 = bf2(vc.z), v3 = bf2(vc.w);
        acc[0] = fmaf(w, v0.x, acc[0]);
        acc[1] = fmaf(w, v0.y, acc[1]);
        acc[2] = fmaf(w, v1.x, acc[2]);
        acc[3] = fmaf(w, v1.y, acc[3]);
        acc[4] = fmaf(w, v2.x, acc[4]);
        acc[5] = fmaf(w, v2.y, acc[5]);
        acc[6] = fmaf(w, v3.x, acc[6]);
        acc[7] = fmaf(w, v3.y, acc[7]);
        kc = kn; vc = vn; pk = pkn; valid = nvalid; i = inext;
    }
    #pragma unroll
    for (int j = 0; j < 8; ++j) {
        acc[j] += __shfl_xor(acc[j], 16);
        acc[j] += __shfl_xor(acc[j], 32);
    }
    wsum += __shfl_xor(wsum, 16);
    wsum += __shfl_xor(wsum, 32);
    if (slot == 0) {
        #pragma unroll
        for (int j = 0; j < 8; ++j) accLDS[wave][sub][j] = acc[j];
        if ((sub & 1) == 0) wsLDS[wave][h] = wsum;
    }
    __syncthreads();
    if (tid < 128) {
        const int c = tid >> 3, j = tid & 7;
        float s = accLDS[0][c][j] + accLDS[1][c][j] + accLDS[2][c][j] + accLDS[3][c][j];
        const int hh = tid >> 4;
        float ws = wsLDS[0][hh] + wsLDS[1][hh] + wsLDS[2][hh] + wsLDS[3][hh];
        out[(size_t)n * HID + tid] = __float2bfloat16(s / (ws + 1e-8f));
    }
}

extern "C" void kernel_launch(void* const* d_in, const int* in_sizes, int n_in,
                              void* d_out, int out_size, void* d_ws, size_t ws_size,
                              hipStream_t stream) {
    const float* x    = (const float*)d_in[0];
    const int*   ei   = (const int*)d_in[1];
    const int*   attr = (const int*)d_in[2];
    const float* Wq   = (const float*)d_in[3];
    const float* bq   = (const float*)d_in[4];
    const float* Wk   = (const float*)d_in[5];
    const float* bk   = (const float*)d_in[6];
    const float* Wv   = (const float*)d_in[7];
    const float* bv   = (const float*)d_in[8];
    const float* Wo   = (const float*)d_in[9];
    const float* bo   = (const float*)d_in[10];
    const float* ebt  = (const float*)d_in[11];
    const float* W1   = (const float*)d_in[12];
    const float* b1   = (const float*)d_in[13];
    const float* W2   = (const float*)d_in[14];
    const float* b2   = (const float*)d_in[15];
    const float* g1   = (const float*)d_in[16];
    const float* be1  = (const float*)d_in[17];
    const float* g2   = (const float*)d_in[18];
    const float* be2  = (const float*)d_in[19];
    float* out = (float*)d_out;

    char* ws = (char*)d_ws;
    const size_t szRowF = (size_t)N_NODES * HID * 4;   // 25.6 MB
    const size_t szRowB = (size_t)N_NODES * HID * 2;   // 12.8 MB
    const size_t ALIGN = 256;
    #define ALN(v) (((v) + ALIGN - 1) & ~(ALIGN - 1))
    size_t o = 0;
    __hip_bfloat16* h_buf = (__hip_bfloat16*)(ws + o); o += szRowB;
    size_t region = o;                                  // f1 aliases Q..Vb (51.2MB exactly)
    float* Q = (float*)(ws + o); o += szRowF;
    __hip_bfloat16* Kb = (__hip_bfloat16*)(ws + o); o += szRowB;
    __hip_bfloat16* Vb = (__hip_bfloat16*)(ws + o); o += szRowB;
    unsigned int* packed = (unsigned int*)(ws + o); o += (size_t)E_EDGES * 4;
    unsigned int* temp = (unsigned int*)(ws + o); o += (size_t)NBKT * BKT_CAP * 4;
    int* bcur = (int*)(ws + o); o = ALN(o + (size_t)NBKT * 4);
    int* offs = (int*)(ws + o); o = ALN(o + (size_t)(N_NODES + 1) * 4);
    __hip_bfloat16* attn_ob = (__hip_bfloat16*)(ws + o); o += szRowB;
    float* x1 = (float*)(ws + o); o += szRowF;
    __hip_bfloat16* Wqt = (__hip_bfloat16*)(ws + o); o += 128 * 128 * 2;
    __hip_bfloat16* Wkt = (__hip_bfloat16*)(ws + o); o += 128 * 128 * 2;
    __hip_bfloat16* Wvt = (__hip_bfloat16*)(ws + o); o += 128 * 128 * 2;
    __hip_bfloat16* Wot = (__hip_bfloat16*)(ws + o); o += 128 * 128 * 2;
    __hip_bfloat16* W1t = (__hip_bfloat16*)(ws + o); o += 512 * 128 * 2;
    __hip_bfloat16* W2t = (__hip_bfloat16*)(ws + o); o += 128 * 512 * 2;  // ~124 MB total
    __hip_bfloat16* h2 = h_buf;                           // alias: h dead after QKV
    __hip_bfloat16* f1 = (__hip_bfloat16*)(ws + region);  // alias: Q/K/V dead at FFN time

    hipMemsetAsync(bcur, 0, (size_t)NBKT * 4, stream);

    // CSR build: two-level LDS-binned counting sort
    binA_kernel<<<(E_EDGES + CHUNK_A - 1) / CHUNK_A, 256, 0, stream>>>(ei, attr, bcur, temp);
    binB_kernel<<<NBKT, 1024, 0, stream>>>(bcur, temp, packed, offs);

    // Weight conversions (single launch)
    wcvt_all<<<768, 256, 0, stream>>>(Wq, Wk, Wv, Wo, W1, W2, Wqt, Wkt, Wvt, Wot, W1t, W2t);

    // LN1 + QKV projections (Q fp32, K/V bf16)
    ln_kernel<<<(N_NODES + 3) / 4, 256, 0, stream>>>(x, g1, be1, h_buf, N_NODES);
    dim3 gm((N_NODES + 63) / 64, 1);
    gemm_mfma<128, 0><<<gm, 256, 0, stream>>>(h_buf, Wqt, bq, nullptr, Q, nullptr, N_NODES, 128, 0);
    gemm_mfma<128, 1><<<gm, 256, 0, stream>>>(h_buf, Wkt, bk, nullptr, nullptr, Kb, N_NODES, 128, 0);
    gemm_mfma<128, 1><<<gm, 256, 0, stream>>>(h_buf, Wvt, bv, nullptr, nullptr, Vb, N_NODES, 128, 0);

    // Fused edge phase
    fused_attn_kernel<<<N_NODES, 256, 0, stream>>>(packed, offs, Q,
                                                   (const uint4*)Kb, (const uint4*)Vb,
                                                   ebt, attn_ob);

    // Wo projection + residual(x) -> x1 fp32
    gemm_mfma<128, 0><<<gm, 256, 0, stream>>>(attn_ob, Wot, bo, x, x1, nullptr, N_NODES, 128, 0);
    // LN2 -> h2 bf16
    ln_kernel<<<(N_NODES + 3) / 4, 256, 0, stream>>>(x1, g2, be2, h2, N_NODES);
    // FFN
    dim3 gf1((N_NODES + 63) / 64, 4);
    gemm_mfma<128, 1><<<gf1, 256, 0, stream>>>(h2, W1t, b1, nullptr, nullptr, f1, N_NODES, 512, 1);
    gemm_mfma<512, 0><<<gm, 256, 0, stream>>>(f1, W2t, b2, x1, out, nullptr, N_NODES, 128, 0);
}

// Round 5
// 318.807 us; speedup vs baseline: 4.2988x; 1.0670x over previous
//
#include <hip/hip_runtime.h>
#include <hip/hip_bf16.h>

#define N_NODES 50000
#define E_EDGES 1600000
#define HID 128
#define NH 8
#define HD 16

#define NBKT 196        // ceil(50000/256) buckets of 256 dst nodes
#define BKT_CAP 9216    // mean 8192, sd ~90 -> +11 sigma headroom
#define CHUNK_A 4096
#define EPT 16          // edges per thread in binA (256 thr * 16)

using short8 = __attribute__((ext_vector_type(8))) short;
using f32x4  = __attribute__((ext_vector_type(4))) float;

__device__ __forceinline__ float wave_reduce_sum(float v) {
    #pragma unroll
    for (int off = 32; off > 0; off >>= 1) v += __shfl_xor(v, off, 64);
    return v;
}

__device__ __forceinline__ float2 bf2(unsigned int u) {
    float2 r;
    r.x = __uint_as_float(u << 16);
    r.y = __uint_as_float(u & 0xFFFF0000u);
    return r;
}

__device__ __forceinline__ unsigned int packbf2(float a, float b) {
    __hip_bfloat162 t;
    t.x = __float2bfloat16(a);
    t.y = __float2bfloat16(b);
    unsigned int u;
    __builtin_memcpy(&u, &t, 4);
    return u;
}

// ---------------- LayerNorm: one wave per row, float2 per lane, bf16 out ----------------
__global__ __launch_bounds__(256) void ln_kernel(const float* __restrict__ x,
                                                 const float* __restrict__ g,
                                                 const float* __restrict__ b,
                                                 __hip_bfloat16* __restrict__ out, int n) {
    int wave = threadIdx.x >> 6;
    int lane = threadIdx.x & 63;
    int row = blockIdx.x * 4 + wave;
    if (row >= n) return;
    float2 v = ((const float2*)(x + (size_t)row * HID))[lane];
    float s = wave_reduce_sum(v.x + v.y);
    float mu = s * (1.0f / HID);
    float dx = v.x - mu, dy = v.y - mu;
    float q = wave_reduce_sum(dx * dx + dy * dy);
    float rstd = rsqrtf(q * (1.0f / HID) + 1e-5f);
    float2 gg = ((const float2*)g)[lane];
    float2 bb = ((const float2*)b)[lane];
    __hip_bfloat162 o;
    o.x = __float2bfloat16(dx * rstd * gg.x + bb.x);
    o.y = __float2bfloat16(dy * rstd * gg.y + bb.y);
    ((__hip_bfloat162*)(out + (size_t)row * HID))[lane] = o;
}

// ---------------- All weight converts + fused qkv bias, one launch ----------------
// Wt[n][k] = bf16(W[k][n]); Wq/Wk/Wv go to consecutive row blocks of Wqkvt.
__global__ __launch_bounds__(256) void wcvt_all(const float* __restrict__ Wq,
                                                const float* __restrict__ Wk,
                                                const float* __restrict__ Wv,
                                                const float* __restrict__ Wo,
                                                const float* __restrict__ W1,
                                                const float* __restrict__ W2,
                                                const float* __restrict__ bq,
                                                const float* __restrict__ bk,
                                                const float* __restrict__ bv,
                                                __hip_bfloat16* __restrict__ Wqkvt,
                                                __hip_bfloat16* __restrict__ Wot,
                                                __hip_bfloat16* __restrict__ W1t,
                                                __hip_bfloat16* __restrict__ W2t,
                                                float* __restrict__ bqkv) {
    int t = blockIdx.x * 256 + threadIdx.x;
    if (t >= 196608) {
        int i = t - 196608;
        if (i < 384) bqkv[i] = i < 128 ? bq[i] : (i < 256 ? bk[i - 128] : bv[i - 256]);
        return;
    }
    const float* W; __hip_bfloat16* Wt; int K, N, idx;
    if (t < 65536) {
        int which = t >> 14; idx = t & 16383; K = 128; N = 128;
        W = which == 0 ? Wq : which == 1 ? Wk : which == 2 ? Wv : Wo;
        Wt = which == 3 ? Wot : Wqkvt + which * 16384;
    } else if (t < 131072) { idx = t - 65536;  K = 128; N = 512; W = W1; Wt = W1t; }
    else                   { idx = t - 131072; K = 512; N = 128; W = W2; Wt = W2t; }
    int n = idx / K, k = idx - n * K;
    Wt[idx] = __float2bfloat16(W[(size_t)k * N + n]);
}

// ---------------- MFMA GEMM: C[M,NC] = A[M,K](bf16) @ Wt[NC,K](bf16)^T + bias ----------
template <int K, int OB>
__global__ __launch_bounds__(256) void gemm_mfma(const __hip_bfloat16* __restrict__ A,
                                                 const __hip_bfloat16* __restrict__ Wt,
                                                 const float* __restrict__ bias,
                                                 const float* __restrict__ res,
                                                 float* __restrict__ C,
                                                 __hip_bfloat16* __restrict__ Cb,
                                                 int M, int NC, int relu) {
    __shared__ short8 smem[1024 + 2048];  // A: 64x128 bf16 (16KB), B: 128x128 bf16 (32KB)
    const int row0 = blockIdx.x * 64;
    const int col0 = blockIdx.y * 128;
    const int tid = threadIdx.x;
    const int w = tid >> 6, l = tid & 63;
    const int lr = l & 15, hi = l >> 4;
    f32x4 acc[8] = {};
    for (int kk = 0; kk < K / 128; ++kk) {
        #pragma unroll
        for (int it = 0; it < 4; ++it) {
            int idx = tid + it * 256;
            int r = idx >> 4, s = idx & 15;
            int gr = row0 + r; if (gr >= M) gr = M - 1;
            short8 v = *(const short8*)(A + (size_t)gr * K + kk * 128 + s * 8);
            smem[r * 16 + (s ^ (r & 7))] = v;
        }
        #pragma unroll
        for (int it = 0; it < 8; ++it) {
            int idx = tid + it * 256;
            int r = idx >> 4, s = idx & 15;
            short8 v = *(const short8*)(Wt + (size_t)(col0 + r) * K + kk * 128 + s * 8);
            smem[1024 + r * 16 + (s ^ (r & 7))] = v;
        }
        __syncthreads();
        const int ar = w * 16 + lr;
        #pragma unroll
        for (int ks = 0; ks < 4; ++ks) {
            int s = ks * 4 + hi;
            short8 a = smem[ar * 16 + (s ^ (ar & 7))];
            #pragma unroll
            for (int f = 0; f < 8; ++f) {
                int br = f * 16 + lr;
                short8 b = smem[1024 + br * 16 + (s ^ (br & 7))];
                acc[f] = __builtin_amdgcn_mfma_f32_16x16x32_bf16(a, b, acc[f], 0, 0, 0);
            }
        }
        __syncthreads();
    }
    #pragma unroll
    for (int f = 0; f < 8; ++f) {
        int c = col0 + f * 16 + lr;
        float bv = bias[c];
        #pragma unroll
        for (int j = 0; j < 4; ++j) {
            int r = row0 + w * 16 + hi * 4 + j;
            if (r < M) {
                float v = acc[f][j] + bv;
                if (relu) v = fmaxf(v, 0.f);
                if (res) v += res[(size_t)r * NC + c];
                if (OB == 0) C[(size_t)r * NC + c] = v;
                else Cb[(size_t)r * NC + c] = __float2bfloat16(v);
            }
        }
    }
}

// ---------------- binA: bucket edges (bucket = dst>>8) with LDS staging -------------
// temp value layout: src(16b) | attr(4b)<<16 | (dst&255)<<20
__global__ __launch_bounds__(256) void binA_kernel(const int* __restrict__ ei,
                                                   const int* __restrict__ attr,
                                                   int* __restrict__ bcur,
                                                   unsigned int* __restrict__ temp) {
    __shared__ unsigned int sval[CHUNK_A];
    __shared__ unsigned short sbkt[CHUNK_A];
    __shared__ int hist[NBKT];
    __shared__ int lofs[NBKT];
    __shared__ int gbase[NBKT];
    __shared__ int lcur[NBKT];
    __shared__ int sc[256];
    const int tid = threadIdx.x;
    const int e0 = blockIdx.x * CHUNK_A;
    const int n = min(CHUNK_A, E_EDGES - e0);
    for (int i = tid; i < NBKT; i += 256) hist[i] = 0;
    __syncthreads();
    unsigned int v[EPT];
    short bk[EPT];
    #pragma unroll
    for (int j = 0; j < EPT; ++j) {
        int i = tid + j * 256;
        bk[j] = -1;
        v[j] = 0;
        if (i < n) {
            int e = e0 + i;
            int src = ei[e];
            int dst = ei[E_EDGES + e];
            int a = attr[e]; a = min(max(a, 0), 12);
            v[j] = (unsigned)src | ((unsigned)a << 16) | ((unsigned)(dst & 255) << 20);
            int b = dst >> 8;
            bk[j] = (short)b;
            atomicAdd(&hist[b], 1);
        }
    }
    __syncthreads();
    sc[tid] = (tid < NBKT) ? hist[tid] : 0;
    __syncthreads();
    for (int off = 1; off < 256; off <<= 1) {
        int x = (tid >= off) ? sc[tid - off] : 0;
        __syncthreads();
        sc[tid] += x;
        __syncthreads();
    }
    if (tid < NBKT) {
        int h = hist[tid];
        lofs[tid] = sc[tid] - h;     // exclusive prefix within block
        lcur[tid] = 0;
        gbase[tid] = h ? atomicAdd(&bcur[tid], h) : 0;
    }
    __syncthreads();
    #pragma unroll
    for (int j = 0; j < EPT; ++j) {
        if (bk[j] >= 0) {
            int p = lofs[bk[j]] + atomicAdd(&lcur[bk[j]], 1);
            sval[p] = v[j];
            sbkt[p] = (unsigned short)bk[j];
        }
    }
    __syncthreads();
    for (int i = tid; i < n; i += 256) {
        int b = sbkt[i];
        temp[(size_t)b * BKT_CAP + gbase[b] + (i - lofs[b])] = sval[i];
    }
}

// ---------------- binB: per-bucket counting sort by dst low byte; writes offs+packed --
__global__ __launch_bounds__(1024) void binB_kernel(const int* __restrict__ bcur,
                                                    const unsigned int* __restrict__ temp,
                                                    unsigned int* __restrict__ packed,
                                                    int* __restrict__ offs) {
    __shared__ int cnts[256];
    __shared__ int hist[256];
    __shared__ int cur[256];
    const int b = blockIdx.x, tid = threadIdx.x;
    if (tid < 256) {
        cnts[tid] = (tid < NBKT) ? bcur[tid] : 0;
        hist[tid] = 0;
    }
    __syncthreads();
    for (int off = 1; off < 256; off <<= 1) {
        int x = 0;
        if (tid < 256 && tid >= off) x = cnts[tid - off];
        __syncthreads();
        if (tid < 256) cnts[tid] += x;
        __syncthreads();
    }
    const int cnt = bcur[b];
    const int start = cnts[b] - cnt;  // exclusive global start of this bucket
    const size_t base = (size_t)b * BKT_CAP;
    for (int i = tid; i < cnt; i += 1024)
        atomicAdd(&hist[(temp[base + i] >> 20) & 255], 1);
    __syncthreads();
    if (tid < 256) cur[tid] = hist[tid];
    __syncthreads();
    for (int off = 1; off < 256; off <<= 1) {
        int x = 0;
        if (tid < 256 && tid >= off) x = cur[tid - off];
        __syncthreads();
        if (tid < 256) cur[tid] += x;
        __syncthreads();
    }
    const int node0 = b * 256;
    if (tid < 256) {
        int excl = cur[tid] - hist[tid];
        cur[tid] = excl;
        int node = node0 + tid;
        if (node < N_NODES) offs[node] = start + excl;
    }
    if (b == NBKT - 1 && tid == 0) offs[N_NODES] = start + cnt;
    __syncthreads();
    for (int i = tid; i < cnt; i += 1024) {
        unsigned int v = temp[base + i];
        int d = (v >> 20) & 255;
        int p = start + atomicAdd(&cur[d], 1);
        packed[p] = v & 0xFFFFFu;   // src | attr<<16
    }
}

// ---------------- Fused edge phase: wave-per-node, 4 edge slots x 16 sub-lanes ------
// QKV rows: bf16 [N,384]; Q at byte 0, K at byte 256, V at byte 512 of each 768B row.
__global__ __launch_bounds__(256) void fused_attn_kernel(
    const unsigned int* __restrict__ packed,
    const int* __restrict__ offs,
    const char* __restrict__ qkv,   // bf16 [N,384]
    const float* __restrict__ btab, // [13,8]
    __hip_bfloat16* __restrict__ out) {
    __shared__ float bLDS[104];
    const int tid = threadIdx.x;
    if (tid < 104) bLDS[tid] = btab[tid];
    __syncthreads();
    const int wave = tid >> 6, lane = tid & 63;
    const int n = blockIdx.x * 4 + wave;
    const int slot = lane >> 4, sub = lane & 15;
    const int h = sub >> 1;
    // Q fragment: 8 bf16, scaled by 1/sqrt(D)
    uint4 qv = *(const uint4*)(qkv + (unsigned)n * 768u + (unsigned)sub * 16u);
    float q[8];
    {
        float2 a0 = bf2(qv.x), a1 = bf2(qv.y), a2 = bf2(qv.z), a3 = bf2(qv.w);
        q[0] = a0.x * 0.25f; q[1] = a0.y * 0.25f;
        q[2] = a1.x * 0.25f; q[3] = a1.y * 0.25f;
        q[4] = a2.x * 0.25f; q[5] = a2.y * 0.25f;
        q[6] = a3.x * 0.25f; q[7] = a3.y * 0.25f;
    }
    const int lo = offs[n], hi = offs[n + 1];
    const int nit = (hi - lo + 3) >> 2;
    int i = lo + slot;
    float acc[8] = {0.f, 0.f, 0.f, 0.f, 0.f, 0.f, 0.f, 0.f};
    float wsum = 0.f;
    bool valid = i < hi;
    unsigned int pk = valid ? packed[i] : 0u;
    unsigned int off = (pk & 0xFFFFu) * 768u + 256u + (unsigned)sub * 16u;
    uint4 kc = *(const uint4*)(qkv + off);
    uint4 vc = *(const uint4*)(qkv + off + 256u);
    for (int it = 0; it < nit; ++it) {
        const int inext = i + 4;
        const bool nvalid = inext < hi;
        const unsigned int pkn = nvalid ? packed[inext] : 0u;
        const unsigned int offn = (pkn & 0xFFFFu) * 768u + 256u + (unsigned)sub * 16u;
        uint4 kn = *(const uint4*)(qkv + offn);
        uint4 vn = *(const uint4*)(qkv + offn + 256u);
        float2 k0 = bf2(kc.x), k1 = bf2(kc.y), k2 = bf2(kc.z), k3 = bf2(kc.w);
        float p = q[0] * k0.x + q[1] * k0.y + q[2] * k1.x + q[3] * k1.y
                + q[4] * k2.x + q[5] * k2.y + q[6] * k3.x + q[7] * k3.y;
        p += __shfl_xor(p, 1);  // head pair (lanes differ in bit 0)
        float s = p + bLDS[((pk >> 16) & 0xFu) * 8 + h];
        float w = valid ? __expf(s) : 0.f;
        wsum += w;
        float2 v0 = bf2(vc.x), v1 = bf2(vc.y), v2 = bf2(vc.z), v3 = bf2(vc.w);
        acc[0] = fmaf(w, v0.x, acc[0]);
        acc[1] = fmaf(w, v0.y, acc[1]);
        acc[2] = fmaf(w, v1.x, acc[2]);
        acc[3] = fmaf(w, v1.y, acc[3]);
        acc[4] = fmaf(w, v2.x, acc[4]);
        acc[5] = fmaf(w, v2.y, acc[5]);
        acc[6] = fmaf(w, v3.x, acc[6]);
        acc[7] = fmaf(w, v3.y, acc[7]);
        kc = kn; vc = vn; pk = pkn; valid = nvalid; i = inext;
    }
    // reduce edge-slots (lane bits 4,5)
    #pragma unroll
    for (int j = 0; j < 8; ++j) {
        acc[j] += __shfl_xor(acc[j], 16);
        acc[j] += __shfl_xor(acc[j], 32);
    }
    wsum += __shfl_xor(wsum, 16);
    wsum += __shfl_xor(wsum, 32);
    if (slot == 0) {
        float inv = 1.0f / (wsum + 1e-8f);
        uint4 ov;
        ov.x = packbf2(acc[0] * inv, acc[1] * inv);
        ov.y = packbf2(acc[2] * inv, acc[3] * inv);
        ov.z = packbf2(acc[4] * inv, acc[5] * inv);
        ov.w = packbf2(acc[6] * inv, acc[7] * inv);
        *(uint4*)((char*)out + (unsigned)n * 256u + (unsigned)sub * 16u) = ov;
    }
}

extern "C" void kernel_launch(void* const* d_in, const int* in_sizes, int n_in,
                              void* d_out, int out_size, void* d_ws, size_t ws_size,
                              hipStream_t stream) {
    const float* x    = (const float*)d_in[0];
    const int*   ei   = (const int*)d_in[1];
    const int*   attr = (const int*)d_in[2];
    const float* Wq   = (const float*)d_in[3];
    const float* bq   = (const float*)d_in[4];
    const float* Wk   = (const float*)d_in[5];
    const float* bk   = (const float*)d_in[6];
    const float* Wv   = (const float*)d_in[7];
    const float* bv   = (const float*)d_in[8];
    const float* Wo   = (const float*)d_in[9];
    const float* bo   = (const float*)d_in[10];
    const float* ebt  = (const float*)d_in[11];
    const float* W1   = (const float*)d_in[12];
    const float* b1   = (const float*)d_in[13];
    const float* W2   = (const float*)d_in[14];
    const float* b2   = (const float*)d_in[15];
    const float* g1   = (const float*)d_in[16];
    const float* be1  = (const float*)d_in[17];
    const float* g2   = (const float*)d_in[18];
    const float* be2  = (const float*)d_in[19];
    float* out = (float*)d_out;

    char* ws = (char*)d_ws;
    const size_t szRowF = (size_t)N_NODES * HID * 4;   // 25.6 MB
    const size_t szRowB = (size_t)N_NODES * HID * 2;   // 12.8 MB
    const size_t ALIGN = 256;
    #define ALN(v) (((v) + ALIGN - 1) & ~(ALIGN - 1))
    size_t o = 0;
    __hip_bfloat16* h_buf = (__hip_bfloat16*)(ws + o); o += szRowB;
    size_t region = o;  // f1 (51.2MB) aliases QKVb+packed+temp (52.03MB, dead by FFN)
    __hip_bfloat16* QKVb = (__hip_bfloat16*)(ws + o); o += (size_t)N_NODES * 384 * 2;  // 38.4MB
    unsigned int* packed = (unsigned int*)(ws + o); o += (size_t)E_EDGES * 4;          // 6.4MB
    unsigned int* temp = (unsigned int*)(ws + o); o += (size_t)NBKT * BKT_CAP * 4;     // 7.2MB
    int* bcur = (int*)(ws + o); o = ALN(o + (size_t)NBKT * 4);
    int* offs = (int*)(ws + o); o = ALN(o + (size_t)(N_NODES + 1) * 4);
    __hip_bfloat16* attn_ob = (__hip_bfloat16*)(ws + o); o += szRowB;
    float* x1 = (float*)(ws + o); o += szRowF;
    __hip_bfloat16* Wqkvt = (__hip_bfloat16*)(ws + o); o += 384 * 128 * 2;
    __hip_bfloat16* Wot = (__hip_bfloat16*)(ws + o); o += 128 * 128 * 2;
    __hip_bfloat16* W1t = (__hip_bfloat16*)(ws + o); o += 512 * 128 * 2;
    __hip_bfloat16* W2t = (__hip_bfloat16*)(ws + o); o += 128 * 512 * 2;
    float* bqkv = (float*)(ws + o); o += 384 * 4;       // ~118 MB total
    __hip_bfloat16* h2 = h_buf;                           // alias: h dead after QKV
    __hip_bfloat16* f1 = (__hip_bfloat16*)(ws + region);  // alias, see above

    hipMemsetAsync(bcur, 0, (size_t)NBKT * 4, stream);

    // CSR build: two-level LDS-binned counting sort
    binA_kernel<<<(E_EDGES + CHUNK_A - 1) / CHUNK_A, 256, 0, stream>>>(ei, attr, bcur, temp);
    binB_kernel<<<NBKT, 1024, 0, stream>>>(bcur, temp, packed, offs);

    // Weight conversions + fused qkv bias (single launch)
    wcvt_all<<<770, 256, 0, stream>>>(Wq, Wk, Wv, Wo, W1, W2, bq, bk, bv,
                                      Wqkvt, Wot, W1t, W2t, bqkv);

    // LN1 + fused QKV projection (bf16 out, [N,384])
    ln_kernel<<<(N_NODES + 3) / 4, 256, 0, stream>>>(x, g1, be1, h_buf, N_NODES);
    dim3 gqkv((N_NODES + 63) / 64, 3);
    gemm_mfma<128, 1><<<gqkv, 256, 0, stream>>>(h_buf, Wqkvt, bqkv, nullptr, nullptr, QKVb, N_NODES, 384, 0);

    // Fused edge phase (wave per node)
    fused_attn_kernel<<<(N_NODES + 3) / 4, 256, 0, stream>>>(packed, offs, (const char*)QKVb, ebt, attn_ob);

    // Wo projection + residual(x) -> x1 fp32
    dim3 gm((N_NODES + 63) / 64, 1);
    gemm_mfma<128, 0><<<gm, 256, 0, stream>>>(attn_ob, Wot, bo, x, x1, nullptr, N_NODES, 128, 0);
    // LN2 -> h2 bf16
    ln_kernel<<<(N_NODES + 3) / 4, 256, 0, stream>>>(x1, g2, be2, h2, N_NODES);
    // FFN
    dim3 gf1((N_NODES + 63) / 64, 4);
    gemm_mfma<128, 1><<<gf1, 256, 0, stream>>>(h2, W1t, b1, nullptr, nullptr, f1, N_NODES, 512, 1);
    gemm_mfma<512, 0><<<gm, 256, 0, stream>>>(f1, W2t, b2, x1, out, nullptr, N_NODES, 128, 0);
}

// Round 6
// 265.505 us; speedup vs baseline: 5.1619x; 1.2008x over previous
//
#include <hip/hip_runtime.h>
#include <hip/hip_bf16.h>

#define N_NODES 50000
#define E_EDGES 1600000
#define HID 128
#define NH 8
#define HD 16

#define NBKT 196        // ceil(50000/256) buckets of 256 dst nodes
#define BKT_CAP 9216    // mean 8192, sd ~90 -> +11 sigma headroom
#define CHUNK_A 4096
#define EPT 16          // edges per thread in binA (256 thr * 16)

using short8 = __attribute__((ext_vector_type(8))) short;
using f32x4  = __attribute__((ext_vector_type(4))) float;
using f32x2  = __attribute__((ext_vector_type(2))) float;

__device__ __forceinline__ float wave_reduce_sum(float v) {
    #pragma unroll
    for (int off = 32; off > 0; off >>= 1) v += __shfl_xor(v, off, 64);
    return v;
}

__device__ __forceinline__ unsigned int packbf2(float a, float b) {
    __hip_bfloat162 t;
    t.x = __float2bfloat16(a);
    t.y = __float2bfloat16(b);
    unsigned int u;
    __builtin_memcpy(&u, &t, 4);
    return u;
}

__device__ __forceinline__ unsigned char fp8e(float v) {
    return (unsigned char)(__builtin_amdgcn_cvt_pk_fp8_f32(v, v, 0u, false) & 0xFFu);
}

// unpack 16 fp8 (uint4) -> 16 f32 via hw v_cvt_pk_f32_fp8
__device__ __forceinline__ void cvt16(uint4 u, float* f) {
    f32x2 t;
    t = __builtin_amdgcn_cvt_pk_f32_fp8(u.x, false); f[0] = t[0];  f[1] = t[1];
    t = __builtin_amdgcn_cvt_pk_f32_fp8(u.x, true);  f[2] = t[0];  f[3] = t[1];
    t = __builtin_amdgcn_cvt_pk_f32_fp8(u.y, false); f[4] = t[0];  f[5] = t[1];
    t = __builtin_amdgcn_cvt_pk_f32_fp8(u.y, true);  f[6] = t[0];  f[7] = t[1];
    t = __builtin_amdgcn_cvt_pk_f32_fp8(u.z, false); f[8] = t[0];  f[9] = t[1];
    t = __builtin_amdgcn_cvt_pk_f32_fp8(u.z, true);  f[10] = t[0]; f[11] = t[1];
    t = __builtin_amdgcn_cvt_pk_f32_fp8(u.w, false); f[12] = t[0]; f[13] = t[1];
    t = __builtin_amdgcn_cvt_pk_f32_fp8(u.w, true);  f[14] = t[0]; f[15] = t[1];
}

// ---------------- LayerNorm: one wave per row, float2 per lane, bf16 out ----------------
__global__ __launch_bounds__(256) void ln_kernel(const float* __restrict__ x,
                                                 const float* __restrict__ g,
                                                 const float* __restrict__ b,
                                                 __hip_bfloat16* __restrict__ out, int n) {
    int wave = threadIdx.x >> 6;
    int lane = threadIdx.x & 63;
    int row = blockIdx.x * 4 + wave;
    if (row >= n) return;
    float2 v = ((const float2*)(x + (size_t)row * HID))[lane];
    float s = wave_reduce_sum(v.x + v.y);
    float mu = s * (1.0f / HID);
    float dx = v.x - mu, dy = v.y - mu;
    float q = wave_reduce_sum(dx * dx + dy * dy);
    float rstd = rsqrtf(q * (1.0f / HID) + 1e-5f);
    float2 gg = ((const float2*)g)[lane];
    float2 bb = ((const float2*)b)[lane];
    __hip_bfloat162 o;
    o.x = __float2bfloat16(dx * rstd * gg.x + bb.x);
    o.y = __float2bfloat16(dy * rstd * gg.y + bb.y);
    ((__hip_bfloat162*)(out + (size_t)row * HID))[lane] = o;
}

// ---------------- All weight converts + fused qkv bias, one launch ----------------
__global__ __launch_bounds__(256) void wcvt_all(const float* __restrict__ Wq,
                                                const float* __restrict__ Wk,
                                                const float* __restrict__ Wv,
                                                const float* __restrict__ Wo,
                                                const float* __restrict__ W1,
                                                const float* __restrict__ W2,
                                                const float* __restrict__ bq,
                                                const float* __restrict__ bk,
                                                const float* __restrict__ bv,
                                                __hip_bfloat16* __restrict__ Wqkvt,
                                                __hip_bfloat16* __restrict__ Wot,
                                                __hip_bfloat16* __restrict__ W1t,
                                                __hip_bfloat16* __restrict__ W2t,
                                                float* __restrict__ bqkv) {
    int t = blockIdx.x * 256 + threadIdx.x;
    if (t >= 196608) {
        int i = t - 196608;
        if (i < 384) bqkv[i] = i < 128 ? bq[i] : (i < 256 ? bk[i - 128] : bv[i - 256]);
        return;
    }
    const float* W; __hip_bfloat16* Wt; int K, N, idx;
    if (t < 65536) {
        int which = t >> 14; idx = t & 16383; K = 128; N = 128;
        W = which == 0 ? Wq : which == 1 ? Wk : which == 2 ? Wv : Wo;
        Wt = which == 3 ? Wot : Wqkvt + which * 16384;
    } else if (t < 131072) { idx = t - 65536;  K = 128; N = 512; W = W1; Wt = W1t; }
    else                   { idx = t - 131072; K = 512; N = 128; W = W2; Wt = W2t; }
    int n = idx / K, k = idx - n * K;
    Wt[idx] = __float2bfloat16(W[(size_t)k * N + n]);
}

// ---------------- MFMA GEMM: C[M,NC] = A[M,K](bf16) @ Wt[NC,K](bf16)^T + bias ----------
// OB: 0 -> f32 out, 1 -> bf16 out, 2 -> fp8 out into C8 plane blockIdx.y (Q plane scaled 0.25)
template <int K, int OB>
__global__ __launch_bounds__(256) void gemm_mfma(const __hip_bfloat16* __restrict__ A,
                                                 const __hip_bfloat16* __restrict__ Wt,
                                                 const float* __restrict__ bias,
                                                 const float* __restrict__ res,
                                                 float* __restrict__ C,
                                                 __hip_bfloat16* __restrict__ Cb,
                                                 unsigned char* __restrict__ C8,
                                                 int M, int NC, int relu) {
    __shared__ short8 smem[1024 + 2048];  // A: 64x128 bf16 (16KB), B: 128x128 bf16 (32KB)
    const int row0 = blockIdx.x * 64;
    const int col0 = blockIdx.y * 128;
    const int tid = threadIdx.x;
    const int w = tid >> 6, l = tid & 63;
    const int lr = l & 15, hi = l >> 4;
    f32x4 acc[8] = {};
    for (int kk = 0; kk < K / 128; ++kk) {
        #pragma unroll
        for (int it = 0; it < 4; ++it) {
            int idx = tid + it * 256;
            int r = idx >> 4, s = idx & 15;
            int gr = row0 + r; if (gr >= M) gr = M - 1;
            short8 v = *(const short8*)(A + (size_t)gr * K + kk * 128 + s * 8);
            smem[r * 16 + (s ^ (r & 7))] = v;
        }
        #pragma unroll
        for (int it = 0; it < 8; ++it) {
            int idx = tid + it * 256;
            int r = idx >> 4, s = idx & 15;
            short8 v = *(const short8*)(Wt + (size_t)(col0 + r) * K + kk * 128 + s * 8);
            smem[1024 + r * 16 + (s ^ (r & 7))] = v;
        }
        __syncthreads();
        const int ar = w * 16 + lr;
        #pragma unroll
        for (int ks = 0; ks < 4; ++ks) {
            int s = ks * 4 + hi;
            short8 a = smem[ar * 16 + (s ^ (ar & 7))];
            #pragma unroll
            for (int f = 0; f < 8; ++f) {
                int br = f * 16 + lr;
                short8 b = smem[1024 + br * 16 + (s ^ (br & 7))];
                acc[f] = __builtin_amdgcn_mfma_f32_16x16x32_bf16(a, b, acc[f], 0, 0, 0);
            }
        }
        __syncthreads();
    }
    const float scl = (OB == 2 && blockIdx.y == 0) ? 0.25f : 1.0f;
    unsigned char* p8 = (OB == 2) ? C8 + (size_t)blockIdx.y * ((size_t)N_NODES * 128) : nullptr;
    #pragma unroll
    for (int f = 0; f < 8; ++f) {
        int c = col0 + f * 16 + lr;
        float bv = bias[c];
        #pragma unroll
        for (int j = 0; j < 4; ++j) {
            int r = row0 + w * 16 + hi * 4 + j;
            if (r < M) {
                float v = acc[f][j] + bv;
                if (relu) v = fmaxf(v, 0.f);
                if (res) v += res[(size_t)r * NC + c];
                if (OB == 0) C[(size_t)r * NC + c] = v;
                else if (OB == 1) Cb[(size_t)r * NC + c] = __float2bfloat16(v);
                else p8[(size_t)r * 128 + (c & 127)] = fp8e(v * scl);
            }
        }
    }
}

// ---------------- binA: bucket edges (bucket = dst>>8) with LDS staging -------------
// temp value layout: src(16b) | attr(4b)<<16 | (dst&255)<<20
__global__ __launch_bounds__(256) void binA_kernel(const int* __restrict__ ei,
                                                   const int* __restrict__ attr,
                                                   int* __restrict__ bcur,
                                                   unsigned int* __restrict__ temp) {
    __shared__ unsigned int sval[CHUNK_A];
    __shared__ unsigned short sbkt[CHUNK_A];
    __shared__ int hist[NBKT];
    __shared__ int lofs[NBKT];
    __shared__ int gbase[NBKT];
    __shared__ int lcur[NBKT];
    __shared__ int sc[256];
    const int tid = threadIdx.x;
    const int e0 = blockIdx.x * CHUNK_A;
    const int n = min(CHUNK_A, E_EDGES - e0);
    for (int i = tid; i < NBKT; i += 256) hist[i] = 0;
    __syncthreads();
    unsigned int v[EPT];
    short bk[EPT];
    #pragma unroll
    for (int j = 0; j < EPT; ++j) {
        int i = tid + j * 256;
        bk[j] = -1;
        v[j] = 0;
        if (i < n) {
            int e = e0 + i;
            int src = ei[e];
            int dst = ei[E_EDGES + e];
            int a = attr[e]; a = min(max(a, 0), 12);
            v[j] = (unsigned)src | ((unsigned)a << 16) | ((unsigned)(dst & 255) << 20);
            int b = dst >> 8;
            bk[j] = (short)b;
            atomicAdd(&hist[b], 1);
        }
    }
    __syncthreads();
    sc[tid] = (tid < NBKT) ? hist[tid] : 0;
    __syncthreads();
    for (int off = 1; off < 256; off <<= 1) {
        int x = (tid >= off) ? sc[tid - off] : 0;
        __syncthreads();
        sc[tid] += x;
        __syncthreads();
    }
    if (tid < NBKT) {
        int h = hist[tid];
        lofs[tid] = sc[tid] - h;     // exclusive prefix within block
        lcur[tid] = 0;
        gbase[tid] = h ? atomicAdd(&bcur[tid], h) : 0;
    }
    __syncthreads();
    #pragma unroll
    for (int j = 0; j < EPT; ++j) {
        if (bk[j] >= 0) {
            int p = lofs[bk[j]] + atomicAdd(&lcur[bk[j]], 1);
            sval[p] = v[j];
            sbkt[p] = (unsigned short)bk[j];
        }
    }
    __syncthreads();
    for (int i = tid; i < n; i += 256) {
        int b = sbkt[i];
        temp[(size_t)b * BKT_CAP + gbase[b] + (i - lofs[b])] = sval[i];
    }
}

// ---------------- binB: per-bucket counting sort by dst low byte; writes offs+packed --
__global__ __launch_bounds__(1024) void binB_kernel(const int* __restrict__ bcur,
                                                    const unsigned int* __restrict__ temp,
                                                    unsigned int* __restrict__ packed,
                                                    int* __restrict__ offs) {
    __shared__ int cnts[256];
    __shared__ int hist[256];
    __shared__ int cur[256];
    const int b = blockIdx.x, tid = threadIdx.x;
    if (tid < 256) {
        cnts[tid] = (tid < NBKT) ? bcur[tid] : 0;
        hist[tid] = 0;
    }
    __syncthreads();
    for (int off = 1; off < 256; off <<= 1) {
        int x = 0;
        if (tid < 256 && tid >= off) x = cnts[tid - off];
        __syncthreads();
        if (tid < 256) cnts[tid] += x;
        __syncthreads();
    }
    const int cnt = bcur[b];
    const int start = cnts[b] - cnt;  // exclusive global start of this bucket
    const size_t base = (size_t)b * BKT_CAP;
    for (int i = tid; i < cnt; i += 1024)
        atomicAdd(&hist[(temp[base + i] >> 20) & 255], 1);
    __syncthreads();
    if (tid < 256) cur[tid] = hist[tid];
    __syncthreads();
    for (int off = 1; off < 256; off <<= 1) {
        int x = 0;
        if (tid < 256 && tid >= off) x = cur[tid - off];
        __syncthreads();
        if (tid < 256) cur[tid] += x;
        __syncthreads();
    }
    const int node0 = b * 256;
    if (tid < 256) {
        int excl = cur[tid] - hist[tid];
        cur[tid] = excl;
        int node = node0 + tid;
        if (node < N_NODES) offs[node] = start + excl;
    }
    if (b == NBKT - 1 && tid == 0) offs[N_NODES] = start + cnt;
    __syncthreads();
    for (int i = tid; i < cnt; i += 1024) {
        unsigned int v = temp[base + i];
        int d = (v >> 20) & 255;
        int p = start + atomicAdd(&cur[d], 1);
        packed[p] = v & 0xFFFFFu;   // src | attr<<16
    }
}

// ---------------- Fused edge phase: wave-per-node, 8 edge slots x 8 lanes ------
// QKV8: fp8 planes [3][N][128]; lane sub (0..7) covers head sub's 16 elems.
// Q pre-scaled by 1/sqrt(D) in GEMM epilogue. No cross-lane ops in inner loop.
__global__ __launch_bounds__(256) void fused_attn_kernel(
    const unsigned int* __restrict__ packed,
    const int* __restrict__ offs,
    const unsigned char* __restrict__ qkv8,
    const float* __restrict__ btab,     // [13,8]
    __hip_bfloat16* __restrict__ out) {
    __shared__ float bLDS[104];
    const int tid = threadIdx.x;
    if (tid < 104) bLDS[tid] = btab[tid];
    __syncthreads();
    const int wave = tid >> 6, lane = tid & 63;
    const int n = blockIdx.x * 4 + wave;
    const int slot = lane >> 3, sub = lane & 7;
    const unsigned char* k8 = qkv8 + (size_t)N_NODES * 128;
    const unsigned char* v8 = qkv8 + (size_t)N_NODES * 256;
    const unsigned sb = (unsigned)sub << 4;
    float q[16];
    cvt16(*(const uint4*)(qkv8 + ((unsigned)n << 7) + sb), q);
    const int lo = offs[n], hi = offs[n + 1];
    const int nit = (hi - lo + 7) >> 3;
    int i = lo + slot;
    float acc[16] = {};
    float wsum = 0.f;
    bool valid = i < hi;
    unsigned int pk = valid ? packed[i] : 0u;
    unsigned roff = ((pk & 0xFFFFu) << 7) + sb;
    uint4 kc = *(const uint4*)(k8 + roff);
    uint4 vc = *(const uint4*)(v8 + roff);
    for (int it = 0; it < nit; ++it) {
        const int inext = i + 8;
        const bool nvalid = inext < hi;
        const unsigned int pkn = nvalid ? packed[inext] : 0u;
        const unsigned roffn = ((pkn & 0xFFFFu) << 7) + sb;
        uint4 kn = *(const uint4*)(k8 + roffn);
        uint4 vn = *(const uint4*)(v8 + roffn);
        float k[16];
        cvt16(kc, k);
        float p = q[0] * k[0];
        #pragma unroll
        for (int j = 1; j < 16; ++j) p = fmaf(q[j], k[j], p);
        float s = p + bLDS[((pk >> 16) & 0xFu) * 8 + sub];
        float w = valid ? __expf(s) : 0.f;
        wsum += w;
        float v[16];
        cvt16(vc, v);
        #pragma unroll
        for (int j = 0; j < 16; ++j) acc[j] = fmaf(w, v[j], acc[j]);
        kc = kn; vc = vn; pk = pkn; valid = nvalid; i = inext;
    }
    // reduce the 8 edge-slots (lane bits 3,4,5)
    #pragma unroll
    for (int j = 0; j < 16; ++j) {
        acc[j] += __shfl_xor(acc[j], 8);
        acc[j] += __shfl_xor(acc[j], 16);
        acc[j] += __shfl_xor(acc[j], 32);
    }
    wsum += __shfl_xor(wsum, 8);
    wsum += __shfl_xor(wsum, 16);
    wsum += __shfl_xor(wsum, 32);
    if (slot == 0) {
        float inv = 1.0f / (wsum + 1e-8f);
        uint4 o0, o1;
        o0.x = packbf2(acc[0] * inv, acc[1] * inv);
        o0.y = packbf2(acc[2] * inv, acc[3] * inv);
        o0.z = packbf2(acc[4] * inv, acc[5] * inv);
        o0.w = packbf2(acc[6] * inv, acc[7] * inv);
        o1.x = packbf2(acc[8] * inv, acc[9] * inv);
        o1.y = packbf2(acc[10] * inv, acc[11] * inv);
        o1.z = packbf2(acc[12] * inv, acc[13] * inv);
        o1.w = packbf2(acc[14] * inv, acc[15] * inv);
        char* op = (char*)out + ((unsigned)n << 8) + ((unsigned)sub << 5);
        *(uint4*)op = o0;
        *(uint4*)(op + 16) = o1;
    }
}

extern "C" void kernel_launch(void* const* d_in, const int* in_sizes, int n_in,
                              void* d_out, int out_size, void* d_ws, size_t ws_size,
                              hipStream_t stream) {
    const float* x    = (const float*)d_in[0];
    const int*   ei   = (const int*)d_in[1];
    const int*   attr = (const int*)d_in[2];
    const float* Wq   = (const float*)d_in[3];
    const float* bq   = (const float*)d_in[4];
    const float* Wk   = (const float*)d_in[5];
    const float* bk   = (const float*)d_in[6];
    const float* Wv   = (const float*)d_in[7];
    const float* bv   = (const float*)d_in[8];
    const float* Wo   = (const float*)d_in[9];
    const float* bo   = (const float*)d_in[10];
    const float* ebt  = (const float*)d_in[11];
    const float* W1   = (const float*)d_in[12];
    const float* b1   = (const float*)d_in[13];
    const float* W2   = (const float*)d_in[14];
    const float* b2   = (const float*)d_in[15];
    const float* g1   = (const float*)d_in[16];
    const float* be1  = (const float*)d_in[17];
    const float* g2   = (const float*)d_in[18];
    const float* be2  = (const float*)d_in[19];
    float* out = (float*)d_out;

    char* ws = (char*)d_ws;
    const size_t szRowF = (size_t)N_NODES * HID * 4;   // 25.6 MB
    const size_t szRowB = (size_t)N_NODES * HID * 2;   // 12.8 MB
    const size_t ALIGN = 256;
    #define ALN(v) (((v) + ALIGN - 1) & ~(ALIGN - 1))
    size_t o = 0;
    __hip_bfloat16* h_buf = (__hip_bfloat16*)(ws + o); o += szRowB;
    unsigned char* QKV8 = (unsigned char*)(ws + o); o += (size_t)N_NODES * 384;  // 19.2MB
    unsigned int* packed = (unsigned int*)(ws + o); o += (size_t)E_EDGES * 4;    // 6.4MB
    unsigned int* temp = (unsigned int*)(ws + o); o += (size_t)NBKT * BKT_CAP * 4; // 7.2MB
    int* bcur = (int*)(ws + o); o = ALN(o + (size_t)NBKT * 4);
    int* offs = (int*)(ws + o); o = ALN(o + (size_t)(N_NODES + 1) * 4);
    __hip_bfloat16* attn_ob = (__hip_bfloat16*)(ws + o); o += szRowB;
    float* x1 = (float*)(ws + o); o += szRowF;
    __hip_bfloat16* f1 = (__hip_bfloat16*)(ws + o); o += (size_t)N_NODES * 512 * 2;  // 51.2MB
    __hip_bfloat16* Wqkvt = (__hip_bfloat16*)(ws + o); o += 384 * 128 * 2;
    __hip_bfloat16* Wot = (__hip_bfloat16*)(ws + o); o += 128 * 128 * 2;
    __hip_bfloat16* W1t = (__hip_bfloat16*)(ws + o); o += 512 * 128 * 2;
    __hip_bfloat16* W2t = (__hip_bfloat16*)(ws + o); o += 128 * 512 * 2;
    float* bqkv = (float*)(ws + o); o += 384 * 4;       // ~136 MB total
    __hip_bfloat16* h2 = h_buf;                          // alias: h dead after QKV

    hipMemsetAsync(bcur, 0, (size_t)NBKT * 4, stream);

    // CSR build: two-level LDS-binned counting sort
    binA_kernel<<<(E_EDGES + CHUNK_A - 1) / CHUNK_A, 256, 0, stream>>>(ei, attr, bcur, temp);
    binB_kernel<<<NBKT, 1024, 0, stream>>>(bcur, temp, packed, offs);

    // Weight conversions + fused qkv bias (single launch)
    wcvt_all<<<770, 256, 0, stream>>>(Wq, Wk, Wv, Wo, W1, W2, bq, bk, bv,
                                      Wqkvt, Wot, W1t, W2t, bqkv);

    // LN1 + fused QKV projection (fp8 planes [3][N][128], Q scaled 0.25)
    ln_kernel<<<(N_NODES + 3) / 4, 256, 0, stream>>>(x, g1, be1, h_buf, N_NODES);
    dim3 gqkv((N_NODES + 63) / 64, 3);
    gemm_mfma<128, 2><<<gqkv, 256, 0, stream>>>(h_buf, Wqkvt, bqkv, nullptr, nullptr, nullptr, QKV8, N_NODES, 384, 0);

    // Fused edge phase (wave per node, 8 slots x 8 lanes)
    fused_attn_kernel<<<(N_NODES + 3) / 4, 256, 0, stream>>>(packed, offs, QKV8, ebt, attn_ob);

    // Wo projection + residual(x) -> x1 fp32
    dim3 gm((N_NODES + 63) / 64, 1);
    gemm_mfma<128, 0><<<gm, 256, 0, stream>>>(attn_ob, Wot, bo, x, x1, nullptr, nullptr, N_NODES, 128, 0);
    // LN2 -> h2 bf16
    ln_kernel<<<(N_NODES + 3) / 4, 256, 0, stream>>>(x1, g2, be2, h2, N_NODES);
    // FFN
    dim3 gf1((N_NODES + 63) / 64, 4);
    gemm_mfma<128, 1><<<gf1, 256, 0, stream>>>(h2, W1t, b1, nullptr, nullptr, f1, nullptr, N_NODES, 512, 1);
    gemm_mfma<512, 0><<<gm, 256, 0, stream>>>(f1, W2t, b2, x1, out, nullptr, nullptr, N_NODES, 128, 0);
}

// Round 7
// 256.254 us; speedup vs baseline: 5.3482x; 1.0361x over previous
//
#include <hip/hip_runtime.h>
#include <hip/hip_bf16.h>

#define N_NODES 50000
#define E_EDGES 1600000
#define HID 128
#define NH 8
#define HD 16

#define NBKT 196        // ceil(50000/256) buckets of 256 dst nodes
#define BKT_CAP 9216    // mean 8192, sd ~90 -> +11 sigma headroom
#define CHUNK_A 4096
#define EPT 16          // edges per thread in binA (256 thr * 16)

using short8 = __attribute__((ext_vector_type(8))) short;
using f32x4  = __attribute__((ext_vector_type(4))) float;
using f32x2  = __attribute__((ext_vector_type(2))) float;
typedef _Float16 h16x2 __attribute__((ext_vector_type(2)));

#if defined(__has_builtin) && __has_builtin(__builtin_amdgcn_fdot2)
#define FDOT2(a, b, c) __builtin_amdgcn_fdot2((a), (b), (c), false)
#else
__device__ __forceinline__ float FDOT2(h16x2 a, h16x2 b, float c) {
    return fmaf((float)a[0], (float)b[0], fmaf((float)a[1], (float)b[1], c));
}
#endif

__device__ __forceinline__ float wave_reduce_sum(float v) {
    #pragma unroll
    for (int off = 32; off > 0; off >>= 1) v += __shfl_xor(v, off, 64);
    return v;
}

__device__ __forceinline__ unsigned int packbf2(float a, float b) {
    __hip_bfloat162 t;
    t.x = __float2bfloat16(a);
    t.y = __float2bfloat16(b);
    unsigned int u;
    __builtin_memcpy(&u, &t, 4);
    return u;
}

__device__ __forceinline__ unsigned char fp8e(float v) {
    return (unsigned char)(__builtin_amdgcn_cvt_pk_fp8_f32(v, v, 0u, false) & 0xFFu);
}

// unpack 16 fp8 (uint4) -> 16 f32 via hw v_cvt_pk_f32_fp8
__device__ __forceinline__ void cvt16(uint4 u, float* f) {
    f32x2 t;
    t = __builtin_amdgcn_cvt_pk_f32_fp8(u.x, false); f[0] = t[0];  f[1] = t[1];
    t = __builtin_amdgcn_cvt_pk_f32_fp8(u.x, true);  f[2] = t[0];  f[3] = t[1];
    t = __builtin_amdgcn_cvt_pk_f32_fp8(u.y, false); f[4] = t[0];  f[5] = t[1];
    t = __builtin_amdgcn_cvt_pk_f32_fp8(u.y, true);  f[6] = t[0];  f[7] = t[1];
    t = __builtin_amdgcn_cvt_pk_f32_fp8(u.z, false); f[8] = t[0];  f[9] = t[1];
    t = __builtin_amdgcn_cvt_pk_f32_fp8(u.z, true);  f[10] = t[0]; f[11] = t[1];
    t = __builtin_amdgcn_cvt_pk_f32_fp8(u.w, false); f[12] = t[0]; f[13] = t[1];
    t = __builtin_amdgcn_cvt_pk_f32_fp8(u.w, true);  f[14] = t[0]; f[15] = t[1];
}

union U4H {
    uint4 u;
    h16x2 h[4];
};

// ---------------- LayerNorm: one wave per row, float2 per lane, bf16 out ----------------
__global__ __launch_bounds__(256) void ln_kernel(const float* __restrict__ x,
                                                 const float* __restrict__ g,
                                                 const float* __restrict__ b,
                                                 __hip_bfloat16* __restrict__ out, int n) {
    int wave = threadIdx.x >> 6;
    int lane = threadIdx.x & 63;
    int row = blockIdx.x * 4 + wave;
    if (row >= n) return;
    float2 v = ((const float2*)(x + (size_t)row * HID))[lane];
    float s = wave_reduce_sum(v.x + v.y);
    float mu = s * (1.0f / HID);
    float dx = v.x - mu, dy = v.y - mu;
    float q = wave_reduce_sum(dx * dx + dy * dy);
    float rstd = rsqrtf(q * (1.0f / HID) + 1e-5f);
    float2 gg = ((const float2*)g)[lane];
    float2 bb = ((const float2*)b)[lane];
    __hip_bfloat162 o;
    o.x = __float2bfloat16(dx * rstd * gg.x + bb.x);
    o.y = __float2bfloat16(dy * rstd * gg.y + bb.y);
    ((__hip_bfloat162*)(out + (size_t)row * HID))[lane] = o;
}

// ---------------- All weight converts + fused qkv bias + bcur zero, one launch --------
__global__ __launch_bounds__(256) void wcvt_all(const float* __restrict__ Wq,
                                                const float* __restrict__ Wk,
                                                const float* __restrict__ Wv,
                                                const float* __restrict__ Wo,
                                                const float* __restrict__ W1,
                                                const float* __restrict__ W2,
                                                const float* __restrict__ bq,
                                                const float* __restrict__ bk,
                                                const float* __restrict__ bv,
                                                __hip_bfloat16* __restrict__ Wqkvt,
                                                __hip_bfloat16* __restrict__ Wot,
                                                __hip_bfloat16* __restrict__ W1t,
                                                __hip_bfloat16* __restrict__ W2t,
                                                float* __restrict__ bqkv,
                                                int* __restrict__ bcur) {
    int t = blockIdx.x * 256 + threadIdx.x;
    if (t >= 196608) {
        int i = t - 196608;
        if (i < 384) bqkv[i] = i < 128 ? bq[i] : (i < 256 ? bk[i - 128] : bv[i - 256]);
        else if (i < 384 + NBKT) bcur[i - 384] = 0;
        return;
    }
    const float* W; __hip_bfloat16* Wt; int K, N, idx;
    if (t < 65536) {
        int which = t >> 14; idx = t & 16383; K = 128; N = 128;
        W = which == 0 ? Wq : which == 1 ? Wk : which == 2 ? Wv : Wo;
        Wt = which == 3 ? Wot : Wqkvt + which * 16384;
    } else if (t < 131072) { idx = t - 65536;  K = 128; N = 512; W = W1; Wt = W1t; }
    else                   { idx = t - 131072; K = 512; N = 128; W = W2; Wt = W2t; }
    int n = idx / K, k = idx - n * K;
    Wt[idx] = __float2bfloat16(W[(size_t)k * N + n]);
}

// ---------------- MFMA GEMM: C[M,NC] = A[M,K](bf16) @ Wt[NC,K](bf16)^T + bias ----------
// 512 threads = 8 waves; tile 128 rows x 128 cols; wave w owns rows w*16..+15.
// OB: 0 -> f32 out, 1 -> bf16 out,
//     2 -> QKV: plane y=0 Q f16 (scaled 0.25), y=1 K f16, y=2 V fp8
template <int K, int OB>
__global__ __launch_bounds__(512) void gemm_mfma(const __hip_bfloat16* __restrict__ A,
                                                 const __hip_bfloat16* __restrict__ Wt,
                                                 const float* __restrict__ bias,
                                                 const float* __restrict__ res,
                                                 float* __restrict__ C,
                                                 __hip_bfloat16* __restrict__ Cb,
                                                 _Float16* __restrict__ Chh,
                                                 unsigned char* __restrict__ C8,
                                                 int M, int NC, int relu) {
    __shared__ short8 smem[2048 + 2048];  // A: 128x128 bf16 (32KB), B: 128x128 bf16 (32KB)
    const int row0 = blockIdx.x * 128;
    const int col0 = blockIdx.y * 128;
    const int tid = threadIdx.x;
    const int w = tid >> 6, l = tid & 63;
    const int lr = l & 15, hi = l >> 4;
    f32x4 acc[8] = {};
    for (int kk = 0; kk < K / 128; ++kk) {
        #pragma unroll
        for (int it = 0; it < 4; ++it) {
            int idx = tid + it * 512;
            int r = idx >> 4, s = idx & 15;
            int gr = row0 + r; if (gr >= M) gr = M - 1;
            short8 v = *(const short8*)(A + (size_t)gr * K + kk * 128 + s * 8);
            smem[r * 16 + (s ^ (r & 7))] = v;
        }
        #pragma unroll
        for (int it = 0; it < 4; ++it) {
            int idx = tid + it * 512;
            int r = idx >> 4, s = idx & 15;
            short8 v = *(const short8*)(Wt + (size_t)(col0 + r) * K + kk * 128 + s * 8);
            smem[2048 + r * 16 + (s ^ (r & 7))] = v;
        }
        __syncthreads();
        const int ar = w * 16 + lr;
        #pragma unroll
        for (int ks = 0; ks < 4; ++ks) {
            int s = ks * 4 + hi;
            short8 a = smem[ar * 16 + (s ^ (ar & 7))];
            #pragma unroll
            for (int f = 0; f < 8; ++f) {
                int br = f * 16 + lr;
                short8 b = smem[2048 + br * 16 + (s ^ (br & 7))];
                acc[f] = __builtin_amdgcn_mfma_f32_16x16x32_bf16(a, b, acc[f], 0, 0, 0);
            }
        }
        __syncthreads();
    }
    const float scl = (OB == 2 && blockIdx.y == 0) ? 0.25f : 1.0f;
    #pragma unroll
    for (int f = 0; f < 8; ++f) {
        int c = col0 + f * 16 + lr;
        float bv = bias[c];
        #pragma unroll
        for (int j = 0; j < 4; ++j) {
            int r = row0 + w * 16 + hi * 4 + j;
            if (r < M) {
                float v = acc[f][j] + bv;
                if (relu) v = fmaxf(v, 0.f);
                if (res) v += res[(size_t)r * NC + c];
                if (OB == 0) C[(size_t)r * NC + c] = v;
                else if (OB == 1) Cb[(size_t)r * NC + c] = __float2bfloat16(v);
                else {
                    if (blockIdx.y < 2)
                        Chh[(size_t)blockIdx.y * N_NODES * 128 + (size_t)r * 128 + (c & 127)] =
                            (_Float16)(v * scl);
                    else
                        C8[(size_t)r * 128 + (c & 127)] = fp8e(v);
                }
            }
        }
    }
}

// ---------------- binA: bucket edges (bucket = dst>>8) with LDS staging -------------
// temp value layout: src(16b) | attr(4b)<<16 | (dst&255)<<20
__global__ __launch_bounds__(256) void binA_kernel(const int* __restrict__ ei,
                                                   const int* __restrict__ attr,
                                                   int* __restrict__ bcur,
                                                   unsigned int* __restrict__ temp) {
    __shared__ unsigned int sval[CHUNK_A];
    __shared__ unsigned short sbkt[CHUNK_A];
    __shared__ int hist[NBKT];
    __shared__ int lofs[NBKT];
    __shared__ int gbase[NBKT];
    __shared__ int lcur[NBKT];
    __shared__ int sc[256];
    const int tid = threadIdx.x;
    const int e0 = blockIdx.x * CHUNK_A;
    const int n = min(CHUNK_A, E_EDGES - e0);
    for (int i = tid; i < NBKT; i += 256) hist[i] = 0;
    __syncthreads();
    unsigned int v[EPT];
    short bk[EPT];
    #pragma unroll
    for (int j = 0; j < EPT; ++j) {
        int i = tid + j * 256;
        bk[j] = -1;
        v[j] = 0;
        if (i < n) {
            int e = e0 + i;
            int src = ei[e];
            int dst = ei[E_EDGES + e];
            int a = attr[e]; a = min(max(a, 0), 12);
            v[j] = (unsigned)src | ((unsigned)a << 16) | ((unsigned)(dst & 255) << 20);
            int b = dst >> 8;
            bk[j] = (short)b;
            atomicAdd(&hist[b], 1);
        }
    }
    __syncthreads();
    sc[tid] = (tid < NBKT) ? hist[tid] : 0;
    __syncthreads();
    for (int off = 1; off < 256; off <<= 1) {
        int x = (tid >= off) ? sc[tid - off] : 0;
        __syncthreads();
        sc[tid] += x;
        __syncthreads();
    }
    if (tid < NBKT) {
        int h = hist[tid];
        lofs[tid] = sc[tid] - h;     // exclusive prefix within block
        lcur[tid] = 0;
        gbase[tid] = h ? atomicAdd(&bcur[tid], h) : 0;
    }
    __syncthreads();
    #pragma unroll
    for (int j = 0; j < EPT; ++j) {
        if (bk[j] >= 0) {
            int p = lofs[bk[j]] + atomicAdd(&lcur[bk[j]], 1);
            sval[p] = v[j];
            sbkt[p] = (unsigned short)bk[j];
        }
    }
    __syncthreads();
    for (int i = tid; i < n; i += 256) {
        int b = sbkt[i];
        temp[(size_t)b * BKT_CAP + gbase[b] + (i - lofs[b])] = sval[i];
    }
}

// ---------------- binB: per-bucket counting sort by dst low byte; writes offs+packed --
__global__ __launch_bounds__(1024) void binB_kernel(const int* __restrict__ bcur,
                                                    const unsigned int* __restrict__ temp,
                                                    unsigned int* __restrict__ packed,
                                                    int* __restrict__ offs) {
    __shared__ int cnts[256];
    __shared__ int hist[256];
    __shared__ int cur[256];
    const int b = blockIdx.x, tid = threadIdx.x;
    if (tid < 256) {
        cnts[tid] = (tid < NBKT) ? bcur[tid] : 0;
        hist[tid] = 0;
    }
    __syncthreads();
    for (int off = 1; off < 256; off <<= 1) {
        int x = 0;
        if (tid < 256 && tid >= off) x = cnts[tid - off];
        __syncthreads();
        if (tid < 256) cnts[tid] += x;
        __syncthreads();
    }
    const int cnt = bcur[b];
    const int start = cnts[b] - cnt;  // exclusive global start of this bucket
    const size_t base = (size_t)b * BKT_CAP;
    for (int i = tid; i < cnt; i += 1024)
        atomicAdd(&hist[(temp[base + i] >> 20) & 255], 1);
    __syncthreads();
    if (tid < 256) cur[tid] = hist[tid];
    __syncthreads();
    for (int off = 1; off < 256; off <<= 1) {
        int x = 0;
        if (tid < 256 && tid >= off) x = cur[tid - off];
        __syncthreads();
        if (tid < 256) cur[tid] += x;
        __syncthreads();
    }
    const int node0 = b * 256;
    if (tid < 256) {
        int excl = cur[tid] - hist[tid];
        cur[tid] = excl;
        int node = node0 + tid;
        if (node < N_NODES) offs[node] = start + excl;
    }
    if (b == NBKT - 1 && tid == 0) offs[N_NODES] = start + cnt;
    __syncthreads();
    for (int i = tid; i < cnt; i += 1024) {
        unsigned int v = temp[base + i];
        int d = (v >> 20) & 255;
        int p = start + atomicAdd(&cur[d], 1);
        packed[p] = v & 0xFFFFFu;   // src | attr<<16
    }
}

// ---------------- Fused edge phase: wave-per-node, 8 edge slots x 8 lanes ------
// Q,K: f16 planes [2][N][128] (Q pre-scaled 1/sqrt(D)); V: fp8 plane [N][128].
// Lane sub (0..7) owns head sub's 16 elems. No cross-lane ops in inner loop.
__global__ __launch_bounds__(256) void fused_attn_kernel(
    const unsigned int* __restrict__ packed,
    const int* __restrict__ offs,
    const _Float16* __restrict__ qkh,   // [2][N][128]
    const unsigned char* __restrict__ v8p,  // [N][128]
    const float* __restrict__ btab,     // [13,8]
    __hip_bfloat16* __restrict__ out) {
    __shared__ float bLDS[104];
    const int tid = threadIdx.x;
    if (tid < 104) bLDS[tid] = btab[tid];
    __syncthreads();
    const int wave = tid >> 6, lane = tid & 63;
    const int n = blockIdx.x * 4 + wave;
    const int slot = lane >> 3, sub = lane & 7;
    const char* qh = (const char*)qkh;
    const char* kh = (const char*)(qkh + (size_t)N_NODES * 128);
    const unsigned sb = (unsigned)sub << 5;   // byte offset of head within f16 row
    U4H q0, q1;
    q0.u = *(const uint4*)(qh + ((unsigned)n << 8) + sb);
    q1.u = *(const uint4*)(qh + ((unsigned)n << 8) + sb + 16u);
    const int lo = offs[n], hi = offs[n + 1];
    const int nit = (hi - lo + 7) >> 3;
    int i = lo + slot;
    float acc[16] = {};
    float wsum = 0.f;
    bool valid = i < hi;
    unsigned int pk = valid ? packed[i] : 0u;
    unsigned src = pk & 0xFFFFu;
    U4H k0, k1;
    k0.u = *(const uint4*)(kh + (src << 8) + sb);
    k1.u = *(const uint4*)(kh + (src << 8) + sb + 16u);
    uint4 vc = *(const uint4*)(v8p + (src << 7) + (sb >> 1));
    for (int it = 0; it < nit; ++it) {
        const int inext = i + 8;
        const bool nvalid = inext < hi;
        const unsigned int pkn = nvalid ? packed[inext] : 0u;
        const unsigned srcn = pkn & 0xFFFFu;
        U4H kn0, kn1;
        kn0.u = *(const uint4*)(kh + (srcn << 8) + sb);
        kn1.u = *(const uint4*)(kh + (srcn << 8) + sb + 16u);
        uint4 vn = *(const uint4*)(v8p + (srcn << 7) + (sb >> 1));
        float p = 0.f;
        #pragma unroll
        for (int j = 0; j < 4; ++j) p = FDOT2(q0.h[j], k0.h[j], p);
        #pragma unroll
        for (int j = 0; j < 4; ++j) p = FDOT2(q1.h[j], k1.h[j], p);
        float s = p + bLDS[((pk >> 16) & 0xFu) * 8 + sub];
        float w = valid ? __expf(s) : 0.f;
        wsum += w;
        float v[16];
        cvt16(vc, v);
        #pragma unroll
        for (int j = 0; j < 16; ++j) acc[j] = fmaf(w, v[j], acc[j]);
        k0 = kn0; k1 = kn1; vc = vn; pk = pkn; valid = nvalid; i = inext;
    }
    // reduce the 8 edge-slots (lane bits 3,4,5)
    #pragma unroll
    for (int j = 0; j < 16; ++j) {
        acc[j] += __shfl_xor(acc[j], 8);
        acc[j] += __shfl_xor(acc[j], 16);
        acc[j] += __shfl_xor(acc[j], 32);
    }
    wsum += __shfl_xor(wsum, 8);
    wsum += __shfl_xor(wsum, 16);
    wsum += __shfl_xor(wsum, 32);
    if (slot == 0) {
        float inv = 1.0f / (wsum + 1e-8f);
        uint4 o0, o1;
        o0.x = packbf2(acc[0] * inv, acc[1] * inv);
        o0.y = packbf2(acc[2] * inv, acc[3] * inv);
        o0.z = packbf2(acc[4] * inv, acc[5] * inv);
        o0.w = packbf2(acc[6] * inv, acc[7] * inv);
        o1.x = packbf2(acc[8] * inv, acc[9] * inv);
        o1.y = packbf2(acc[10] * inv, acc[11] * inv);
        o1.z = packbf2(acc[12] * inv, acc[13] * inv);
        o1.w = packbf2(acc[14] * inv, acc[15] * inv);
        char* op = (char*)out + ((unsigned)n << 8) + ((unsigned)sub << 5);
        *(uint4*)op = o0;
        *(uint4*)(op + 16) = o1;
    }
}

extern "C" void kernel_launch(void* const* d_in, const int* in_sizes, int n_in,
                              void* d_out, int out_size, void* d_ws, size_t ws_size,
                              hipStream_t stream) {
    const float* x    = (const float*)d_in[0];
    const int*   ei   = (const int*)d_in[1];
    const int*   attr = (const int*)d_in[2];
    const float* Wq   = (const float*)d_in[3];
    const float* bq   = (const float*)d_in[4];
    const float* Wk   = (const float*)d_in[5];
    const float* bk   = (const float*)d_in[6];
    const float* Wv   = (const float*)d_in[7];
    const float* bv   = (const float*)d_in[8];
    const float* Wo   = (const float*)d_in[9];
    const float* bo   = (const float*)d_in[10];
    const float* ebt  = (const float*)d_in[11];
    const float* W1   = (const float*)d_in[12];
    const float* b1   = (const float*)d_in[13];
    const float* W2   = (const float*)d_in[14];
    const float* b2   = (const float*)d_in[15];
    const float* g1   = (const float*)d_in[16];
    const float* be1  = (const float*)d_in[17];
    const float* g2   = (const float*)d_in[18];
    const float* be2  = (const float*)d_in[19];
    float* out = (float*)d_out;

    char* ws = (char*)d_ws;
    const size_t szRowF = (size_t)N_NODES * HID * 4;   // 25.6 MB
    const size_t szRowB = (size_t)N_NODES * HID * 2;   // 12.8 MB
    const size_t ALIGN = 256;
    #define ALN(v) (((v) + ALIGN - 1) & ~(ALIGN - 1))
    size_t o = 0;
    __hip_bfloat16* h_buf = (__hip_bfloat16*)(ws + o); o += szRowB;
    _Float16* QKh = (_Float16*)(ws + o); o += (size_t)N_NODES * 256 * 2;        // 25.6MB (Q+K f16)
    unsigned char* V8 = (unsigned char*)(ws + o); o += (size_t)N_NODES * 128;   // 6.4MB
    unsigned int* packed = (unsigned int*)(ws + o); o += (size_t)E_EDGES * 4;   // 6.4MB
    unsigned int* temp = (unsigned int*)(ws + o); o += (size_t)NBKT * BKT_CAP * 4; // 7.2MB
    int* bcur = (int*)(ws + o); o = ALN(o + (size_t)NBKT * 4);
    int* offs = (int*)(ws + o); o = ALN(o + (size_t)(N_NODES + 1) * 4);
    __hip_bfloat16* attn_ob = (__hip_bfloat16*)(ws + o); o += szRowB;
    float* x1 = (float*)(ws + o); o += szRowF;
    __hip_bfloat16* f1 = (__hip_bfloat16*)(ws + o); o += (size_t)N_NODES * 512 * 2;  // 51.2MB
    __hip_bfloat16* Wqkvt = (__hip_bfloat16*)(ws + o); o += 384 * 128 * 2;
    __hip_bfloat16* Wot = (__hip_bfloat16*)(ws + o); o += 128 * 128 * 2;
    __hip_bfloat16* W1t = (__hip_bfloat16*)(ws + o); o += 512 * 128 * 2;
    __hip_bfloat16* W2t = (__hip_bfloat16*)(ws + o); o += 128 * 512 * 2;
    float* bqkv = (float*)(ws + o); o += 384 * 4;       // ~148 MB total
    __hip_bfloat16* h2 = h_buf;                          // alias: h dead after QKV

    // Weight conversions + fused qkv bias + bcur zeroing (single launch, first)
    wcvt_all<<<771, 256, 0, stream>>>(Wq, Wk, Wv, Wo, W1, W2, bq, bk, bv,
                                      Wqkvt, Wot, W1t, W2t, bqkv, bcur);

    // CSR build: two-level LDS-binned counting sort
    binA_kernel<<<(E_EDGES + CHUNK_A - 1) / CHUNK_A, 256, 0, stream>>>(ei, attr, bcur, temp);
    binB_kernel<<<NBKT, 1024, 0, stream>>>(bcur, temp, packed, offs);

    // LN1 + fused QKV projection (Q/K f16 planes, V fp8 plane)
    ln_kernel<<<(N_NODES + 3) / 4, 256, 0, stream>>>(x, g1, be1, h_buf, N_NODES);
    dim3 gqkv((N_NODES + 127) / 128, 3);
    gemm_mfma<128, 2><<<gqkv, 512, 0, stream>>>(h_buf, Wqkvt, bqkv, nullptr,
                                                nullptr, nullptr, QKh, V8, N_NODES, 384, 0);

    // Fused edge phase (wave per node, 8 slots x 8 lanes)
    fused_attn_kernel<<<(N_NODES + 3) / 4, 256, 0, stream>>>(packed, offs, QKh, V8, ebt, attn_ob);

    // Wo projection + residual(x) -> x1 fp32
    dim3 gm((N_NODES + 127) / 128, 1);
    gemm_mfma<128, 0><<<gm, 512, 0, stream>>>(attn_ob, Wot, bo, x, x1,
                                              nullptr, nullptr, nullptr, N_NODES, 128, 0);
    // LN2 -> h2 bf16
    ln_kernel<<<(N_NODES + 3) / 4, 256, 0, stream>>>(x1, g2, be2, h2, N_NODES);
    // FFN
    dim3 gf1((N_NODES + 127) / 128, 4);
    gemm_mfma<128, 1><<<gf1, 512, 0, stream>>>(h2, W1t, b1, nullptr, nullptr,
                                               f1, nullptr, nullptr, N_NODES, 512, 1);
    gemm_mfma<512, 0><<<gm, 512, 0, stream>>>(f1, W2t, b2, x1, out,
                                              nullptr, nullptr, nullptr, N_NODES, 128, 0);
}

// Round 8
// 234.450 us; speedup vs baseline: 5.8456x; 1.0930x over previous
//
#include <hip/hip_runtime.h>
#include <hip/hip_bf16.h>

#define N_NODES 50000
#define E_EDGES 1600000
#define HID 128
#define NH 8
#define HD 16

#define NBKT 196        // ceil(50000/256) buckets of 256 dst nodes
#define BKT_CAP 9216    // mean 8192, sd ~90 -> +11 sigma headroom
#define CHUNK_A 4096
#define EPT 16          // edges per thread in binA (256 thr * 16)

using short8 = __attribute__((ext_vector_type(8))) short;
using f32x4  = __attribute__((ext_vector_type(4))) float;
using f32x2  = __attribute__((ext_vector_type(2))) float;
typedef _Float16 h16x2 __attribute__((ext_vector_type(2)));

#if defined(__has_builtin) && __has_builtin(__builtin_amdgcn_fdot2)
#define FDOT2(a, b, c) __builtin_amdgcn_fdot2((a), (b), (c), false)
#else
__device__ __forceinline__ float FDOT2(h16x2 a, h16x2 b, float c) {
    return fmaf((float)a[0], (float)b[0], fmaf((float)a[1], (float)b[1], c));
}
#endif

__device__ __forceinline__ float wave_reduce_sum(float v) {
    #pragma unroll
    for (int off = 32; off > 0; off >>= 1) v += __shfl_xor(v, off, 64);
    return v;
}

__device__ __forceinline__ unsigned int packbf2(float a, float b) {
    __hip_bfloat162 t;
    t.x = __float2bfloat16(a);
    t.y = __float2bfloat16(b);
    unsigned int u;
    __builtin_memcpy(&u, &t, 4);
    return u;
}

__device__ __forceinline__ unsigned char fp8e(float v) {
    return (unsigned char)(__builtin_amdgcn_cvt_pk_fp8_f32(v, v, 0u, false) & 0xFFu);
}

// unpack 16 fp8 (uint4) -> 16 f32 via hw v_cvt_pk_f32_fp8
__device__ __forceinline__ void cvt16(uint4 u, float* f) {
    f32x2 t;
    t = __builtin_amdgcn_cvt_pk_f32_fp8(u.x, false); f[0] = t[0];  f[1] = t[1];
    t = __builtin_amdgcn_cvt_pk_f32_fp8(u.x, true);  f[2] = t[0];  f[3] = t[1];
    t = __builtin_amdgcn_cvt_pk_f32_fp8(u.y, false); f[4] = t[0];  f[5] = t[1];
    t = __builtin_amdgcn_cvt_pk_f32_fp8(u.y, true);  f[6] = t[0];  f[7] = t[1];
    t = __builtin_amdgcn_cvt_pk_f32_fp8(u.z, false); f[8] = t[0];  f[9] = t[1];
    t = __builtin_amdgcn_cvt_pk_f32_fp8(u.z, true);  f[10] = t[0]; f[11] = t[1];
    t = __builtin_amdgcn_cvt_pk_f32_fp8(u.w, false); f[12] = t[0]; f[13] = t[1];
    t = __builtin_amdgcn_cvt_pk_f32_fp8(u.w, true);  f[14] = t[0]; f[15] = t[1];
}

union U4H {
    uint4 u;
    h16x2 h[4];
};

// ---------------- LayerNorm: one wave per row, float2 per lane, bf16 out ----------------
__global__ __launch_bounds__(256) void ln_kernel(const float* __restrict__ x,
                                                 const float* __restrict__ g,
                                                 const float* __restrict__ b,
                                                 __hip_bfloat16* __restrict__ out, int n) {
    int wave = threadIdx.x >> 6;
    int lane = threadIdx.x & 63;
    int row = blockIdx.x * 4 + wave;
    if (row >= n) return;
    float2 v = ((const float2*)(x + (size_t)row * HID))[lane];
    float s = wave_reduce_sum(v.x + v.y);
    float mu = s * (1.0f / HID);
    float dx = v.x - mu, dy = v.y - mu;
    float q = wave_reduce_sum(dx * dx + dy * dy);
    float rstd = rsqrtf(q * (1.0f / HID) + 1e-5f);
    float2 gg = ((const float2*)g)[lane];
    float2 bb = ((const float2*)b)[lane];
    __hip_bfloat162 o;
    o.x = __float2bfloat16(dx * rstd * gg.x + bb.x);
    o.y = __float2bfloat16(dy * rstd * gg.y + bb.y);
    ((__hip_bfloat162*)(out + (size_t)row * HID))[lane] = o;
}

// ---------------- All weight converts + fused qkv bias + bcur zero, one launch --------
__global__ __launch_bounds__(256) void wcvt_all(const float* __restrict__ Wq,
                                                const float* __restrict__ Wk,
                                                const float* __restrict__ Wv,
                                                const float* __restrict__ Wo,
                                                const float* __restrict__ W1,
                                                const float* __restrict__ W2,
                                                const float* __restrict__ bq,
                                                const float* __restrict__ bk,
                                                const float* __restrict__ bv,
                                                __hip_bfloat16* __restrict__ Wqkvt,
                                                __hip_bfloat16* __restrict__ Wot,
                                                __hip_bfloat16* __restrict__ W1t,
                                                __hip_bfloat16* __restrict__ W2t,
                                                float* __restrict__ bqkv,
                                                int* __restrict__ bcur) {
    int t = blockIdx.x * 256 + threadIdx.x;
    if (t >= 196608) {
        int i = t - 196608;
        if (i < 384) bqkv[i] = i < 128 ? bq[i] : (i < 256 ? bk[i - 128] : bv[i - 256]);
        else if (i < 384 + NBKT) bcur[i - 384] = 0;
        return;
    }
    const float* W; __hip_bfloat16* Wt; int K, N, idx;
    if (t < 65536) {
        int which = t >> 14; idx = t & 16383; K = 128; N = 128;
        W = which == 0 ? Wq : which == 1 ? Wk : which == 2 ? Wv : Wo;
        Wt = which == 3 ? Wot : Wqkvt + which * 16384;
    } else if (t < 131072) { idx = t - 65536;  K = 128; N = 512; W = W1; Wt = W1t; }
    else                   { idx = t - 131072; K = 512; N = 128; W = W2; Wt = W2t; }
    int n = idx / K, k = idx - n * K;
    Wt[idx] = __float2bfloat16(W[(size_t)k * N + n]);
}

// ---------------- MFMA GEMM: C[M,NC] = A[M,K](bf16) @ Wt[NC,K](bf16)^T + bias ----------
// 512 threads = 8 waves; tile 128x128; staging via global_load_lds (dest LDS-linear,
// source pre-swizzled so LDS image == XOR-swizzled layout; reads unchanged).
// OB: 0 -> f32 out, 1 -> bf16 out,
//     2 -> QKV: plane y=0 Q f16 (scaled 0.25), y=1 K f16, y=2 V fp8
//     3 -> Wo+LN2: C=x1 f32 (acc+bias+res), Cb=bf16 LN(x1) with gw/bw params
template <int K, int OB>
__global__ __launch_bounds__(512) void gemm_mfma(const __hip_bfloat16* __restrict__ A,
                                                 const __hip_bfloat16* __restrict__ Wt,
                                                 const float* __restrict__ bias,
                                                 const float* __restrict__ res,
                                                 float* __restrict__ C,
                                                 __hip_bfloat16* __restrict__ Cb,
                                                 _Float16* __restrict__ Chh,
                                                 unsigned char* __restrict__ C8,
                                                 const float* __restrict__ gw,
                                                 const float* __restrict__ bw,
                                                 int M, int NC, int relu) {
    __shared__ short8 smem[2048 + 2048];  // A: 128x128 bf16 (32KB), B: 128x128 bf16 (32KB)
    const int row0 = blockIdx.x * 128;
    const int col0 = blockIdx.y * 128;
    const int tid = threadIdx.x;
    const int w = tid >> 6, l = tid & 63;
    const int lr = l & 15, hi = l >> 4;
    f32x4 acc[8] = {};
    for (int kk = 0; kk < K / 128; ++kk) {
        #pragma unroll
        for (int it = 0; it < 4; ++it) {
            unsigned d = tid + it * 512;
            int r = d >> 4, sd = d & 15;
            int ss = sd ^ (r & 7);
            int gr = row0 + r; if (gr >= M) gr = M - 1;
            __builtin_amdgcn_global_load_lds(
                (const __attribute__((address_space(1))) void*)(A + (size_t)gr * K + kk * 128 + ss * 8),
                (__attribute__((address_space(3))) void*)(smem + (d & ~63u)),
                16, 0, 0);
        }
        #pragma unroll
        for (int it = 0; it < 4; ++it) {
            unsigned d = tid + it * 512;
            int r = d >> 4, sd = d & 15;
            int ss = sd ^ (r & 7);
            __builtin_amdgcn_global_load_lds(
                (const __attribute__((address_space(1))) void*)(Wt + (size_t)(col0 + r) * K + kk * 128 + ss * 8),
                (__attribute__((address_space(3))) void*)(smem + 2048 + (d & ~63u)),
                16, 0, 0);
        }
        __syncthreads();
        const int ar = w * 16 + lr;
        #pragma unroll
        for (int ks = 0; ks < 4; ++ks) {
            int s = ks * 4 + hi;
            short8 a = smem[ar * 16 + (s ^ (ar & 7))];
            #pragma unroll
            for (int f = 0; f < 8; ++f) {
                int br = f * 16 + lr;
                short8 b = smem[2048 + br * 16 + (s ^ (br & 7))];
                acc[f] = __builtin_amdgcn_mfma_f32_16x16x32_bf16(a, b, acc[f], 0, 0, 0);
            }
        }
        __syncthreads();
    }
    if (OB == 3) {
        // epilogue: x1 = acc + bias + res; h2 = LN(x1)*gw+bw. Full rows in block (NC=128).
        float vv[8][4];
        float gc[8], bc[8];
        #pragma unroll
        for (int f = 0; f < 8; ++f) {
            int c = f * 16 + lr;
            gc[f] = gw[c]; bc[f] = bw[c];
            float bv = bias[c];
            #pragma unroll
            for (int j = 0; j < 4; ++j) {
                int r = row0 + w * 16 + hi * 4 + j;
                int rr = r < M ? r : M - 1;
                vv[f][j] = acc[f][j] + bv + res[(size_t)rr * NC + c];
            }
        }
        #pragma unroll
        for (int j = 0; j < 4; ++j) {
            int r = row0 + w * 16 + hi * 4 + j;
            float s = 0.f, qq = 0.f;
            #pragma unroll
            for (int f = 0; f < 8; ++f) { s += vv[f][j]; qq += vv[f][j] * vv[f][j]; }
            #pragma unroll
            for (int m = 1; m <= 8; m <<= 1) { s += __shfl_xor(s, m); qq += __shfl_xor(qq, m); }
            float mu = s * (1.0f / 128.0f);
            float rstd = rsqrtf(qq * (1.0f / 128.0f) - mu * mu + 1e-5f);
            if (r < M) {
                #pragma unroll
                for (int f = 0; f < 8; ++f) {
                    int c = f * 16 + lr;
                    C[(size_t)r * NC + c] = vv[f][j];
                    Cb[(size_t)r * NC + c] = __float2bfloat16((vv[f][j] - mu) * rstd * gc[f] + bc[f]);
                }
            }
        }
        return;
    }
    const float scl = (OB == 2 && blockIdx.y == 0) ? 0.25f : 1.0f;
    #pragma unroll
    for (int f = 0; f < 8; ++f) {
        int c = col0 + f * 16 + lr;
        float bv = bias[c];
        #pragma unroll
        for (int j = 0; j < 4; ++j) {
            int r = row0 + w * 16 + hi * 4 + j;
            if (r < M) {
                float v = acc[f][j] + bv;
                if (relu) v = fmaxf(v, 0.f);
                if (res) v += res[(size_t)r * NC + c];
                if (OB == 0) C[(size_t)r * NC + c] = v;
                else if (OB == 1) Cb[(size_t)r * NC + c] = __float2bfloat16(v);
                else {
                    if (blockIdx.y < 2)
                        Chh[(size_t)blockIdx.y * N_NODES * 128 + (size_t)r * 128 + (c & 127)] =
                            (_Float16)(v * scl);
                    else
                        C8[(size_t)r * 128 + (c & 127)] = fp8e(v);
                }
            }
        }
    }
}

// ---------------- binA: bucket edges (bucket = dst>>8) with LDS staging -------------
// temp value layout: src(16b) | attr(4b)<<16 | (dst&255)<<20
__global__ __launch_bounds__(256) void binA_kernel(const int* __restrict__ ei,
                                                   const int* __restrict__ attr,
                                                   int* __restrict__ bcur,
                                                   unsigned int* __restrict__ temp) {
    __shared__ unsigned int sval[CHUNK_A];
    __shared__ unsigned short sbkt[CHUNK_A];
    __shared__ int hist[NBKT];
    __shared__ int lofs[NBKT];
    __shared__ int gbase[NBKT];
    __shared__ int lcur[NBKT];
    __shared__ int sc[256];
    const int tid = threadIdx.x;
    const int e0 = blockIdx.x * CHUNK_A;
    const int n = min(CHUNK_A, E_EDGES - e0);
    for (int i = tid; i < NBKT; i += 256) hist[i] = 0;
    __syncthreads();
    unsigned int v[EPT];
    short bk[EPT];
    #pragma unroll
    for (int j = 0; j < EPT; ++j) {
        int i = tid + j * 256;
        bk[j] = -1;
        v[j] = 0;
        if (i < n) {
            int e = e0 + i;
            int src = ei[e];
            int dst = ei[E_EDGES + e];
            int a = attr[e]; a = min(max(a, 0), 12);
            v[j] = (unsigned)src | ((unsigned)a << 16) | ((unsigned)(dst & 255) << 20);
            int b = dst >> 8;
            bk[j] = (short)b;
            atomicAdd(&hist[b], 1);
        }
    }
    __syncthreads();
    sc[tid] = (tid < NBKT) ? hist[tid] : 0;
    __syncthreads();
    for (int off = 1; off < 256; off <<= 1) {
        int x = (tid >= off) ? sc[tid - off] : 0;
        __syncthreads();
        sc[tid] += x;
        __syncthreads();
    }
    if (tid < NBKT) {
        int h = hist[tid];
        lofs[tid] = sc[tid] - h;     // exclusive prefix within block
        lcur[tid] = 0;
        gbase[tid] = h ? atomicAdd(&bcur[tid], h) : 0;
    }
    __syncthreads();
    #pragma unroll
    for (int j = 0; j < EPT; ++j) {
        if (bk[j] >= 0) {
            int p = lofs[bk[j]] + atomicAdd(&lcur[bk[j]], 1);
            sval[p] = v[j];
            sbkt[p] = (unsigned short)bk[j];
        }
    }
    __syncthreads();
    for (int i = tid; i < n; i += 256) {
        int b = sbkt[i];
        temp[(size_t)b * BKT_CAP + gbase[b] + (i - lofs[b])] = sval[i];
    }
}

// ---------------- binB: per-bucket counting sort by dst low byte; writes offs+packed --
__global__ __launch_bounds__(1024) void binB_kernel(const int* __restrict__ bcur,
                                                    const unsigned int* __restrict__ temp,
                                                    unsigned int* __restrict__ packed,
                                                    int* __restrict__ offs) {
    __shared__ int cnts[256];
    __shared__ int hist[256];
    __shared__ int cur[256];
    const int b = blockIdx.x, tid = threadIdx.x;
    if (tid < 256) {
        cnts[tid] = (tid < NBKT) ? bcur[tid] : 0;
        hist[tid] = 0;
    }
    __syncthreads();
    for (int off = 1; off < 256; off <<= 1) {
        int x = 0;
        if (tid < 256 && tid >= off) x = cnts[tid - off];
        __syncthreads();
        if (tid < 256) cnts[tid] += x;
        __syncthreads();
    }
    const int cnt = bcur[b];
    const int start = cnts[b] - cnt;  // exclusive global start of this bucket
    const size_t base = (size_t)b * BKT_CAP;
    for (int i = tid; i < cnt; i += 1024)
        atomicAdd(&hist[(temp[base + i] >> 20) & 255], 1);
    __syncthreads();
    if (tid < 256) cur[tid] = hist[tid];
    __syncthreads();
    for (int off = 1; off < 256; off <<= 1) {
        int x = 0;
        if (tid < 256 && tid >= off) x = cur[tid - off];
        __syncthreads();
        if (tid < 256) cur[tid] += x;
        __syncthreads();
    }
    const int node0 = b * 256;
    if (tid < 256) {
        int excl = cur[tid] - hist[tid];
        cur[tid] = excl;
        int node = node0 + tid;
        if (node < N_NODES) offs[node] = start + excl;
    }
    if (b == NBKT - 1 && tid == 0) offs[N_NODES] = start + cnt;
    __syncthreads();
    for (int i = tid; i < cnt; i += 1024) {
        unsigned int v = temp[base + i];
        int d = (v >> 20) & 255;
        int p = start + atomicAdd(&cur[d], 1);
        packed[p] = v & 0xFFFFFu;   // src | attr<<16
    }
}

// ---------------- Fused edge phase: wave-per-node, 8 edge slots x 8 lanes ------
// Q,K: f16 planes [2][N][128] (Q pre-scaled 1/sqrt(D)); V: fp8 plane [N][128].
// Lane sub (0..7) owns head sub's 16 elems. packed[] prefetched 2 iterations ahead
// so the K/V gather addresses never wait on the same-iteration index load.
__global__ __launch_bounds__(256) void fused_attn_kernel(
    const unsigned int* __restrict__ packed,
    const int* __restrict__ offs,
    const _Float16* __restrict__ qkh,   // [2][N][128]
    const unsigned char* __restrict__ v8p,  // [N][128]
    const float* __restrict__ btab,     // [13,8]
    __hip_bfloat16* __restrict__ out) {
    __shared__ float bLDS[104];
    const int tid = threadIdx.x;
    if (tid < 104) bLDS[tid] = btab[tid];
    __syncthreads();
    const int wave = tid >> 6, lane = tid & 63;
    const int n = blockIdx.x * 4 + wave;
    const int slot = lane >> 3, sub = lane & 7;
    const char* qh = (const char*)qkh;
    const char* kh = (const char*)(qkh + (size_t)N_NODES * 128);
    const unsigned sb = (unsigned)sub << 5;   // byte offset of head within f16 row
    U4H q0, q1;
    q0.u = *(const uint4*)(qh + ((unsigned)n << 8) + sb);
    q1.u = *(const uint4*)(qh + ((unsigned)n << 8) + sb + 16u);
    const int lo = offs[n], hi = offs[n + 1];
    const int nit = (hi - lo + 7) >> 3;
    int i = lo + slot;
    float acc[16] = {};
    float wsum = 0.f;
    bool valid = i < hi;
    unsigned int pk = valid ? packed[i] : 0u;
    int i1 = i + 8;
    bool valid1 = i1 < hi;
    unsigned int pk1 = valid1 ? packed[i1] : 0u;
    unsigned src = pk & 0xFFFFu;
    U4H k0, k1;
    k0.u = *(const uint4*)(kh + (src << 8) + sb);
    k1.u = *(const uint4*)(kh + (src << 8) + sb + 16u);
    uint4 vc = *(const uint4*)(v8p + (src << 7) + (sb >> 1));
    for (int it = 0; it < nit; ++it) {
        const int i2 = i1 + 8;
        const bool valid2 = i2 < hi;
        const unsigned int pk2 = valid2 ? packed[i2] : 0u;   // 2-ahead index prefetch
        const unsigned srcn = pk1 & 0xFFFFu;
        U4H kn0, kn1;
        kn0.u = *(const uint4*)(kh + (srcn << 8) + sb);
        kn1.u = *(const uint4*)(kh + (srcn << 8) + sb + 16u);
        uint4 vn = *(const uint4*)(v8p + (srcn << 7) + (sb >> 1));
        float p = 0.f;
        #pragma unroll
        for (int j = 0; j < 4; ++j) p = FDOT2(q0.h[j], k0.h[j], p);
        #pragma unroll
        for (int j = 0; j < 4; ++j) p = FDOT2(q1.h[j], k1.h[j], p);
        float s = p + bLDS[((pk >> 16) & 0xFu) * 8 + sub];
        float w = valid ? __expf(s) : 0.f;
        wsum += w;
        float v[16];
        cvt16(vc, v);
        #pragma unroll
        for (int j = 0; j < 16; ++j) acc[j] = fmaf(w, v[j], acc[j]);
        k0 = kn0; k1 = kn1; vc = vn;
        pk = pk1; valid = valid1;
        pk1 = pk2; valid1 = valid2; i1 = i2;
    }
    // reduce the 8 edge-slots (lane bits 3,4,5)
    #pragma unroll
    for (int j = 0; j < 16; ++j) {
        acc[j] += __shfl_xor(acc[j], 8);
        acc[j] += __shfl_xor(acc[j], 16);
        acc[j] += __shfl_xor(acc[j], 32);
    }
    wsum += __shfl_xor(wsum, 8);
    wsum += __shfl_xor(wsum, 16);
    wsum += __shfl_xor(wsum, 32);
    if (slot == 0) {
        float inv = 1.0f / (wsum + 1e-8f);
        uint4 o0, o1;
        o0.x = packbf2(acc[0] * inv, acc[1] * inv);
        o0.y = packbf2(acc[2] * inv, acc[3] * inv);
        o0.z = packbf2(acc[4] * inv, acc[5] * inv);
        o0.w = packbf2(acc[6] * inv, acc[7] * inv);
        o1.x = packbf2(acc[8] * inv, acc[9] * inv);
        o1.y = packbf2(acc[10] * inv, acc[11] * inv);
        o1.z = packbf2(acc[12] * inv, acc[13] * inv);
        o1.w = packbf2(acc[14] * inv, acc[15] * inv);
        char* op = (char*)out + ((unsigned)n << 8) + ((unsigned)sub << 5);
        *(uint4*)op = o0;
        *(uint4*)(op + 16) = o1;
    }
}

extern "C" void kernel_launch(void* const* d_in, const int* in_sizes, int n_in,
                              void* d_out, int out_size, void* d_ws, size_t ws_size,
                              hipStream_t stream) {
    const float* x    = (const float*)d_in[0];
    const int*   ei   = (const int*)d_in[1];
    const int*   attr = (const int*)d_in[2];
    const float* Wq   = (const float*)d_in[3];
    const float* bq   = (const float*)d_in[4];
    const float* Wk   = (const float*)d_in[5];
    const float* bk   = (const float*)d_in[6];
    const float* Wv   = (const float*)d_in[7];
    const float* bv   = (const float*)d_in[8];
    const float* Wo   = (const float*)d_in[9];
    const float* bo   = (const float*)d_in[10];
    const float* ebt  = (const float*)d_in[11];
    const float* W1   = (const float*)d_in[12];
    const float* b1   = (const float*)d_in[13];
    const float* W2   = (const float*)d_in[14];
    const float* b2   = (const float*)d_in[15];
    const float* g1   = (const float*)d_in[16];
    const float* be1  = (const float*)d_in[17];
    const float* g2   = (const float*)d_in[18];
    const float* be2  = (const float*)d_in[19];
    float* out = (float*)d_out;

    char* ws = (char*)d_ws;
    const size_t szRowF = (size_t)N_NODES * HID * 4;   // 25.6 MB
    const size_t szRowB = (size_t)N_NODES * HID * 2;   // 12.8 MB
    const size_t ALIGN = 256;
    #define ALN(v) (((v) + ALIGN - 1) & ~(ALIGN - 1))
    size_t o = 0;
    __hip_bfloat16* h_buf = (__hip_bfloat16*)(ws + o); o += szRowB;
    _Float16* QKh = (_Float16*)(ws + o); o += (size_t)N_NODES * 256 * 2;        // 25.6MB (Q+K f16)
    unsigned char* V8 = (unsigned char*)(ws + o); o += (size_t)N_NODES * 128;   // 6.4MB
    unsigned int* packed = (unsigned int*)(ws + o); o += (size_t)E_EDGES * 4;   // 6.4MB
    unsigned int* temp = (unsigned int*)(ws + o); o += (size_t)NBKT * BKT_CAP * 4; // 7.2MB
    int* bcur = (int*)(ws + o); o = ALN(o + (size_t)NBKT * 4);
    int* offs = (int*)(ws + o); o = ALN(o + (size_t)(N_NODES + 1) * 4);
    __hip_bfloat16* attn_ob = (__hip_bfloat16*)(ws + o); o += szRowB;
    float* x1 = (float*)(ws + o); o += szRowF;
    __hip_bfloat16* f1 = (__hip_bfloat16*)(ws + o); o += (size_t)N_NODES * 512 * 2;  // 51.2MB
    __hip_bfloat16* Wqkvt = (__hip_bfloat16*)(ws + o); o += 384 * 128 * 2;
    __hip_bfloat16* Wot = (__hip_bfloat16*)(ws + o); o += 128 * 128 * 2;
    __hip_bfloat16* W1t = (__hip_bfloat16*)(ws + o); o += 512 * 128 * 2;
    __hip_bfloat16* W2t = (__hip_bfloat16*)(ws + o); o += 128 * 512 * 2;
    float* bqkv = (float*)(ws + o); o += 384 * 4;       // ~148 MB total
    __hip_bfloat16* h2 = h_buf;                          // alias: h dead after QKV

    // Weight conversions + fused qkv bias + bcur zeroing (single launch, first)
    wcvt_all<<<771, 256, 0, stream>>>(Wq, Wk, Wv, Wo, W1, W2, bq, bk, bv,
                                      Wqkvt, Wot, W1t, W2t, bqkv, bcur);

    // CSR build: two-level LDS-binned counting sort
    binA_kernel<<<(E_EDGES + CHUNK_A - 1) / CHUNK_A, 256, 0, stream>>>(ei, attr, bcur, temp);
    binB_kernel<<<NBKT, 1024, 0, stream>>>(bcur, temp, packed, offs);

    // LN1 + fused QKV projection (Q/K f16 planes, V fp8 plane)
    ln_kernel<<<(N_NODES + 3) / 4, 256, 0, stream>>>(x, g1, be1, h_buf, N_NODES);
    dim3 gqkv((N_NODES + 127) / 128, 3);
    gemm_mfma<128, 2><<<gqkv, 512, 0, stream>>>(h_buf, Wqkvt, bqkv, nullptr,
                                                nullptr, nullptr, QKh, V8,
                                                nullptr, nullptr, N_NODES, 384, 0);

    // Fused edge phase (wave per node, 8 slots x 8 lanes)
    fused_attn_kernel<<<(N_NODES + 3) / 4, 256, 0, stream>>>(packed, offs, QKh, V8, ebt, attn_ob);

    // Wo projection + residual(x) + fused LN2 -> x1 f32, h2 bf16
    dim3 gm((N_NODES + 127) / 128, 1);
    gemm_mfma<128, 3><<<gm, 512, 0, stream>>>(attn_ob, Wot, bo, x, x1,
                                              h2, nullptr, nullptr, g2, be2, N_NODES, 128, 0);

    // FFN
    dim3 gf1((N_NODES + 127) / 128, 4);
    gemm_mfma<128, 1><<<gf1, 512, 0, stream>>>(h2, W1t, b1, nullptr, nullptr,
                                               f1, nullptr, nullptr, nullptr, nullptr, N_NODES, 512, 1);
    gemm_mfma<512, 0><<<gm, 512, 0, stream>>>(f1, W2t, b2, x1, out,
                                              nullptr, nullptr, nullptr, nullptr, nullptr, N_NODES, 128, 0);
}

// Round 9
// 228.379 us; speedup vs baseline: 6.0010x; 1.0266x over previous
//
#include <hip/hip_runtime.h>
#include <hip/hip_bf16.h>

#define N_NODES 50000
#define E_EDGES 1600000
#define HID 128
#define NH 8
#define HD 16

#define NBKT 196        // ceil(50000/256) buckets of 256 dst nodes
#define BKT_CAP 9216    // mean 8192, sd ~90 -> +11 sigma headroom
#define CHUNK_A 4096
#define EPT 16          // edges per thread in binA (256 thr * 16)
#define BINA_BLOCKS ((E_EDGES + CHUNK_A - 1) / CHUNK_A)   // 391
#define WCVT_BLOCKS 771
#define LN_BLOCKS 12500

using short8 = __attribute__((ext_vector_type(8))) short;
using f32x4  = __attribute__((ext_vector_type(4))) float;
using f32x2  = __attribute__((ext_vector_type(2))) float;
typedef _Float16 h16x2 __attribute__((ext_vector_type(2)));

#if defined(__has_builtin) && __has_builtin(__builtin_amdgcn_fdot2)
#define FDOT2(a, b, c) __builtin_amdgcn_fdot2((a), (b), (c), false)
#else
__device__ __forceinline__ float FDOT2(h16x2 a, h16x2 b, float c) {
    return fmaf((float)a[0], (float)b[0], fmaf((float)a[1], (float)b[1], c));
}
#endif

__device__ __forceinline__ float wave_reduce_sum(float v) {
    #pragma unroll
    for (int off = 32; off > 0; off >>= 1) v += __shfl_xor(v, off, 64);
    return v;
}

__device__ __forceinline__ unsigned int packbf2(float a, float b) {
    __hip_bfloat162 t;
    t.x = __float2bfloat16(a);
    t.y = __float2bfloat16(b);
    unsigned int u;
    __builtin_memcpy(&u, &t, 4);
    return u;
}

__device__ __forceinline__ unsigned char fp8e(float v) {
    return (unsigned char)(__builtin_amdgcn_cvt_pk_fp8_f32(v, v, 0u, false) & 0xFFu);
}

union U4H {
    uint4 u;
    h16x2 h[4];
};

struct KV {
    U4H k0, k1;
    uint4 v;
};

// ================= prep kernel: binA + weight-convert + LN1 in one launch ==========
// blocks [0,391): binA; [391,1162): wcvt; [1162,13662): LN1 (4 rows each).
// bcur must be zeroed by hipMemsetAsync BEFORE this kernel (binA atomics race else).
__global__ __launch_bounds__(256) void prep_kernel(
    const int* __restrict__ ei, const int* __restrict__ attr,
    int* __restrict__ bcur, unsigned int* __restrict__ temp,
    const float* __restrict__ Wq, const float* __restrict__ Wk,
    const float* __restrict__ Wv, const float* __restrict__ Wo,
    const float* __restrict__ W1, const float* __restrict__ W2,
    const float* __restrict__ bq, const float* __restrict__ bk,
    const float* __restrict__ bv,
    __hip_bfloat16* __restrict__ Wqkvt, __hip_bfloat16* __restrict__ Wot,
    __hip_bfloat16* __restrict__ W1t, __hip_bfloat16* __restrict__ W2t,
    float* __restrict__ bqkv,
    const float* __restrict__ x, const float* __restrict__ g1,
    const float* __restrict__ be1, __hip_bfloat16* __restrict__ h_out) {
    __shared__ unsigned int sval[CHUNK_A];
    __shared__ unsigned short sbkt[CHUNK_A];
    __shared__ int hist[NBKT];
    __shared__ int lofs[NBKT];
    __shared__ int gbase[NBKT];
    __shared__ int lcur[NBKT];
    __shared__ int sc[256];
    const int b = blockIdx.x;
    const int tid = threadIdx.x;
    if (b < BINA_BLOCKS) {
        // ---- binA: bucket edges (bucket = dst>>8) with LDS staging ----
        const int e0 = b * CHUNK_A;
        const int n = min(CHUNK_A, E_EDGES - e0);
        for (int i = tid; i < NBKT; i += 256) hist[i] = 0;
        __syncthreads();
        unsigned int v[EPT];
        short bk_[EPT];
        #pragma unroll
        for (int j = 0; j < EPT; ++j) {
            int i = tid + j * 256;
            bk_[j] = -1;
            v[j] = 0;
            if (i < n) {
                int e = e0 + i;
                int src = ei[e];
                int dst = ei[E_EDGES + e];
                int a = attr[e]; a = min(max(a, 0), 12);
                v[j] = (unsigned)src | ((unsigned)a << 16) | ((unsigned)(dst & 255) << 20);
                int bb = dst >> 8;
                bk_[j] = (short)bb;
                atomicAdd(&hist[bb], 1);
            }
        }
        __syncthreads();
        sc[tid] = (tid < NBKT) ? hist[tid] : 0;
        __syncthreads();
        for (int off = 1; off < 256; off <<= 1) {
            int xx = (tid >= off) ? sc[tid - off] : 0;
            __syncthreads();
            sc[tid] += xx;
            __syncthreads();
        }
        if (tid < NBKT) {
            int h = hist[tid];
            lofs[tid] = sc[tid] - h;
            lcur[tid] = 0;
            gbase[tid] = h ? atomicAdd(&bcur[tid], h) : 0;
        }
        __syncthreads();
        #pragma unroll
        for (int j = 0; j < EPT; ++j) {
            if (bk_[j] >= 0) {
                int p = lofs[bk_[j]] + atomicAdd(&lcur[bk_[j]], 1);
                sval[p] = v[j];
                sbkt[p] = (unsigned short)bk_[j];
            }
        }
        __syncthreads();
        for (int i = tid; i < n; i += 256) {
            int bb = sbkt[i];
            temp[(size_t)bb * BKT_CAP + gbase[bb] + (i - lofs[bb])] = sval[i];
        }
    } else if (b < BINA_BLOCKS + WCVT_BLOCKS) {
        // ---- wcvt: Wt[n][k] = bf16(W[k][n]); fused qkv bias ----
        int t = (b - BINA_BLOCKS) * 256 + tid;
        if (t >= 196608) {
            int i = t - 196608;
            if (i < 384) bqkv[i] = i < 128 ? bq[i] : (i < 256 ? bk[i - 128] : bv[i - 256]);
            return;
        }
        const float* W; __hip_bfloat16* Wt; int K, N, idx;
        if (t < 65536) {
            int which = t >> 14; idx = t & 16383; K = 128; N = 128;
            W = which == 0 ? Wq : which == 1 ? Wk : which == 2 ? Wv : Wo;
            Wt = which == 3 ? Wot : Wqkvt + which * 16384;
        } else if (t < 131072) { idx = t - 65536;  K = 128; N = 512; W = W1; Wt = W1t; }
        else                   { idx = t - 131072; K = 512; N = 128; W = W2; Wt = W2t; }
        int n = idx / K, k = idx - n * K;
        Wt[idx] = __float2bfloat16(W[(size_t)k * N + n]);
    } else {
        // ---- LN1: one wave per row ----
        int wave = tid >> 6;
        int lane = tid & 63;
        int row = (b - BINA_BLOCKS - WCVT_BLOCKS) * 4 + wave;
        if (row >= N_NODES) return;
        float2 v = ((const float2*)(x + (size_t)row * HID))[lane];
        float s = wave_reduce_sum(v.x + v.y);
        float mu = s * (1.0f / HID);
        float dx = v.x - mu, dy = v.y - mu;
        float q = wave_reduce_sum(dx * dx + dy * dy);
        float rstd = rsqrtf(q * (1.0f / HID) + 1e-5f);
        float2 gg = ((const float2*)g1)[lane];
        float2 bb = ((const float2*)be1)[lane];
        __hip_bfloat162 o;
        o.x = __float2bfloat16(dx * rstd * gg.x + bb.x);
        o.y = __float2bfloat16(dy * rstd * gg.y + bb.y);
        ((__hip_bfloat162*)(h_out + (size_t)row * HID))[lane] = o;
    }
}

// ---------------- MFMA GEMM: C[M,NC] = A[M,K](bf16) @ Wt[NC,K](bf16)^T + bias ----------
// 512 threads = 8 waves; tile 128x128; staging via global_load_lds (dest LDS-linear,
// source pre-swizzled so LDS image == XOR-swizzled layout; reads unchanged).
// OB: 0 -> f32 out, 1 -> bf16 out,
//     2 -> QKV: plane y=0 Q f16 (scaled 0.25), y=1 K f16, y=2 V fp8
//     3 -> Wo+LN2: C=x1 f32 (acc+bias+res), Cb=bf16 LN(x1) with gw/bw params
template <int K, int OB>
__global__ __launch_bounds__(512) void gemm_mfma(const __hip_bfloat16* __restrict__ A,
                                                 const __hip_bfloat16* __restrict__ Wt,
                                                 const float* __restrict__ bias,
                                                 const float* __restrict__ res,
                                                 float* __restrict__ C,
                                                 __hip_bfloat16* __restrict__ Cb,
                                                 _Float16* __restrict__ Chh,
                                                 unsigned char* __restrict__ C8,
                                                 const float* __restrict__ gw,
                                                 const float* __restrict__ bw,
                                                 int M, int NC, int relu) {
    __shared__ short8 smem[2048 + 2048];  // A: 128x128 bf16 (32KB), B: 128x128 bf16 (32KB)
    const int row0 = blockIdx.x * 128;
    const int col0 = blockIdx.y * 128;
    const int tid = threadIdx.x;
    const int w = tid >> 6, l = tid & 63;
    const int lr = l & 15, hi = l >> 4;
    f32x4 acc[8] = {};
    for (int kk = 0; kk < K / 128; ++kk) {
        #pragma unroll
        for (int it = 0; it < 4; ++it) {
            unsigned d = tid + it * 512;
            int r = d >> 4, sd = d & 15;
            int ss = sd ^ (r & 7);
            int gr = row0 + r; if (gr >= M) gr = M - 1;
            __builtin_amdgcn_global_load_lds(
                (const __attribute__((address_space(1))) void*)(A + (size_t)gr * K + kk * 128 + ss * 8),
                (__attribute__((address_space(3))) void*)(smem + (d & ~63u)),
                16, 0, 0);
        }
        #pragma unroll
        for (int it = 0; it < 4; ++it) {
            unsigned d = tid + it * 512;
            int r = d >> 4, sd = d & 15;
            int ss = sd ^ (r & 7);
            __builtin_amdgcn_global_load_lds(
                (const __attribute__((address_space(1))) void*)(Wt + (size_t)(col0 + r) * K + kk * 128 + ss * 8),
                (__attribute__((address_space(3))) void*)(smem + 2048 + (d & ~63u)),
                16, 0, 0);
        }
        __syncthreads();
        const int ar = w * 16 + lr;
        #pragma unroll
        for (int ks = 0; ks < 4; ++ks) {
            int s = ks * 4 + hi;
            short8 a = smem[ar * 16 + (s ^ (ar & 7))];
            #pragma unroll
            for (int f = 0; f < 8; ++f) {
                int br = f * 16 + lr;
                short8 b = smem[2048 + br * 16 + (s ^ (br & 7))];
                acc[f] = __builtin_amdgcn_mfma_f32_16x16x32_bf16(a, b, acc[f], 0, 0, 0);
            }
        }
        __syncthreads();
    }
    if (OB == 3) {
        float vv[8][4];
        float gc[8], bc[8];
        #pragma unroll
        for (int f = 0; f < 8; ++f) {
            int c = f * 16 + lr;
            gc[f] = gw[c]; bc[f] = bw[c];
            float bv = bias[c];
            #pragma unroll
            for (int j = 0; j < 4; ++j) {
                int r = row0 + w * 16 + hi * 4 + j;
                int rr = r < M ? r : M - 1;
                vv[f][j] = acc[f][j] + bv + res[(size_t)rr * NC + c];
            }
        }
        #pragma unroll
        for (int j = 0; j < 4; ++j) {
            int r = row0 + w * 16 + hi * 4 + j;
            float s = 0.f, qq = 0.f;
            #pragma unroll
            for (int f = 0; f < 8; ++f) { s += vv[f][j]; qq += vv[f][j] * vv[f][j]; }
            #pragma unroll
            for (int m = 1; m <= 8; m <<= 1) { s += __shfl_xor(s, m); qq += __shfl_xor(qq, m); }
            float mu = s * (1.0f / 128.0f);
            float rstd = rsqrtf(qq * (1.0f / 128.0f) - mu * mu + 1e-5f);
            if (r < M) {
                #pragma unroll
                for (int f = 0; f < 8; ++f) {
                    int c = f * 16 + lr;
                    C[(size_t)r * NC + c] = vv[f][j];
                    Cb[(size_t)r * NC + c] = __float2bfloat16((vv[f][j] - mu) * rstd * gc[f] + bc[f]);
                }
            }
        }
        return;
    }
    const float scl = (OB == 2 && blockIdx.y == 0) ? 0.25f : 1.0f;
    #pragma unroll
    for (int f = 0; f < 8; ++f) {
        int c = col0 + f * 16 + lr;
        float bv = bias[c];
        #pragma unroll
        for (int j = 0; j < 4; ++j) {
            int r = row0 + w * 16 + hi * 4 + j;
            if (r < M) {
                float v = acc[f][j] + bv;
                if (relu) v = fmaxf(v, 0.f);
                if (res) v += res[(size_t)r * NC + c];
                if (OB == 0) C[(size_t)r * NC + c] = v;
                else if (OB == 1) Cb[(size_t)r * NC + c] = __float2bfloat16(v);
                else {
                    if (blockIdx.y < 2)
                        Chh[(size_t)blockIdx.y * N_NODES * 128 + (size_t)r * 128 + (c & 127)] =
                            (_Float16)(v * scl);
                    else
                        C8[(size_t)r * 128 + (c & 127)] = fp8e(v);
                }
            }
        }
    }
}

// ---------------- binB: per-bucket counting sort by dst low byte; writes offs+packed --
__global__ __launch_bounds__(1024) void binB_kernel(const int* __restrict__ bcur,
                                                    const unsigned int* __restrict__ temp,
                                                    unsigned int* __restrict__ packed,
                                                    int* __restrict__ offs) {
    __shared__ int cnts[256];
    __shared__ int hist[256];
    __shared__ int cur[256];
    const int b = blockIdx.x, tid = threadIdx.x;
    if (tid < 256) {
        cnts[tid] = (tid < NBKT) ? bcur[tid] : 0;
        hist[tid] = 0;
    }
    __syncthreads();
    for (int off = 1; off < 256; off <<= 1) {
        int x = 0;
        if (tid < 256 && tid >= off) x = cnts[tid - off];
        __syncthreads();
        if (tid < 256) cnts[tid] += x;
        __syncthreads();
    }
    const int cnt = bcur[b];
    const int start = cnts[b] - cnt;  // exclusive global start of this bucket
    const size_t base = (size_t)b * BKT_CAP;
    for (int i = tid; i < cnt; i += 1024)
        atomicAdd(&hist[(temp[base + i] >> 20) & 255], 1);
    __syncthreads();
    if (tid < 256) cur[tid] = hist[tid];
    __syncthreads();
    for (int off = 1; off < 256; off <<= 1) {
        int x = 0;
        if (tid < 256 && tid >= off) x = cur[tid - off];
        __syncthreads();
        if (tid < 256) cur[tid] += x;
        __syncthreads();
    }
    const int node0 = b * 256;
    if (tid < 256) {
        int excl = cur[tid] - hist[tid];
        cur[tid] = excl;
        int node = node0 + tid;
        if (node < N_NODES) offs[node] = start + excl;
    }
    if (b == NBKT - 1 && tid == 0) offs[N_NODES] = start + cnt;
    __syncthreads();
    for (int i = tid; i < cnt; i += 1024) {
        unsigned int v = temp[base + i];
        int d = (v >> 20) & 255;
        int p = start + atomicAdd(&cur[d], 1);
        packed[p] = v & 0xFFFFFu;   // src | attr<<16
    }
}

// ---------------- Fused edge phase: wave-per-node, 8 edge slots x 8 lanes ------
// Q,K: f16 planes [2][N][128] (Q pre-scaled 1/sqrt(D)); V: fp8 plane [N][128].
// Lane sub (0..7) owns head sub's 16 elems. Index pipeline 3-ahead; K/V gathers
// 2-deep (~6 loads in flight/wave). V accumulated via packed f32 (v_pk_fma_f32).
__global__ __launch_bounds__(256) void fused_attn_kernel(
    const unsigned int* __restrict__ packed,
    const int* __restrict__ offs,
    const _Float16* __restrict__ qkh,   // [2][N][128]
    const unsigned char* __restrict__ v8p,  // [N][128]
    const float* __restrict__ btab,     // [13,8]
    __hip_bfloat16* __restrict__ out) {
    __shared__ float bLDS[104];
    const int tid = threadIdx.x;
    if (tid < 104) bLDS[tid] = btab[tid];
    __syncthreads();
    const int wave = tid >> 6, lane = tid & 63;
    const int n = blockIdx.x * 4 + wave;
    const int slot = lane >> 3, sub = lane & 7;
    const char* qh = (const char*)qkh;
    const char* kh = (const char*)(qkh + (size_t)N_NODES * 128);
    const unsigned sb = (unsigned)sub << 5;   // byte offset of head within f16 row
    U4H q0, q1;
    q0.u = *(const uint4*)(qh + ((unsigned)n << 8) + sb);
    q1.u = *(const uint4*)(qh + ((unsigned)n << 8) + sb + 16u);
    const int lo = offs[n], hi = offs[n + 1];
    const int nit = (hi - lo + 7) >> 3;
    f32x2 acc2[8] = {};
    float wsum = 0.f;
    // index pipeline (3 ahead), K/V pipeline (2 deep)
    int i0 = lo + slot;
    bool vd0 = i0 < hi;           unsigned pk0 = vd0 ? packed[i0] : 0u;
    bool vd1 = i0 + 8 < hi;       unsigned pk1 = vd1 ? packed[i0 + 8] : 0u;
    bool vd2 = i0 + 16 < hi;      unsigned pk2 = vd2 ? packed[i0 + 16] : 0u;
    int inext = i0 + 24;
    KV kv0, kv1;
    {
        unsigned r0 = (pk0 & 0xFFFFu);
        kv0.k0.u = *(const uint4*)(kh + (r0 << 8) + sb);
        kv0.k1.u = *(const uint4*)(kh + (r0 << 8) + sb + 16u);
        kv0.v = *(const uint4*)(v8p + (r0 << 7) + (sb >> 1));
        unsigned r1 = (pk1 & 0xFFFFu);
        kv1.k0.u = *(const uint4*)(kh + (r1 << 8) + sb);
        kv1.k1.u = *(const uint4*)(kh + (r1 << 8) + sb + 16u);
        kv1.v = *(const uint4*)(v8p + (r1 << 7) + (sb >> 1));
    }
    for (int it = 0; it < nit; ++it) {
        const bool vd3 = inext < hi;
        const unsigned pk3 = vd3 ? packed[inext] : 0u;
        KV kv2;
        {
            unsigned r2 = (pk2 & 0xFFFFu);
            kv2.k0.u = *(const uint4*)(kh + (r2 << 8) + sb);
            kv2.k1.u = *(const uint4*)(kh + (r2 << 8) + sb + 16u);
            kv2.v = *(const uint4*)(v8p + (r2 << 7) + (sb >> 1));
        }
        float p = 0.f;
        #pragma unroll
        for (int j = 0; j < 4; ++j) p = FDOT2(q0.h[j], kv0.k0.h[j], p);
        #pragma unroll
        for (int j = 0; j < 4; ++j) p = FDOT2(q1.h[j], kv0.k1.h[j], p);
        float s = p + bLDS[((pk0 >> 16) & 0xFu) * 8 + sub];
        float w = vd0 ? __expf(s) : 0.f;
        wsum += w;
        f32x2 w2; w2[0] = w; w2[1] = w;
        f32x2 t;
        t = __builtin_amdgcn_cvt_pk_f32_fp8(kv0.v.x, false); acc2[0] = t * w2 + acc2[0];
        t = __builtin_amdgcn_cvt_pk_f32_fp8(kv0.v.x, true);  acc2[1] = t * w2 + acc2[1];
        t = __builtin_amdgcn_cvt_pk_f32_fp8(kv0.v.y, false); acc2[2] = t * w2 + acc2[2];
        t = __builtin_amdgcn_cvt_pk_f32_fp8(kv0.v.y, true);  acc2[3] = t * w2 + acc2[3];
        t = __builtin_amdgcn_cvt_pk_f32_fp8(kv0.v.z, false); acc2[4] = t * w2 + acc2[4];
        t = __builtin_amdgcn_cvt_pk_f32_fp8(kv0.v.z, true);  acc2[5] = t * w2 + acc2[5];
        t = __builtin_amdgcn_cvt_pk_f32_fp8(kv0.v.w, false); acc2[6] = t * w2 + acc2[6];
        t = __builtin_amdgcn_cvt_pk_f32_fp8(kv0.v.w, true);  acc2[7] = t * w2 + acc2[7];
        // shift pipelines
        pk0 = pk1; vd0 = vd1;
        pk1 = pk2; vd1 = vd2;
        pk2 = pk3; vd2 = vd3;
        kv0 = kv1; kv1 = kv2;
        inext += 8;
    }
    float accf[16];
    #pragma unroll
    for (int j = 0; j < 8; ++j) { accf[2 * j] = acc2[j][0]; accf[2 * j + 1] = acc2[j][1]; }
    // reduce the 8 edge-slots (lane bits 3,4,5)
    #pragma unroll
    for (int j = 0; j < 16; ++j) {
        accf[j] += __shfl_xor(accf[j], 8);
        accf[j] += __shfl_xor(accf[j], 16);
        accf[j] += __shfl_xor(accf[j], 32);
    }
    wsum += __shfl_xor(wsum, 8);
    wsum += __shfl_xor(wsum, 16);
    wsum += __shfl_xor(wsum, 32);
    if (slot == 0) {
        float inv = 1.0f / (wsum + 1e-8f);
        uint4 o0, o1;
        o0.x = packbf2(accf[0] * inv, accf[1] * inv);
        o0.y = packbf2(accf[2] * inv, accf[3] * inv);
        o0.z = packbf2(accf[4] * inv, accf[5] * inv);
        o0.w = packbf2(accf[6] * inv, accf[7] * inv);
        o1.x = packbf2(accf[8] * inv, accf[9] * inv);
        o1.y = packbf2(accf[10] * inv, accf[11] * inv);
        o1.z = packbf2(accf[12] * inv, accf[13] * inv);
        o1.w = packbf2(accf[14] * inv, accf[15] * inv);
        char* op = (char*)out + ((unsigned)n << 8) + ((unsigned)sub << 5);
        *(uint4*)op = o0;
        *(uint4*)(op + 16) = o1;
    }
}

extern "C" void kernel_launch(void* const* d_in, const int* in_sizes, int n_in,
                              void* d_out, int out_size, void* d_ws, size_t ws_size,
                              hipStream_t stream) {
    const float* x    = (const float*)d_in[0];
    const int*   ei   = (const int*)d_in[1];
    const int*   attr = (const int*)d_in[2];
    const float* Wq   = (const float*)d_in[3];
    const float* bq   = (const float*)d_in[4];
    const float* Wk   = (const float*)d_in[5];
    const float* bk   = (const float*)d_in[6];
    const float* Wv   = (const float*)d_in[7];
    const float* bv   = (const float*)d_in[8];
    const float* Wo   = (const float*)d_in[9];
    const float* bo   = (const float*)d_in[10];
    const float* ebt  = (const float*)d_in[11];
    const float* W1   = (const float*)d_in[12];
    const float* b1   = (const float*)d_in[13];
    const float* W2   = (const float*)d_in[14];
    const float* b2   = (const float*)d_in[15];
    const float* g1   = (const float*)d_in[16];
    const float* be1  = (const float*)d_in[17];
    const float* g2   = (const float*)d_in[18];
    const float* be2  = (const float*)d_in[19];
    float* out = (float*)d_out;

    char* ws = (char*)d_ws;
    const size_t szRowF = (size_t)N_NODES * HID * 4;   // 25.6 MB
    const size_t szRowB = (size_t)N_NODES * HID * 2;   // 12.8 MB
    const size_t ALIGN = 256;
    #define ALN(v) (((v) + ALIGN - 1) & ~(ALIGN - 1))
    size_t o = 0;
    __hip_bfloat16* h_buf = (__hip_bfloat16*)(ws + o); o += szRowB;
    _Float16* QKh = (_Float16*)(ws + o); o += (size_t)N_NODES * 256 * 2;        // 25.6MB (Q+K f16)
    unsigned char* V8 = (unsigned char*)(ws + o); o += (size_t)N_NODES * 128;   // 6.4MB
    unsigned int* packed = (unsigned int*)(ws + o); o += (size_t)E_EDGES * 4;   // 6.4MB
    unsigned int* temp = (unsigned int*)(ws + o); o += (size_t)NBKT * BKT_CAP * 4; // 7.2MB
    int* bcur = (int*)(ws + o); o = ALN(o + (size_t)NBKT * 4);
    int* offs = (int*)(ws + o); o = ALN(o + (size_t)(N_NODES + 1) * 4);
    __hip_bfloat16* attn_ob = (__hip_bfloat16*)(ws + o); o += szRowB;
    float* x1 = (float*)(ws + o); o += szRowF;
    __hip_bfloat16* f1 = (__hip_bfloat16*)(ws + o); o += (size_t)N_NODES * 512 * 2;  // 51.2MB
    __hip_bfloat16* Wqkvt = (__hip_bfloat16*)(ws + o); o += 384 * 128 * 2;
    __hip_bfloat16* Wot = (__hip_bfloat16*)(ws + o); o += 128 * 128 * 2;
    __hip_bfloat16* W1t = (__hip_bfloat16*)(ws + o); o += 512 * 128 * 2;
    __hip_bfloat16* W2t = (__hip_bfloat16*)(ws + o); o += 128 * 512 * 2;
    float* bqkv = (float*)(ws + o); o += 384 * 4;       // ~148 MB total
    __hip_bfloat16* h2 = h_buf;                          // alias: h dead after QKV

    hipMemsetAsync(bcur, 0, (size_t)NBKT * 4, stream);

    // Stage 1: binA + weight converts + LN1 co-scheduled in one launch
    prep_kernel<<<BINA_BLOCKS + WCVT_BLOCKS + LN_BLOCKS, 256, 0, stream>>>(
        ei, attr, bcur, temp,
        Wq, Wk, Wv, Wo, W1, W2, bq, bk, bv,
        Wqkvt, Wot, W1t, W2t, bqkv,
        x, g1, be1, h_buf);

    // Stage 2: binB finalizes CSR
    binB_kernel<<<NBKT, 1024, 0, stream>>>(bcur, temp, packed, offs);

    // Fused QKV projection (Q/K f16 planes, V fp8 plane)
    dim3 gqkv((N_NODES + 127) / 128, 3);
    gemm_mfma<128, 2><<<gqkv, 512, 0, stream>>>(h_buf, Wqkvt, bqkv, nullptr,
                                                nullptr, nullptr, QKh, V8,
                                                nullptr, nullptr, N_NODES, 384, 0);

    // Fused edge phase (wave per node, 8 slots x 8 lanes, depth-2 gather pipeline)
    fused_attn_kernel<<<(N_NODES + 3) / 4, 256, 0, stream>>>(packed, offs, QKh, V8, ebt, attn_ob);

    // Wo projection + residual(x) + fused LN2 -> x1 f32, h2 bf16
    dim3 gm((N_NODES + 127) / 128, 1);
    gemm_mfma<128, 3><<<gm, 512, 0, stream>>>(attn_ob, Wot, bo, x, x1,
                                              h2, nullptr, nullptr, g2, be2, N_NODES, 128, 0);

    // FFN
    dim3 gf1((N_NODES + 127) / 128, 4);
    gemm_mfma<128, 1><<<gf1, 512, 0, stream>>>(h2, W1t, b1, nullptr, nullptr,
                                               f1, nullptr, nullptr, nullptr, nullptr, N_NODES, 512, 1);
    gemm_mfma<512, 0><<<gm, 512, 0, stream>>>(f1, W2t, b2, x1, out,
                                              nullptr, nullptr, nullptr, nullptr, nullptr, N_NODES, 128, 0);
}

// Round 10
// 220.583 us; speedup vs baseline: 6.2131x; 1.0353x over previous
//
#include <hip/hip_runtime.h>
#include <hip/hip_bf16.h>

#define N_NODES 50000
#define E_EDGES 1600000
#define HID 128
#define NH 8
#define HD 16

#define NBKT 196        // ceil(50000/256) buckets of 256 dst nodes
#define BKT_CAP 9216    // mean 8192, sd ~90 -> +11 sigma headroom
#define CHUNK_A 4096
#define EPT 16          // edges per thread in binA (256 thr * 16)
#define BINA_BLOCKS ((E_EDGES + CHUNK_A - 1) / CHUNK_A)   // 391
#define WCVT_BLOCKS 771
#define LN_BLOCKS 12500
#define QKV_XBLOCKS ((N_NODES + 127) / 128)               // 391

using short8 = __attribute__((ext_vector_type(8))) short;
using f32x4  = __attribute__((ext_vector_type(4))) float;
using f32x2  = __attribute__((ext_vector_type(2))) float;
typedef _Float16 h16x2 __attribute__((ext_vector_type(2)));

#if defined(__has_builtin) && __has_builtin(__builtin_amdgcn_fdot2)
#define FDOT2(a, b, c) __builtin_amdgcn_fdot2((a), (b), (c), false)
#else
__device__ __forceinline__ float FDOT2(h16x2 a, h16x2 b, float c) {
    return fmaf((float)a[0], (float)b[0], fmaf((float)a[1], (float)b[1], c));
}
#endif

__device__ __forceinline__ float wave_reduce_sum(float v) {
    #pragma unroll
    for (int off = 32; off > 0; off >>= 1) v += __shfl_xor(v, off, 64);
    return v;
}

__device__ __forceinline__ unsigned int packbf2(float a, float b) {
    __hip_bfloat162 t;
    t.x = __float2bfloat16(a);
    t.y = __float2bfloat16(b);
    unsigned int u;
    __builtin_memcpy(&u, &t, 4);
    return u;
}

__device__ __forceinline__ unsigned char fp8e(float v) {
    return (unsigned char)(__builtin_amdgcn_cvt_pk_fp8_f32(v, v, 0u, false) & 0xFFu);
}

union U4H {
    uint4 u;
    h16x2 h[4];
};

struct KV {
    U4H k0, k1;
    uint4 v;
};

__device__ __forceinline__ KV loadkv(const char* khs, const unsigned char* v8s, unsigned pk) {
    KV r;
    unsigned rr = pk & 0xFFFFu;
    r.k0.u = *(const uint4*)(khs + (rr << 8));
    r.k1.u = *(const uint4*)(khs + (rr << 8) + 16u);
    r.v = *(const uint4*)(v8s + (rr << 7));
    return r;
}

__device__ __forceinline__ void consume_kv(const KV& kv, unsigned pk, bool vd,
                                           const U4H& q0, const U4H& q1,
                                           const float* bLDS, int sub,
                                           f32x2* acc2, float& wsum) {
    float p = 0.f;
    #pragma unroll
    for (int j = 0; j < 4; ++j) p = FDOT2(q0.h[j], kv.k0.h[j], p);
    #pragma unroll
    for (int j = 0; j < 4; ++j) p = FDOT2(q1.h[j], kv.k1.h[j], p);
    float s = p + bLDS[((pk >> 16) & 0xFu) * 8 + sub];
    float w = vd ? __expf(s) : 0.f;
    wsum += w;
    f32x2 w2; w2[0] = w; w2[1] = w;
    f32x2 t;
    t = __builtin_amdgcn_cvt_pk_f32_fp8(kv.v.x, false); acc2[0] = t * w2 + acc2[0];
    t = __builtin_amdgcn_cvt_pk_f32_fp8(kv.v.x, true);  acc2[1] = t * w2 + acc2[1];
    t = __builtin_amdgcn_cvt_pk_f32_fp8(kv.v.y, false); acc2[2] = t * w2 + acc2[2];
    t = __builtin_amdgcn_cvt_pk_f32_fp8(kv.v.y, true);  acc2[3] = t * w2 + acc2[3];
    t = __builtin_amdgcn_cvt_pk_f32_fp8(kv.v.z, false); acc2[4] = t * w2 + acc2[4];
    t = __builtin_amdgcn_cvt_pk_f32_fp8(kv.v.z, true);  acc2[5] = t * w2 + acc2[5];
    t = __builtin_amdgcn_cvt_pk_f32_fp8(kv.v.w, false); acc2[6] = t * w2 + acc2[6];
    t = __builtin_amdgcn_cvt_pk_f32_fp8(kv.v.w, true);  acc2[7] = t * w2 + acc2[7];
}

// ================= prep kernel: binA + weight-convert + LN1 in one launch ==========
// blocks [0,391): binA; [391,1162): wcvt; [1162,13662): LN1 (4 rows each).
// bcur must be zeroed by hipMemsetAsync BEFORE this kernel (binA atomics race else).
__global__ __launch_bounds__(256) void prep_kernel(
    const int* __restrict__ ei, const int* __restrict__ attr,
    int* __restrict__ bcur, unsigned int* __restrict__ temp,
    const float* __restrict__ Wq, const float* __restrict__ Wk,
    const float* __restrict__ Wv, const float* __restrict__ Wo,
    const float* __restrict__ W1, const float* __restrict__ W2,
    const float* __restrict__ bq, const float* __restrict__ bk,
    const float* __restrict__ bv,
    __hip_bfloat16* __restrict__ Wqkvt, __hip_bfloat16* __restrict__ Wot,
    __hip_bfloat16* __restrict__ W1t, __hip_bfloat16* __restrict__ W2t,
    float* __restrict__ bqkv,
    const float* __restrict__ x, const float* __restrict__ g1,
    const float* __restrict__ be1, __hip_bfloat16* __restrict__ h_out) {
    __shared__ unsigned int sval[CHUNK_A];
    __shared__ unsigned short sbkt[CHUNK_A];
    __shared__ int hist[NBKT];
    __shared__ int lofs[NBKT];
    __shared__ int gbase[NBKT];
    __shared__ int lcur[NBKT];
    __shared__ int sc[256];
    const int b = blockIdx.x;
    const int tid = threadIdx.x;
    if (b < BINA_BLOCKS) {
        // ---- binA: bucket edges (bucket = dst>>8) with LDS staging ----
        const int e0 = b * CHUNK_A;
        const int n = min(CHUNK_A, E_EDGES - e0);
        for (int i = tid; i < NBKT; i += 256) hist[i] = 0;
        __syncthreads();
        unsigned int v[EPT];
        short bk_[EPT];
        #pragma unroll
        for (int j = 0; j < EPT; ++j) {
            int i = tid + j * 256;
            bk_[j] = -1;
            v[j] = 0;
            if (i < n) {
                int e = e0 + i;
                int src = ei[e];
                int dst = ei[E_EDGES + e];
                int a = attr[e]; a = min(max(a, 0), 12);
                v[j] = (unsigned)src | ((unsigned)a << 16) | ((unsigned)(dst & 255) << 20);
                int bb = dst >> 8;
                bk_[j] = (short)bb;
                atomicAdd(&hist[bb], 1);
            }
        }
        __syncthreads();
        sc[tid] = (tid < NBKT) ? hist[tid] : 0;
        __syncthreads();
        for (int off = 1; off < 256; off <<= 1) {
            int xx = (tid >= off) ? sc[tid - off] : 0;
            __syncthreads();
            sc[tid] += xx;
            __syncthreads();
        }
        if (tid < NBKT) {
            int h = hist[tid];
            lofs[tid] = sc[tid] - h;
            lcur[tid] = 0;
            gbase[tid] = h ? atomicAdd(&bcur[tid], h) : 0;
        }
        __syncthreads();
        #pragma unroll
        for (int j = 0; j < EPT; ++j) {
            if (bk_[j] >= 0) {
                int p = lofs[bk_[j]] + atomicAdd(&lcur[bk_[j]], 1);
                sval[p] = v[j];
                sbkt[p] = (unsigned short)bk_[j];
            }
        }
        __syncthreads();
        for (int i = tid; i < n; i += 256) {
            int bb = sbkt[i];
            temp[(size_t)bb * BKT_CAP + gbase[bb] + (i - lofs[bb])] = sval[i];
        }
    } else if (b < BINA_BLOCKS + WCVT_BLOCKS) {
        // ---- wcvt: Wt[n][k] = bf16(W[k][n]); fused qkv bias ----
        int t = (b - BINA_BLOCKS) * 256 + tid;
        if (t >= 196608) {
            int i = t - 196608;
            if (i < 384) bqkv[i] = i < 128 ? bq[i] : (i < 256 ? bk[i - 128] : bv[i - 256]);
            return;
        }
        const float* W; __hip_bfloat16* Wt; int K, N, idx;
        if (t < 65536) {
            int which = t >> 14; idx = t & 16383; K = 128; N = 128;
            W = which == 0 ? Wq : which == 1 ? Wk : which == 2 ? Wv : Wo;
            Wt = which == 3 ? Wot : Wqkvt + which * 16384;
        } else if (t < 131072) { idx = t - 65536;  K = 128; N = 512; W = W1; Wt = W1t; }
        else                   { idx = t - 131072; K = 512; N = 128; W = W2; Wt = W2t; }
        int n = idx / K, k = idx - n * K;
        Wt[idx] = __float2bfloat16(W[(size_t)k * N + n]);
    } else {
        // ---- LN1: one wave per row ----
        int wave = tid >> 6;
        int lane = tid & 63;
        int row = (b - BINA_BLOCKS - WCVT_BLOCKS) * 4 + wave;
        if (row >= N_NODES) return;
        float2 v = ((const float2*)(x + (size_t)row * HID))[lane];
        float s = wave_reduce_sum(v.x + v.y);
        float mu = s * (1.0f / HID);
        float dx = v.x - mu, dy = v.y - mu;
        float q = wave_reduce_sum(dx * dx + dy * dy);
        float rstd = rsqrtf(q * (1.0f / HID) + 1e-5f);
        float2 gg = ((const float2*)g1)[lane];
        float2 bb = ((const float2*)be1)[lane];
        __hip_bfloat162 o;
        o.x = __float2bfloat16(dx * rstd * gg.x + bb.x);
        o.y = __float2bfloat16(dy * rstd * gg.y + bb.y);
        ((__hip_bfloat162*)(h_out + (size_t)row * HID))[lane] = o;
    }
}

// ================= merged kernel: binB (first 196 blocks) + QKV GEMM (rest) =========
// binB: per-bucket counting sort by dst low byte, 512 threads.
// GEMM: 128x128 tile, K=128; plane 0 Q f16 (scaled 0.25), 1 K f16, 2 V fp8.
__global__ __launch_bounds__(512) void qkv_binb_kernel(
    const int* __restrict__ bcur, const unsigned int* __restrict__ temp,
    unsigned int* __restrict__ packed, int* __restrict__ offs,
    const __hip_bfloat16* __restrict__ A, const __hip_bfloat16* __restrict__ Wt,
    const float* __restrict__ bias,
    _Float16* __restrict__ Chh, unsigned char* __restrict__ C8, int M) {
    __shared__ short8 smem[2048 + 2048];  // 64KB; binB aliases first 3KB
    const int tid = threadIdx.x;
    if (blockIdx.x < NBKT) {
        int* cnts = (int*)smem;
        int* hist = cnts + 256;
        int* cur = hist + 256;
        const int b = blockIdx.x;
        if (tid < 256) {
            cnts[tid] = (tid < NBKT) ? bcur[tid] : 0;
            hist[tid] = 0;
        }
        __syncthreads();
        for (int off = 1; off < 256; off <<= 1) {
            int x = 0;
            if (tid < 256 && tid >= off) x = cnts[tid - off];
            __syncthreads();
            if (tid < 256) cnts[tid] += x;
            __syncthreads();
        }
        const int cnt = bcur[b];
        const int start = cnts[b] - cnt;  // exclusive global start of this bucket
        const size_t base = (size_t)b * BKT_CAP;
        for (int i = tid; i < cnt; i += 512)
            atomicAdd(&hist[(temp[base + i] >> 20) & 255], 1);
        __syncthreads();
        if (tid < 256) cur[tid] = hist[tid];
        __syncthreads();
        for (int off = 1; off < 256; off <<= 1) {
            int x = 0;
            if (tid < 256 && tid >= off) x = cur[tid - off];
            __syncthreads();
            if (tid < 256) cur[tid] += x;
            __syncthreads();
        }
        const int node0 = b * 256;
        if (tid < 256) {
            int excl = cur[tid] - hist[tid];
            cur[tid] = excl;
            int node = node0 + tid;
            if (node < N_NODES) offs[node] = start + excl;
        }
        if (b == NBKT - 1 && tid == 0) offs[N_NODES] = start + cnt;
        __syncthreads();
        for (int i = tid; i < cnt; i += 512) {
            unsigned int v = temp[base + i];
            int d = (v >> 20) & 255;
            int p = start + atomicAdd(&cur[d], 1);
            packed[p] = v & 0xFFFFFu;   // src | attr<<16
        }
        return;
    }
    // ---- QKV GEMM part ----
    const int gb = blockIdx.x - NBKT;
    const int plane = gb / QKV_XBLOCKS;
    const int xb = gb - plane * QKV_XBLOCKS;
    const int row0 = xb * 128;
    const int col0 = plane * 128;
    const int w = tid >> 6, l = tid & 63;
    const int lr = l & 15, hi = l >> 4;
    f32x4 acc[8] = {};
    #pragma unroll
    for (int it = 0; it < 4; ++it) {
        unsigned d = tid + it * 512;
        int r = d >> 4, sd = d & 15;
        int ss = sd ^ (r & 7);
        int gr = row0 + r; if (gr >= M) gr = M - 1;
        __builtin_amdgcn_global_load_lds(
            (const __attribute__((address_space(1))) void*)(A + (size_t)gr * 128 + ss * 8),
            (__attribute__((address_space(3))) void*)(smem + (d & ~63u)),
            16, 0, 0);
    }
    #pragma unroll
    for (int it = 0; it < 4; ++it) {
        unsigned d = tid + it * 512;
        int r = d >> 4, sd = d & 15;
        int ss = sd ^ (r & 7);
        __builtin_amdgcn_global_load_lds(
            (const __attribute__((address_space(1))) void*)(Wt + (size_t)(col0 + r) * 128 + ss * 8),
            (__attribute__((address_space(3))) void*)(smem + 2048 + (d & ~63u)),
            16, 0, 0);
    }
    __syncthreads();
    const int ar = w * 16 + lr;
    #pragma unroll
    for (int ks = 0; ks < 4; ++ks) {
        int s = ks * 4 + hi;
        short8 a = smem[ar * 16 + (s ^ (ar & 7))];
        #pragma unroll
        for (int f = 0; f < 8; ++f) {
            int br = f * 16 + lr;
            short8 b = smem[2048 + br * 16 + (s ^ (br & 7))];
            acc[f] = __builtin_amdgcn_mfma_f32_16x16x32_bf16(a, b, acc[f], 0, 0, 0);
        }
    }
    const float scl = (plane == 0) ? 0.25f : 1.0f;
    #pragma unroll
    for (int f = 0; f < 8; ++f) {
        int c = col0 + f * 16 + lr;
        float bv = bias[c];
        #pragma unroll
        for (int j = 0; j < 4; ++j) {
            int r = row0 + w * 16 + hi * 4 + j;
            if (r < M) {
                float v = acc[f][j] + bv;
                if (plane < 2)
                    Chh[(size_t)plane * N_NODES * 128 + (size_t)r * 128 + (c & 127)] =
                        (_Float16)(v * scl);
                else
                    C8[(size_t)r * 128 + (c & 127)] = fp8e(v);
            }
        }
    }
}

// ---------------- MFMA GEMM: C[M,NC] = A[M,K](bf16) @ Wt[NC,K](bf16)^T + bias ----------
// 512 threads = 8 waves; tile 128x128; staging via global_load_lds (dest LDS-linear,
// source pre-swizzled so LDS image == XOR-swizzled layout; reads unchanged).
// OB: 0 -> f32 out, 1 -> bf16 out,
//     3 -> Wo+LN2: C=x1 f32 (acc+bias+res), Cb=bf16 LN(x1) with gw/bw params
template <int K, int OB>
__global__ __launch_bounds__(512) void gemm_mfma(const __hip_bfloat16* __restrict__ A,
                                                 const __hip_bfloat16* __restrict__ Wt,
                                                 const float* __restrict__ bias,
                                                 const float* __restrict__ res,
                                                 float* __restrict__ C,
                                                 __hip_bfloat16* __restrict__ Cb,
                                                 const float* __restrict__ gw,
                                                 const float* __restrict__ bw,
                                                 int M, int NC, int relu) {
    __shared__ short8 smem[2048 + 2048];  // A: 128x128 bf16 (32KB), B: 128x128 bf16 (32KB)
    const int row0 = blockIdx.x * 128;
    const int col0 = blockIdx.y * 128;
    const int tid = threadIdx.x;
    const int w = tid >> 6, l = tid & 63;
    const int lr = l & 15, hi = l >> 4;
    f32x4 acc[8] = {};
    for (int kk = 0; kk < K / 128; ++kk) {
        #pragma unroll
        for (int it = 0; it < 4; ++it) {
            unsigned d = tid + it * 512;
            int r = d >> 4, sd = d & 15;
            int ss = sd ^ (r & 7);
            int gr = row0 + r; if (gr >= M) gr = M - 1;
            __builtin_amdgcn_global_load_lds(
                (const __attribute__((address_space(1))) void*)(A + (size_t)gr * K + kk * 128 + ss * 8),
                (__attribute__((address_space(3))) void*)(smem + (d & ~63u)),
                16, 0, 0);
        }
        #pragma unroll
        for (int it = 0; it < 4; ++it) {
            unsigned d = tid + it * 512;
            int r = d >> 4, sd = d & 15;
            int ss = sd ^ (r & 7);
            __builtin_amdgcn_global_load_lds(
                (const __attribute__((address_space(1))) void*)(Wt + (size_t)(col0 + r) * K + kk * 128 + ss * 8),
                (__attribute__((address_space(3))) void*)(smem + 2048 + (d & ~63u)),
                16, 0, 0);
        }
        __syncthreads();
        const int ar = w * 16 + lr;
        #pragma unroll
        for (int ks = 0; ks < 4; ++ks) {
            int s = ks * 4 + hi;
            short8 a = smem[ar * 16 + (s ^ (ar & 7))];
            #pragma unroll
            for (int f = 0; f < 8; ++f) {
                int br = f * 16 + lr;
                short8 b = smem[2048 + br * 16 + (s ^ (br & 7))];
                acc[f] = __builtin_amdgcn_mfma_f32_16x16x32_bf16(a, b, acc[f], 0, 0, 0);
            }
        }
        __syncthreads();
    }
    if (OB == 3) {
        float vv[8][4];
        float gc[8], bc[8];
        #pragma unroll
        for (int f = 0; f < 8; ++f) {
            int c = f * 16 + lr;
            gc[f] = gw[c]; bc[f] = bw[c];
            float bv = bias[c];
            #pragma unroll
            for (int j = 0; j < 4; ++j) {
                int r = row0 + w * 16 + hi * 4 + j;
                int rr = r < M ? r : M - 1;
                vv[f][j] = acc[f][j] + bv + res[(size_t)rr * NC + c];
            }
        }
        #pragma unroll
        for (int j = 0; j < 4; ++j) {
            int r = row0 + w * 16 + hi * 4 + j;
            float s = 0.f, qq = 0.f;
            #pragma unroll
            for (int f = 0; f < 8; ++f) { s += vv[f][j]; qq += vv[f][j] * vv[f][j]; }
            #pragma unroll
            for (int m = 1; m <= 8; m <<= 1) { s += __shfl_xor(s, m); qq += __shfl_xor(qq, m); }
            float mu = s * (1.0f / 128.0f);
            float rstd = rsqrtf(qq * (1.0f / 128.0f) - mu * mu + 1e-5f);
            if (r < M) {
                #pragma unroll
                for (int f = 0; f < 8; ++f) {
                    int c = f * 16 + lr;
                    C[(size_t)r * NC + c] = vv[f][j];
                    Cb[(size_t)r * NC + c] = __float2bfloat16((vv[f][j] - mu) * rstd * gc[f] + bc[f]);
                }
            }
        }
        return;
    }
    #pragma unroll
    for (int f = 0; f < 8; ++f) {
        int c = col0 + f * 16 + lr;
        float bv = bias[c];
        #pragma unroll
        for (int j = 0; j < 4; ++j) {
            int r = row0 + w * 16 + hi * 4 + j;
            if (r < M) {
                float v = acc[f][j] + bv;
                if (relu) v = fmaxf(v, 0.f);
                if (res) v += res[(size_t)r * NC + c];
                if (OB == 0) C[(size_t)r * NC + c] = v;
                else Cb[(size_t)r * NC + c] = __float2bfloat16(v);
            }
        }
    }
}

// ---------------- Fused edge phase: wave-per-node, 8 edge slots x 8 lanes ------
// Q,K: f16 planes [2][N][128] (Q pre-scaled 1/sqrt(D)); V: fp8 plane [N][128].
// Steady-state 2x-unrolled: two KV register sets a,b; each half consumes its set
// then reloads the SAME registers for edge i+16 -> depth-2 pipeline, zero movs.
__global__ __launch_bounds__(256) void fused_attn_kernel(
    const unsigned int* __restrict__ packed,
    const int* __restrict__ offs,
    const _Float16* __restrict__ qkh,   // [2][N][128]
    const unsigned char* __restrict__ v8p,  // [N][128]
    const float* __restrict__ btab,     // [13,8]
    __hip_bfloat16* __restrict__ out) {
    __shared__ float bLDS[104];
    const int tid = threadIdx.x;
    if (tid < 104) bLDS[tid] = btab[tid];
    __syncthreads();
    const int wave = tid >> 6, lane = tid & 63;
    const int n = blockIdx.x * 4 + wave;
    const int slot = lane >> 3, sub = lane & 7;
    const char* qh = (const char*)qkh;
    const unsigned sb = (unsigned)sub << 5;   // byte offset of head within f16 row
    const char* khs = (const char*)(qkh + (size_t)N_NODES * 128) + sb;
    const unsigned char* v8s = v8p + (sb >> 1);
    U4H q0, q1;
    q0.u = *(const uint4*)(qh + ((unsigned)n << 8) + sb);
    q1.u = *(const uint4*)(qh + ((unsigned)n << 8) + sb + 16u);
    const int lo = offs[n], hi = offs[n + 1];
    const int nit = (hi - lo + 7) >> 3;
    f32x2 acc2[8] = {};
    float wsum = 0.f;
    int i = lo + slot;
    bool vd0 = i < hi;       unsigned pk0 = vd0 ? packed[i] : 0u;
    bool vd1 = i + 8 < hi;   unsigned pk1 = vd1 ? packed[i + 8] : 0u;
    KV a = loadkv(khs, v8s, pk0);
    KV b = loadkv(khs, v8s, pk1);
    int ii = i + 16;        // next edge index to fetch
    int rem = nit;
    while (rem >= 2) {
        const bool vd2 = ii < hi;
        const unsigned pk2 = vd2 ? packed[ii] : 0u;
        const bool vd3 = ii + 8 < hi;
        const unsigned pk3 = vd3 ? packed[ii + 8] : 0u;
        consume_kv(a, pk0, vd0, q0, q1, bLDS, sub, acc2, wsum);
        a = loadkv(khs, v8s, pk2);          // reload same regs (edge ii)
        consume_kv(b, pk1, vd1, q0, q1, bLDS, sub, acc2, wsum);
        b = loadkv(khs, v8s, pk3);          // reload same regs (edge ii+8)
        pk0 = pk2; vd0 = vd2;
        pk1 = pk3; vd1 = vd3;
        ii += 16;
        rem -= 2;
    }
    if (rem == 1) consume_kv(a, pk0, vd0, q0, q1, bLDS, sub, acc2, wsum);
    float accf[16];
    #pragma unroll
    for (int j = 0; j < 8; ++j) { accf[2 * j] = acc2[j][0]; accf[2 * j + 1] = acc2[j][1]; }
    // reduce the 8 edge-slots (lane bits 3,4,5)
    #pragma unroll
    for (int j = 0; j < 16; ++j) {
        accf[j] += __shfl_xor(accf[j], 8);
        accf[j] += __shfl_xor(accf[j], 16);
        accf[j] += __shfl_xor(accf[j], 32);
    }
    wsum += __shfl_xor(wsum, 8);
    wsum += __shfl_xor(wsum, 16);
    wsum += __shfl_xor(wsum, 32);
    if (slot == 0) {
        float inv = 1.0f / (wsum + 1e-8f);
        uint4 o0, o1;
        o0.x = packbf2(accf[0] * inv, accf[1] * inv);
        o0.y = packbf2(accf[2] * inv, accf[3] * inv);
        o0.z = packbf2(accf[4] * inv, accf[5] * inv);
        o0.w = packbf2(accf[6] * inv, accf[7] * inv);
        o1.x = packbf2(accf[8] * inv, accf[9] * inv);
        o1.y = packbf2(accf[10] * inv, accf[11] * inv);
        o1.z = packbf2(accf[12] * inv, accf[13] * inv);
        o1.w = packbf2(accf[14] * inv, accf[15] * inv);
        char* op = (char*)out + ((unsigned)n << 8) + ((unsigned)sub << 5);
        *(uint4*)op = o0;
        *(uint4*)(op + 16) = o1;
    }
}

extern "C" void kernel_launch(void* const* d_in, const int* in_sizes, int n_in,
                              void* d_out, int out_size, void* d_ws, size_t ws_size,
                              hipStream_t stream) {
    const float* x    = (const float*)d_in[0];
    const int*   ei   = (const int*)d_in[1];
    const int*   attr = (const int*)d_in[2];
    const float* Wq   = (const float*)d_in[3];
    const float* bq   = (const float*)d_in[4];
    const float* Wk   = (const float*)d_in[5];
    const float* bk   = (const float*)d_in[6];
    const float* Wv   = (const float*)d_in[7];
    const float* bv   = (const float*)d_in[8];
    const float* Wo   = (const float*)d_in[9];
    const float* bo   = (const float*)d_in[10];
    const float* ebt  = (const float*)d_in[11];
    const float* W1   = (const float*)d_in[12];
    const float* b1   = (const float*)d_in[13];
    const float* W2   = (const float*)d_in[14];
    const float* b2   = (const float*)d_in[15];
    const float* g1   = (const float*)d_in[16];
    const float* be1  = (const float*)d_in[17];
    const float* g2   = (const float*)d_in[18];
    const float* be2  = (const float*)d_in[19];
    float* out = (float*)d_out;

    char* ws = (char*)d_ws;
    const size_t szRowF = (size_t)N_NODES * HID * 4;   // 25.6 MB
    const size_t szRowB = (size_t)N_NODES * HID * 2;   // 12.8 MB
    const size_t ALIGN = 256;
    #define ALN(v) (((v) + ALIGN - 1) & ~(ALIGN - 1))
    size_t o = 0;
    __hip_bfloat16* h_buf = (__hip_bfloat16*)(ws + o); o += szRowB;
    _Float16* QKh = (_Float16*)(ws + o); o += (size_t)N_NODES * 256 * 2;        // 25.6MB (Q+K f16)
    unsigned char* V8 = (unsigned char*)(ws + o); o += (size_t)N_NODES * 128;   // 6.4MB
    unsigned int* packed = (unsigned int*)(ws + o); o += (size_t)E_EDGES * 4;   // 6.4MB
    unsigned int* temp = (unsigned int*)(ws + o); o += (size_t)NBKT * BKT_CAP * 4; // 7.2MB
    int* bcur = (int*)(ws + o); o = ALN(o + (size_t)NBKT * 4);
    int* offs = (int*)(ws + o); o = ALN(o + (size_t)(N_NODES + 1) * 4);
    __hip_bfloat16* attn_ob = (__hip_bfloat16*)(ws + o); o += szRowB;
    float* x1 = (float*)(ws + o); o += szRowF;
    __hip_bfloat16* f1 = (__hip_bfloat16*)(ws + o); o += (size_t)N_NODES * 512 * 2;  // 51.2MB
    __hip_bfloat16* Wqkvt = (__hip_bfloat16*)(ws + o); o += 384 * 128 * 2;
    __hip_bfloat16* Wot = (__hip_bfloat16*)(ws + o); o += 128 * 128 * 2;
    __hip_bfloat16* W1t = (__hip_bfloat16*)(ws + o); o += 512 * 128 * 2;
    __hip_bfloat16* W2t = (__hip_bfloat16*)(ws + o); o += 128 * 512 * 2;
    float* bqkv = (float*)(ws + o); o += 384 * 4;       // ~148 MB total
    __hip_bfloat16* h2 = h_buf;                          // alias: h dead after QKV

    hipMemsetAsync(bcur, 0, (size_t)NBKT * 4, stream);

    // Stage 1: binA + weight converts + LN1 co-scheduled in one launch
    prep_kernel<<<BINA_BLOCKS + WCVT_BLOCKS + LN_BLOCKS, 256, 0, stream>>>(
        ei, attr, bcur, temp,
        Wq, Wk, Wv, Wo, W1, W2, bq, bk, bv,
        Wqkvt, Wot, W1t, W2t, bqkv,
        x, g1, be1, h_buf);

    // Stage 2: binB (196 blocks) + QKV GEMM (391x3 blocks) in one launch
    qkv_binb_kernel<<<NBKT + QKV_XBLOCKS * 3, 512, 0, stream>>>(
        bcur, temp, packed, offs,
        h_buf, Wqkvt, bqkv, QKh, V8, N_NODES);

    // Fused edge phase (wave per node, 8 slots x 8 lanes, 2x-unrolled depth-2 pipeline)
    fused_attn_kernel<<<(N_NODES + 3) / 4, 256, 0, stream>>>(packed, offs, QKh, V8, ebt, attn_ob);

    // Wo projection + residual(x) + fused LN2 -> x1 f32, h2 bf16
    dim3 gm((N_NODES + 127) / 128, 1);
    gemm_mfma<128, 3><<<gm, 512, 0, stream>>>(attn_ob, Wot, bo, x, x1,
                                              h2, g2, be2, N_NODES, 128, 0);

    // FFN
    dim3 gf1((N_NODES + 127) / 128, 4);
    gemm_mfma<128, 1><<<gf1, 512, 0, stream>>>(h2, W1t, b1, nullptr, nullptr,
                                               f1, nullptr, nullptr, N_NODES, 512, 1);
    gemm_mfma<512, 0><<<gm, 512, 0, stream>>>(f1, W2t, b2, x1, out,
                                              nullptr, nullptr, nullptr, N_NODES, 128, 0);
}